// Round 6
// baseline (2423.277 us; speedup 1.0000x reference)
//
#include <hip/hip_runtime.h>
#include <hip/hip_bf16.h>
#include <math.h>

#define DIMK 1024
#define NDEPTH 4
#define DS 16
#define DCONV 4
#define DI 2048
#define DTR 64
#define NB 4
#define SL 2048
#define MT (NB * SL)        // 8192
#define NXZ (2 * DI)        // 4096
#define NDBC (DTR + 2 * DS) // 96

typedef float f32x4 __attribute__((ext_vector_type(4)));
typedef float f32x2 __attribute__((ext_vector_type(2)));
typedef short short8 __attribute__((ext_vector_type(8)));
typedef short short4v __attribute__((ext_vector_type(4)));

__device__ inline unsigned short f2bf(float f) {
    unsigned u = __builtin_bit_cast(unsigned, f);
    unsigned r = (u + 0x7FFFu + ((u >> 16) & 1u)) >> 16;
    return (unsigned short)r;
}
__device__ inline float bf2f(unsigned short h) {
    unsigned u = ((unsigned)h) << 16;
    return __builtin_bit_cast(float, u);
}
__device__ inline void split_bf(float f, unsigned short& hi, unsigned short& lo) {
    hi = f2bf(f);
    lo = f2bf(f - bf2f(hi));
}
__device__ inline unsigned short cvt1(float f) {
    __hip_bfloat16 t = __float2bfloat16(f);
    return __builtin_bit_cast(unsigned short, t);
}
__device__ inline void mfma16(f32x4& d, short8 a, short8 b) {
    asm volatile("v_mfma_f32_16x16x32_bf16 %0, %1, %2, %0"
                 : "+v"(d) : "v"(a), "v"(b));
}
template <int CTRL>
__device__ inline float dpp_radd(float v) {
    int x = __builtin_bit_cast(int, v);
    int m = __builtin_amdgcn_update_dpp(0, x, CTRL, 0xF, 0xF, false);
    return v + __builtin_bit_cast(float, m);
}
// async global->LDS, 16 B per lane. LDS dest = wave-uniform base + lane*16.
__device__ __forceinline__ void gload16(const unsigned short* g, unsigned short* l) {
    __builtin_amdgcn_global_load_lds(
        (const __attribute__((address_space(1))) unsigned int*)(g),
        (__attribute__((address_space(3))) unsigned int*)(l),
        16, 0, 0);
}

// ---------------------------------------------------------------------------
// elementwise fp32 -> bf16 (RNE), 4 per thread
__global__ __launch_bounds__(256) void cvt_bf16(
    const float* __restrict__ s, unsigned short* __restrict__ d, int n4)
{
    const int g = blockIdx.x * 256 + threadIdx.x;
    if (g < n4) {
        const float4 f = *(const float4*)(s + (size_t)g * 4);
        short4v v;
        v[0] = (short)cvt1(f.x); v[1] = (short)cvt1(f.y);
        v[2] = (short)cvt1(f.z); v[3] = (short)cvt1(f.w);
        *(short4v*)(d + (size_t)g * 4) = v;
    }
}

// ---------------------------------------------------------------------------
// C[m,n] = sum_k A[m,k]*B[n,k]; A,B bf16 in global, C fp32.
__global__ __launch_bounds__(256) void gemm_bb(
    const unsigned short* __restrict__ A, const unsigned short* __restrict__ B,
    float* __restrict__ C, int K, int lda, int ldb, int ldc)
{
    __shared__ unsigned short As[128 * 32];
    __shared__ unsigned short Bs[128 * 32];
    const int tid = threadIdx.x;
    const int bm = blockIdx.y * 128, bn = blockIdx.x * 128;
    const int wv = tid >> 6, ln = tid & 63;
    const int wr = wv >> 1, wc = wv & 1;
    const int fr = ln & 15, kg = ln >> 4;
    const int sr0 = wv * 32 + (ln >> 2);
    const int sr1 = sr0 + 16;
    const int sl = ln & 3;
    const int cg0 = sl ^ ((sr0 >> 1) & 3);
    const int cg1 = sl ^ ((sr1 >> 1) & 3);
    const unsigned short* pa0 = A + (size_t)(bm + sr0) * lda + cg0 * 8;
    const unsigned short* pa1 = A + (size_t)(bm + sr1) * lda + cg1 * 8;
    const unsigned short* pb0 = B + (size_t)(bn + sr0) * ldb + cg0 * 8;
    const unsigned short* pb1 = B + (size_t)(bn + sr1) * ldb + cg1 * 8;
    unsigned short* la0 = As + (wv * 32 + 0) * 32;
    unsigned short* la1 = As + (wv * 32 + 16) * 32;
    unsigned short* lb0 = Bs + (wv * 32 + 0) * 32;
    unsigned short* lb1 = Bs + (wv * 32 + 16) * 32;
    f32x4 acc[4][4] = {};
    for (int k0 = 0; k0 < K; k0 += 32) {
        gload16(pa0 + k0, la0);
        gload16(pa1 + k0, la1);
        gload16(pb0 + k0, lb0);
        gload16(pb1 + k0, lb1);
        __syncthreads();
        short8 af[4], bw[4];
        #pragma unroll
        for (int f = 0; f < 4; ++f) {
            const int ra = wr * 64 + f * 16 + fr;
            af[f] = *(const short8*)&As[ra * 32 + ((kg ^ ((ra >> 1) & 3)) * 8)];
            const int rb = wc * 64 + f * 16 + fr;
            bw[f] = *(const short8*)&Bs[rb * 32 + ((kg ^ ((rb >> 1) & 3)) * 8)];
        }
        #pragma unroll
        for (int fi = 0; fi < 4; ++fi)
            #pragma unroll
            for (int fj = 0; fj < 4; ++fj)
                mfma16(acc[fi][fj], af[fi], bw[fj]);
        __syncthreads();
    }
    #pragma unroll
    for (int fi = 0; fi < 4; ++fi) {
        const int m0 = bm + wr * 64 + fi * 16 + kg * 4;
        #pragma unroll
        for (int fj = 0; fj < 4; ++fj) {
            const int n = bn + wc * 64 + fj * 16 + fr;
            #pragma unroll
            for (int q = 0; q < 4; ++q)
                C[(size_t)(m0 + q) * ldc + n] = acc[fi][fj][q];
        }
    }
}

// ---------------------------------------------------------------------------
// A fp32 (reg-staged + cvt), B bf16 (global_load_lds). CBF: 1 -> bf16 C out.
template <int CBF>
__global__ __launch_bounds__(256) void gemm_fb(
    const float* __restrict__ A, const unsigned short* __restrict__ B,
    void* __restrict__ Cv, int K, int lda, int ldb, int ldc)
{
    __shared__ unsigned short As[128 * 32];
    __shared__ unsigned short Bs[128 * 32];
    const int tid = threadIdx.x;
    const int bm = blockIdx.y * 128, bn = blockIdx.x * 128;
    const int wv = tid >> 6, ln = tid & 63;
    const int wr = wv >> 1, wc = wv & 1;
    const int fr = ln & 15, kg = ln >> 4;
    const int r = tid >> 1, hf = tid & 1;
    const int sr0 = wv * 32 + (ln >> 2);
    const int sr1 = sr0 + 16;
    const int sl = ln & 3;
    const int cg0 = sl ^ ((sr0 >> 1) & 3);
    const int cg1 = sl ^ ((sr1 >> 1) & 3);
    const unsigned short* pb0 = B + (size_t)(bn + sr0) * ldb + cg0 * 8;
    const unsigned short* pb1 = B + (size_t)(bn + sr1) * ldb + cg1 * 8;
    unsigned short* lb0 = Bs + (wv * 32 + 0) * 32;
    unsigned short* lb1 = Bs + (wv * 32 + 16) * 32;
    const float* ga = A + (size_t)(bm + r) * lda + hf * 16;
    f32x4 acc[4][4] = {};
    for (int k0 = 0; k0 < K; k0 += 32) {
        gload16(pb0 + k0, lb0);
        gload16(pb1 + k0, lb1);
        #pragma unroll
        for (int p = 0; p < 2; ++p) {
            const int pk = (2 * hf + p) ^ ((r >> 1) & 3);
            const float4 f0 = *(const float4*)(ga + k0 + p * 8);
            const float4 f1 = *(const float4*)(ga + k0 + p * 8 + 4);
            short8 v;
            v[0] = (short)cvt1(f0.x); v[1] = (short)cvt1(f0.y);
            v[2] = (short)cvt1(f0.z); v[3] = (short)cvt1(f0.w);
            v[4] = (short)cvt1(f1.x); v[5] = (short)cvt1(f1.y);
            v[6] = (short)cvt1(f1.z); v[7] = (short)cvt1(f1.w);
            *(short8*)&As[r * 32 + pk * 8] = v;
        }
        __syncthreads();
        short8 af[4], bw[4];
        #pragma unroll
        for (int f = 0; f < 4; ++f) {
            const int ra = wr * 64 + f * 16 + fr;
            af[f] = *(const short8*)&As[ra * 32 + ((kg ^ ((ra >> 1) & 3)) * 8)];
            const int rb = wc * 64 + f * 16 + fr;
            bw[f] = *(const short8*)&Bs[rb * 32 + ((kg ^ ((rb >> 1) & 3)) * 8)];
        }
        #pragma unroll
        for (int fi = 0; fi < 4; ++fi)
            #pragma unroll
            for (int fj = 0; fj < 4; ++fj)
                mfma16(acc[fi][fj], af[fi], bw[fj]);
        __syncthreads();
    }
    #pragma unroll
    for (int fi = 0; fi < 4; ++fi) {
        const int m0 = bm + wr * 64 + fi * 16 + kg * 4;
        #pragma unroll
        for (int fj = 0; fj < 4; ++fj) {
            const int n = bn + wc * 64 + fj * 16 + fr;
            #pragma unroll
            for (int q = 0; q < 4; ++q) {
                if (CBF) {
                    unsigned short* Cs = (unsigned short*)Cv;
                    Cs[(size_t)(m0 + q) * ldc + n] = cvt1(acc[fi][fj][q]);
                } else {
                    float* Cf = (float*)Cv;
                    Cf[(size_t)(m0 + q) * ldc + n] = acc[fi][fj][q];
                }
            }
        }
    }
}

// ---------------------------------------------------------------------------
// fallback GEMM (fp32 in/out), used only if ws too small
__global__ __launch_bounds__(256) void gemm_mfma(
    const float* __restrict__ A, const float* __restrict__ W,
    float* __restrict__ C, int K, int lda, int ldc)
{
    __shared__ unsigned short As[128 * 32];
    __shared__ unsigned short Ws[128 * 32];
    const int tid = threadIdx.x;
    const int bm = blockIdx.y * 128;
    const int bn = blockIdx.x * 128;
    const int r = tid >> 1;
    const int h = tid & 1;
    const int wv = tid >> 6;
    const int wr = wv >> 1;
    const int wc = wv & 1;
    const int ln = tid & 63;
    const int fr = ln & 15;
    const int kg = ln >> 4;
    f32x4 acc[4][4] = {};
    const float* ga = A + (size_t)(bm + r) * lda + h * 16;
    const float* gw = W + (size_t)(bn + r) * K + h * 16;
    for (int k0 = 0; k0 < K; k0 += 32) {
        #pragma unroll
        for (int p = 0; p < 2; ++p) {
            const int pk = (2 * h + p) ^ ((r >> 1) & 3);
            float4 f0 = *(const float4*)(ga + k0 + p * 8);
            float4 f1 = *(const float4*)(ga + k0 + p * 8 + 4);
            short8 v;
            v[0] = (short)cvt1(f0.x); v[1] = (short)cvt1(f0.y);
            v[2] = (short)cvt1(f0.z); v[3] = (short)cvt1(f0.w);
            v[4] = (short)cvt1(f1.x); v[5] = (short)cvt1(f1.y);
            v[6] = (short)cvt1(f1.z); v[7] = (short)cvt1(f1.w);
            *(short8*)&As[r * 32 + pk * 8] = v;
            f0 = *(const float4*)(gw + k0 + p * 8);
            f1 = *(const float4*)(gw + k0 + p * 8 + 4);
            v[0] = (short)cvt1(f0.x); v[1] = (short)cvt1(f0.y);
            v[2] = (short)cvt1(f0.z); v[3] = (short)cvt1(f0.w);
            v[4] = (short)cvt1(f1.x); v[5] = (short)cvt1(f1.y);
            v[6] = (short)cvt1(f1.z); v[7] = (short)cvt1(f1.w);
            *(short8*)&Ws[r * 32 + pk * 8] = v;
        }
        __syncthreads();
        short8 af[4], bw[4];
        #pragma unroll
        for (int f = 0; f < 4; ++f) {
            const int ra = wr * 64 + f * 16 + fr;
            af[f] = *(const short8*)&As[ra * 32 + ((kg ^ ((ra >> 1) & 3)) * 8)];
            const int rb = wc * 64 + f * 16 + fr;
            bw[f] = *(const short8*)&Ws[rb * 32 + ((kg ^ ((rb >> 1) & 3)) * 8)];
        }
        #pragma unroll
        for (int fi = 0; fi < 4; ++fi)
            #pragma unroll
            for (int fj = 0; fj < 4; ++fj)
                mfma16(acc[fi][fj], af[fi], bw[fj]);
        __syncthreads();
    }
    #pragma unroll
    for (int fi = 0; fi < 4; ++fi) {
        const int m0 = bm + wr * 64 + fi * 16 + kg * 4;
        #pragma unroll
        for (int fj = 0; fj < 4; ++fj) {
            const int n = bn + wc * 64 + fj * 16 + fr;
            #pragma unroll
            for (int q = 0; q < 4; ++q)
                C[(size_t)(m0 + q) * ldc + n] = acc[fi][fj][q];
        }
    }
}

// ---------------------------------------------------------------------------
// dbc = xc @ xp^T, hi/lo-split bf16 MFMA (~fp32 accuracy). BM=128, BN=32.
__global__ __launch_bounds__(256) void gemm_xproj(
    const float* __restrict__ A, const float* __restrict__ W,
    float* __restrict__ C, int K, int lda)
{
    __shared__ unsigned short Ah[128 * 32], Al[128 * 32];
    __shared__ unsigned short Wh[32 * 32], Wl[32 * 32];
    const int tid = threadIdx.x;
    const int bm = blockIdx.y * 128;
    const int bn = blockIdx.x * 32;
    const int r = tid >> 1, hf = tid & 1;
    const int wv = tid >> 6;
    const int ln = tid & 63, fr = ln & 15, kg = ln >> 4;
    const int wsr = tid >> 3;
    const int wc4 = (tid & 7) << 2;
    f32x4 acc[2][2] = {};
    const float* ga = A + (size_t)(bm + r) * lda + hf * 16;
    const float* gw = W + (size_t)(bn + wsr) * K + wc4;
    for (int k0 = 0; k0 < K; k0 += 32) {
        #pragma unroll
        for (int j = 0; j < 4; ++j) {
            const int col = hf * 16 + j * 4;
            const int ad = r * 32 + (((col >> 3) ^ ((r >> 1) & 3)) << 3) + (col & 7);
            const float4 fa = *(const float4*)(ga + k0 + j * 4);
            short4v h4, l4;
            #pragma unroll
            for (int e = 0; e < 4; ++e) {
                unsigned short hh, llo;
                split_bf((&fa.x)[e], hh, llo);
                h4[e] = (short)hh; l4[e] = (short)llo;
            }
            *(short4v*)&Ah[ad] = h4;
            *(short4v*)&Al[ad] = l4;
        }
        {
            const int ad = wsr * 32 + (((wc4 >> 3) ^ ((wsr >> 1) & 3)) << 3) + (wc4 & 7);
            const float4 fw = *(const float4*)(gw + k0);
            short4v h4, l4;
            #pragma unroll
            for (int e = 0; e < 4; ++e) {
                unsigned short hh, llo;
                split_bf((&fw.x)[e], hh, llo);
                h4[e] = (short)hh; l4[e] = (short)llo;
            }
            *(short4v*)&Wh[ad] = h4;
            *(short4v*)&Wl[ad] = l4;
        }
        __syncthreads();
        short8 ah[2], alo[2], bh[2], bl[2];
        #pragma unroll
        for (int f = 0; f < 2; ++f) {
            const int ra = wv * 32 + f * 16 + fr;
            const int ao = ra * 32 + ((kg ^ ((ra >> 1) & 3)) * 8);
            ah[f]  = *(const short8*)&Ah[ao];
            alo[f] = *(const short8*)&Al[ao];
            const int rb = f * 16 + fr;
            const int bo = rb * 32 + ((kg ^ ((rb >> 1) & 3)) * 8);
            bh[f] = *(const short8*)&Wh[bo];
            bl[f] = *(const short8*)&Wl[bo];
        }
        #pragma unroll
        for (int fi = 0; fi < 2; ++fi)
            #pragma unroll
            for (int fj = 0; fj < 2; ++fj) {
                mfma16(acc[fi][fj], ah[fi], bh[fj]);
                mfma16(acc[fi][fj], ah[fi], bl[fj]);
                mfma16(acc[fi][fj], alo[fi], bh[fj]);
            }
        __syncthreads();
    }
    #pragma unroll
    for (int fi = 0; fi < 2; ++fi) {
        const int m0 = bm + wv * 32 + fi * 16 + kg * 4;
        #pragma unroll
        for (int fj = 0; fj < 2; ++fj) {
            const int n = bn + fj * 16 + fr;
            #pragma unroll
            for (int q = 0; q < 4; ++q)
                C[(size_t)(m0 + q) * NDBC + n] = acc[fi][fj][q];
        }
    }
}

// ---------------------------------------------------------------------------
// delta = softplus(dt @ dtw^T + dtb) -> xi half of xz. Split MFMA, K=64.
__global__ __launch_bounds__(256) void gemm_delta(
    const float* __restrict__ A, const float* __restrict__ W,
    float* __restrict__ C, const float* __restrict__ bias)
{
    __shared__ unsigned short Ah[128 * 32], Al[128 * 32];
    __shared__ unsigned short Wh[128 * 32], Wl[128 * 32];
    const int tid = threadIdx.x;
    const int bm = blockIdx.y * 128;
    const int bn = blockIdx.x * 128;
    const int r = tid >> 1, hf = tid & 1;
    const int wv = tid >> 6, wr = wv >> 1, wc = wv & 1;
    const int ln = tid & 63, fr = ln & 15, kg = ln >> 4;
    f32x4 acc[4][4] = {};
    const float* ga = A + (size_t)(bm + r) * NDBC + hf * 16;
    const float* gw = W + (size_t)(bn + r) * DTR + hf * 16;
    for (int k0 = 0; k0 < DTR; k0 += 32) {
        #pragma unroll
        for (int j = 0; j < 4; ++j) {
            const int col = hf * 16 + j * 4;
            const int ad = r * 32 + (((col >> 3) ^ ((r >> 1) & 3)) << 3) + (col & 7);
            const float4 fa = *(const float4*)(ga + k0 + j * 4);
            const float4 fw = *(const float4*)(gw + k0 + j * 4);
            short4v ah4, al4, wh4, wl4;
            #pragma unroll
            for (int e = 0; e < 4; ++e) {
                unsigned short hh, llo;
                split_bf((&fa.x)[e], hh, llo);
                ah4[e] = (short)hh; al4[e] = (short)llo;
                split_bf((&fw.x)[e], hh, llo);
                wh4[e] = (short)hh; wl4[e] = (short)llo;
            }
            *(short4v*)&Ah[ad] = ah4; *(short4v*)&Al[ad] = al4;
            *(short4v*)&Wh[ad] = wh4; *(short4v*)&Wl[ad] = wl4;
        }
        __syncthreads();
        short8 ah[4], alo[4], bh[4], bl[4];
        #pragma unroll
        for (int f = 0; f < 4; ++f) {
            const int ra = wr * 64 + f * 16 + fr;
            const int ao = ra * 32 + ((kg ^ ((ra >> 1) & 3)) * 8);
            ah[f]  = *(const short8*)&Ah[ao];
            alo[f] = *(const short8*)&Al[ao];
            const int rb = wc * 64 + f * 16 + fr;
            const int bo = rb * 32 + ((kg ^ ((rb >> 1) & 3)) * 8);
            bh[f] = *(const short8*)&Wh[bo];
            bl[f] = *(const short8*)&Wl[bo];
        }
        #pragma unroll
        for (int fi = 0; fi < 4; ++fi)
            #pragma unroll
            for (int fj = 0; fj < 4; ++fj) {
                mfma16(acc[fi][fj], ah[fi], bh[fj]);
                mfma16(acc[fi][fj], ah[fi], bl[fj]);
                mfma16(acc[fi][fj], alo[fi], bh[fj]);
            }
        __syncthreads();
    }
    #pragma unroll
    for (int fi = 0; fi < 4; ++fi) {
        const int m0 = bm + wr * 64 + fi * 16 + kg * 4;
        #pragma unroll
        for (int fj = 0; fj < 4; ++fj) {
            const int n = bn + wc * 64 + fj * 16 + fr;
            const float bb = bias[n];
            #pragma unroll
            for (int q = 0; q < 4; ++q) {
                float v = acc[fi][fj][q] + bb;
                v = (v > 20.f) ? v : log1pf(__expf(v));
                C[(size_t)(m0 + q) * NXZ + n] = v;
            }
        }
    }
}

// ---------------------------------------------------------------------------
__global__ __launch_bounds__(256) void conv_silu(
    const float* __restrict__ xz, const float* __restrict__ cw,
    const float* __restrict__ cb, float* __restrict__ xc)
{
    const int g = blockIdx.x * 256 + threadIdx.x;
    const int c4 = g & (DI / 4 - 1);
    const int m = g >> 9;
    const int l = m & (SL - 1);
    const int c = c4 << 2;
    const float4 w0 = *(const float4*)(cw + (size_t)(c + 0) * DCONV);
    const float4 w1 = *(const float4*)(cw + (size_t)(c + 1) * DCONV);
    const float4 w2 = *(const float4*)(cw + (size_t)(c + 2) * DCONV);
    const float4 w3 = *(const float4*)(cw + (size_t)(c + 3) * DCONV);
    float4 acc = *(const float4*)(cb + c);
    #pragma unroll
    for (int j = 0; j < DCONV; ++j) {
        const int lj = l - 3 + j;
        if (lj >= 0) {
            const float4 v = *(const float4*)(xz + (size_t)(m - 3 + j) * NXZ + c);
            acc.x = fmaf(v.x, (&w0.x)[j], acc.x);
            acc.y = fmaf(v.y, (&w1.x)[j], acc.y);
            acc.z = fmaf(v.z, (&w2.x)[j], acc.z);
            acc.w = fmaf(v.w, (&w3.x)[j], acc.w);
        }
    }
    acc.x = acc.x / (1.f + __expf(-acc.x));
    acc.y = acc.y / (1.f + __expf(-acc.y));
    acc.z = acc.z / (1.f + __expf(-acc.z));
    acc.w = acc.w / (1.f + __expf(-acc.w));
    *(float4*)(xc + (size_t)m * DI + c) = acc;
}

// ---------------------------------------------------------------------------
// Selective scan v3: 4 states/thread, packed f32x2 math, quad DPP reduce.
// Block = 128 thr = 2 independent waves (no barriers). Wave = 16 ch x 4 lanes.
__global__ __launch_bounds__(128) void scan_k(
    const float* u,                 // xc [M, DI]
    const float* __restrict__ dbc,  // [M, 96]: B 64..79, C 80..95
    const float* __restrict__ xz,   // delta at col c, z at col DI+c
    float* y,                       // = xc (aliased with u)
    const float* __restrict__ Alog, // [DI, DS] layer slice
    const float* __restrict__ Dl)   // [DI]
{
    __shared__ float sdl[2][16][68];
    __shared__ float sxb[2][16][68];
    __shared__ float sB [2][64][20];
    __shared__ float sC [2][64][20];
    __shared__ float sy [2][16][68];

    const int tid = threadIdx.x;
    const int wv = tid >> 6, lane = tid & 63;
    const int b = blockIdx.y;
    const int c0w = blockIdx.x * 32 + wv * 16;
    const int ch = lane >> 2, a = lane & 3;
    const int c = c0w + ch;

    const float4 al4 = *(const float4*)(Alog + (size_t)c * DS + a * 4);
    f32x2 AaA, AaB;
    AaA[0] = -__expf(al4.x); AaA[1] = -__expf(al4.y);
    AaB[0] = -__expf(al4.z); AaB[1] = -__expf(al4.w);

    const int lt = lane >> 2, lq = (lane & 3) << 2;   // dl/u/z role: 16t x 4col
    const int bt = lane >> 3, bq = (lane & 7) << 2;   // B/C role: 8t x 8col

    const float4 D4 = *(const float4*)(Dl + c0w + lq);

    float4 gdl[4], gu[4], gz[4], gbc[8];
    float4 p0r[4], p1r[4];
    f32x2 h01 = {0.f, 0.f}, h23 = {0.f, 0.f};

    const size_t base = (size_t)b * SL;

    // prologue: issue loads for tile 0
    #pragma unroll
    for (int it = 0; it < 4; ++it) {
        const size_t m = base + it * 16 + lt;
        gdl[it] = *(const float4*)(xz + m * NXZ + c0w + lq);
        gu [it] = *(const float4*)(u  + m * DI  + c0w + lq);
        gz [it] = *(const float4*)(xz + m * NXZ + DI + c0w + lq);
    }
    #pragma unroll
    for (int it = 0; it < 8; ++it) {
        const size_t m = base + it * 8 + bt;
        gbc[it] = *(const float4*)(dbc + m * NDBC + DTR + bq);
    }

    for (int tile = 0; tile < SL / 64; ++tile) {
        // ---- transform + LDS store (consumes prefetched regs) ----
        #pragma unroll
        for (int it = 0; it < 4; ++it) {
            const int t = it * 16 + lt;
            const float4 d4 = gdl[it], u4 = gu[it], z4 = gz[it];
            float4 p0v, p1v;
            #pragma unroll
            for (int e = 0; e < 4; ++e) {
                const float dl = (&d4.x)[e], uu = (&u4.x)[e], zz = (&z4.x)[e];
                const float w = zz / (1.f + __expf(-zz));
                sdl[wv][lq + e][t] = dl;
                sxb[wv][lq + e][t] = dl * uu;
                (&p1v.x)[e] = w;
                (&p0v.x)[e] = uu * (&D4.x)[e] * w;
            }
            p0r[it] = p0v; p1r[it] = p1v;
        }
        #pragma unroll
        for (int it = 0; it < 8; ++it) {
            const int t = it * 8 + bt;
            float* dst = (bq < 16) ? &sB[wv][t][bq] : &sC[wv][t][bq - 16];
            *(float4*)dst = gbc[it];
        }
        // ---- issue loads for next tile (hidden under the t-loop) ----
        if (tile + 1 < SL / 64) {
            const size_t mb = base + (size_t)(tile + 1) * 64;
            #pragma unroll
            for (int it = 0; it < 4; ++it) {
                const size_t m = mb + it * 16 + lt;
                gdl[it] = *(const float4*)(xz + m * NXZ + c0w + lq);
                gu [it] = *(const float4*)(u  + m * DI  + c0w + lq);
                gz [it] = *(const float4*)(xz + m * NXZ + DI + c0w + lq);
            }
            #pragma unroll
            for (int it = 0; it < 8; ++it) {
                const size_t m = mb + it * 8 + bt;
                gbc[it] = *(const float4*)(dbc + m * NDBC + DTR + bq);
            }
        }
        // ---- serial t-loop: 4 states/lane, packed ops ----
        for (int jt = 0; jt < 16; ++jt) {
            const float4 dlq = *(const float4*)&sdl[wv][ch][jt * 4];
            const float4 xbq = *(const float4*)&sxb[wv][ch][jt * 4];
            float4 ys;
            #pragma unroll
            for (int tt = 0; tt < 4; ++tt) {
                const float4 B4 = *(const float4*)&sB[wv][jt * 4 + tt][a * 4];
                const float4 C4 = *(const float4*)&sC[wv][jt * 4 + tt][a * 4];
                const float dl = (&dlq.x)[tt], xb = (&xbq.x)[tt];
                f32x2 dl2; dl2[0] = dl; dl2[1] = dl;
                f32x2 dA = dl2 * AaA;
                f32x2 eA; eA[0] = __expf(dA[0]); eA[1] = __expf(dA[1]);
                f32x2 t1; t1[0] = xb * B4.x; t1[1] = xb * B4.y;
                h01 = eA * h01 + t1;
                dA = dl2 * AaB;
                eA[0] = __expf(dA[0]); eA[1] = __expf(dA[1]);
                t1[0] = xb * B4.z; t1[1] = xb * B4.w;
                h23 = eA * h23 + t1;
                f32x2 c01; c01[0] = C4.x; c01[1] = C4.y;
                f32x2 c23; c23[0] = C4.z; c23[1] = C4.w;
                f32x2 p = h01 * c01 + h23 * c23;
                float py = p[0] + p[1];
                py = dpp_radd<0xB1>(py);   // quad_perm [1,0,3,2]
                py = dpp_radd<0x4E>(py);   // quad_perm [2,3,0,1]
                (&ys.x)[tt] = py;
            }
            if (a == 0)
                *(float4*)&sy[wv][ch][jt * 4] = ys;
        }
        // ---- epilogue: y = py * silu(z) + u*D*silu(z), coalesced store ----
        const size_t mb = base + (size_t)tile * 64;
        #pragma unroll
        for (int it = 0; it < 4; ++it) {
            const int t = it * 16 + lt;
            float4 yv;
            #pragma unroll
            for (int e = 0; e < 4; ++e)
                (&yv.x)[e] = fmaf(sy[wv][lq + e][t], (&p1r[it].x)[e],
                                  (&p0r[it].x)[e]);
            *(float4*)(y + (mb + t) * DI + c0w + lq) = yv;
        }
    }
}

// ---------------------------------------------------------------------------
extern "C" void kernel_launch(void* const* d_in, const int* in_sizes, int n_in,
                              void* d_out, int out_size, void* d_ws, size_t ws_size,
                              hipStream_t stream)
{
    const float* x0   = (const float*)d_in[0];
    const float* in_w = (const float*)d_in[1];
    const float* cw   = (const float*)d_in[2];
    const float* cb   = (const float*)d_in[3];
    const float* xpw  = (const float*)d_in[4];
    const float* dtw  = (const float*)d_in[5];
    const float* dtb  = (const float*)d_in[6];
    const float* Alog = (const float*)d_in[7];
    const float* Dp   = (const float*)d_in[8];
    const float* ow   = (const float*)d_in[9];

    const size_t perB = (size_t)SL * (NXZ + DI + NDBC) * sizeof(float); // ~51.1MB
    const size_t wby  = ((size_t)NXZ * DIMK + (size_t)DIMK * DI) * 2;   // 12.6MB
    int nbc = 0, fast = 0;
    if (ws_size >= 4 * perB + wby)      { nbc = 4; fast = 1; }
    else if (ws_size >= 2 * perB + wby) { nbc = 2; fast = 1; }
    else if (ws_size >= perB + wby)     { nbc = 1; fast = 1; }
    else if (ws_size >= 4 * perB)       { nbc = 4; }
    else if (ws_size >= 2 * perB)       { nbc = 2; }
    else if (ws_size >= perB)           { nbc = 1; }
    else return;
    const int nchunks = NB / nbc;
    const int M = nbc * SL;

    float* xz  = (float*)d_ws;                 // [M, NXZ]; xi half reused as delta
    float* xc  = xz + (size_t)M * NXZ;         // [M, DI];  reused as y
    float* dbc = xc + (size_t)M * DI;          // [M, NDBC]
    unsigned short* wi16 = (unsigned short*)(dbc + (size_t)M * NDBC);
    unsigned short* ow16 = wi16 + (size_t)NXZ * DIMK;

    unsigned short* xb16 = (unsigned short*)d_out + (size_t)MT * DIMK;
    float* xbuf = (float*)d_out;

    const dim3 blk(256);
    if (fast) {
        const int n4x = MT * DIMK / 4;
        cvt_bf16<<<dim3(n4x / 256), blk, 0, stream>>>(x0, xb16, n4x);
    }
    for (int ly = 0; ly < NDEPTH; ++ly) {
        const float* Wi   = in_w + (size_t)ly * NXZ * DIMK;
        const float* cwl  = cw   + (size_t)ly * DI * DCONV;
        const float* cbl  = cb   + (size_t)ly * DI;
        const float* xpl  = xpw  + (size_t)ly * NDBC * DI;
        const float* dtwl = dtw  + (size_t)ly * DI * DTR;
        const float* dtbl = dtb  + (size_t)ly * DI;
        const float* Al   = Alog + (size_t)ly * DI * DS;
        const float* Dl   = Dp   + (size_t)ly * DI;
        const float* owl  = ow   + (size_t)ly * DIMK * DI;

        if (fast) {
            const int n4w = NXZ * DIMK / 4;
            cvt_bf16<<<dim3(n4w / 256), blk, 0, stream>>>(Wi, wi16, n4w);
            const int n4o = DIMK * DI / 4;
            cvt_bf16<<<dim3(n4o / 256), blk, 0, stream>>>(owl, ow16, n4o);
        }

        for (int ck = 0; ck < nchunks; ++ck) {
            if (fast) {
                const unsigned short* xin16 = xb16 + (size_t)ck * M * DIMK;
                gemm_bb<<<dim3(NXZ / 128, M / 128), blk, 0, stream>>>(
                    xin16, wi16, xz, DIMK, DIMK, DIMK, NXZ);
            } else {
                const float* xin = (ly == 0 ? x0 : xbuf) + (size_t)ck * M * DIMK;
                gemm_mfma<<<dim3(NXZ / 128, M / 128), blk, 0, stream>>>(
                    xin, Wi, xz, DIMK, DIMK, NXZ);
            }
            conv_silu<<<dim3(M * (DI / 4) / 256), blk, 0, stream>>>(xz, cwl, cbl, xc);
            gemm_xproj<<<dim3(3, M / 128), blk, 0, stream>>>(
                xc, xpl, dbc, DI, DI);
            gemm_delta<<<dim3(DI / 128, M / 128), blk, 0, stream>>>(
                dbc, dtwl, xz, dtbl);
            // scan v3: 128-thread blocks, 32 channels each (2 waves x 16)
            scan_k<<<dim3(DI / 32, nbc), dim3(128), 0, stream>>>(
                xc, dbc, xz, xc, Al, Dl);
            if (fast) {
                if (ly < NDEPTH - 1) {
                    gemm_fb<1><<<dim3(DIMK / 128, M / 128), blk, 0, stream>>>(
                        xc, ow16, xb16 + (size_t)ck * M * DIMK, DI, DI, DI, DIMK);
                } else {
                    gemm_fb<0><<<dim3(DIMK / 128, M / 128), blk, 0, stream>>>(
                        xc, ow16, (float*)d_out + (size_t)ck * M * DIMK,
                        DI, DI, DI, DIMK);
                }
            } else {
                float* xdst = (ly == NDEPTH - 1 ? (float*)d_out : xbuf) +
                              (size_t)ck * M * DIMK;
                gemm_mfma<<<dim3(DIMK / 128, M / 128), blk, 0, stream>>>(
                    xc, owl, xdst, DI, DI, DIMK);
            }
        }
    }
}

// Round 7
// 2262.969 us; speedup vs baseline: 1.0708x; 1.0708x over previous
//
#include <hip/hip_runtime.h>
#include <hip/hip_bf16.h>
#include <math.h>

#define DIMK 1024
#define NDEPTH 4
#define DS 16
#define DCONV 4
#define DI 2048
#define DTR 64
#define NB 4
#define SL 2048
#define MT (NB * SL)        // 8192
#define NXZ (2 * DI)        // 4096
#define NDBC (DTR + 2 * DS) // 96

typedef float f32x4 __attribute__((ext_vector_type(4)));
typedef short short8 __attribute__((ext_vector_type(8)));
typedef short short4v __attribute__((ext_vector_type(4)));

__device__ inline unsigned short f2bf(float f) {
    unsigned u = __builtin_bit_cast(unsigned, f);
    unsigned r = (u + 0x7FFFu + ((u >> 16) & 1u)) >> 16;
    return (unsigned short)r;
}
__device__ inline float bf2f(unsigned short h) {
    unsigned u = ((unsigned)h) << 16;
    return __builtin_bit_cast(float, u);
}
__device__ inline void split_bf(float f, unsigned short& hi, unsigned short& lo) {
    hi = f2bf(f);
    lo = f2bf(f - bf2f(hi));
}
__device__ inline unsigned short cvt1(float f) {
    __hip_bfloat16 t = __float2bfloat16(f);
    return __builtin_bit_cast(unsigned short, t);
}
__device__ inline void mfma16(f32x4& d, short8 a, short8 b) {
    asm volatile("v_mfma_f32_16x16x32_bf16 %0, %1, %2, %0"
                 : "+v"(d) : "v"(a), "v"(b));
}
template <int CTRL>
__device__ inline float dpp_radd(float v) {
    int x = __builtin_bit_cast(int, v);
    int m = __builtin_amdgcn_update_dpp(0, x, CTRL, 0xF, 0xF, false);
    return v + __builtin_bit_cast(float, m);
}
__device__ __forceinline__ void gload16(const unsigned short* g, unsigned short* l) {
    __builtin_amdgcn_global_load_lds(
        (const __attribute__((address_space(1))) unsigned int*)(g),
        (__attribute__((address_space(3))) unsigned int*)(l),
        16, 0, 0);
}

// ---------------------------------------------------------------------------
__global__ __launch_bounds__(256) void cvt_bf16(
    const float* __restrict__ s, unsigned short* __restrict__ d, int n4)
{
    const int g = blockIdx.x * 256 + threadIdx.x;
    if (g < n4) {
        const float4 f = *(const float4*)(s + (size_t)g * 4);
        short4v v;
        v[0] = (short)cvt1(f.x); v[1] = (short)cvt1(f.y);
        v[2] = (short)cvt1(f.z); v[3] = (short)cvt1(f.w);
        *(short4v*)(d + (size_t)g * 4) = v;
    }
}

// fp32 -> (hi, lo) bf16 split, elementwise
__global__ __launch_bounds__(256) void cvt_split(
    const float* __restrict__ s, unsigned short* __restrict__ dh,
    unsigned short* __restrict__ dl, int n)
{
    const int i = blockIdx.x * 256 + threadIdx.x;
    if (i < n) {
        unsigned short h, l;
        split_bf(s[i], h, l);
        dh[i] = h; dl[i] = l;
    }
}

// ---------------------------------------------------------------------------
// C[m,n] = sum_k A[m,k]*B[n,k]; A,B bf16 global. 2-phase dbuf + XCD swizzle.
__global__ __launch_bounds__(256) void gemm_bb(
    const unsigned short* __restrict__ A, const unsigned short* __restrict__ B,
    float* __restrict__ C, int K, int lda, int ldb, int ldc)
{
    __shared__ unsigned short As[2][128 * 32];
    __shared__ unsigned short Bs[2][128 * 32];
    // bijective XCD swizzle (nwg % 8 == 0 for all grids used)
    int id = blockIdx.y * gridDim.x + blockIdx.x;
    const int qq = (gridDim.x * gridDim.y) >> 3;
    id = (id & 7) * qq + (id >> 3);
    const int bm = (id / gridDim.x) * 128, bn = (id % gridDim.x) * 128;

    const int tid = threadIdx.x;
    const int wv = tid >> 6, ln = tid & 63;
    const int wr = wv >> 1, wc = wv & 1;
    const int fr = ln & 15, kg = ln >> 4;
    const int sr0 = wv * 32 + (ln >> 2);
    const int sr1 = sr0 + 16;
    const int sl = ln & 3;
    const int cg0 = sl ^ ((sr0 >> 1) & 3);
    const int cg1 = sl ^ ((sr1 >> 1) & 3);
    const unsigned short* pa0 = A + (size_t)(bm + sr0) * lda + cg0 * 8;
    const unsigned short* pa1 = A + (size_t)(bm + sr1) * lda + cg1 * 8;
    const unsigned short* pb0 = B + (size_t)(bn + sr0) * ldb + cg0 * 8;
    const unsigned short* pb1 = B + (size_t)(bn + sr1) * ldb + cg1 * 8;
    const int ldst0 = (wv * 32 + 0) * 32;
    const int ldst1 = (wv * 32 + 16) * 32;
    // frag offsets (within one buffer)
    int offA[4], offB[4];
    #pragma unroll
    for (int f = 0; f < 4; ++f) {
        const int ra = wr * 64 + f * 16 + fr;
        offA[f] = ra * 32 + ((kg ^ ((ra >> 1) & 3)) * 8);
        const int rb = wc * 64 + f * 16 + fr;
        offB[f] = rb * 32 + ((kg ^ ((rb >> 1) & 3)) * 8);
    }
    f32x4 acc[4][4] = {};
    // prologue: stage k0=0 into buf 0
    gload16(pa0, &As[0][ldst0]);
    gload16(pa1, &As[0][ldst1]);
    gload16(pb0, &Bs[0][ldst0]);
    gload16(pb1, &Bs[0][ldst1]);
    __syncthreads();
    int cur = 0;
    for (int k0 = 0; k0 < K; k0 += 32) {
        const int nxt = cur ^ 1;
        if (k0 + 32 < K) {
            gload16(pa0 + k0 + 32, &As[nxt][ldst0]);
            gload16(pa1 + k0 + 32, &As[nxt][ldst1]);
            gload16(pb0 + k0 + 32, &Bs[nxt][ldst0]);
            gload16(pb1 + k0 + 32, &Bs[nxt][ldst1]);
        }
        short8 af[4], bw[4];
        #pragma unroll
        for (int f = 0; f < 4; ++f) {
            af[f] = *(const short8*)&As[cur][offA[f]];
            bw[f] = *(const short8*)&Bs[cur][offB[f]];
        }
        #pragma unroll
        for (int fi = 0; fi < 4; ++fi)
            #pragma unroll
            for (int fj = 0; fj < 4; ++fj)
                mfma16(acc[fi][fj], af[fi], bw[fj]);
        __syncthreads();   // drains gloads (next tile ready) + read-done fence
        cur = nxt;
    }
    #pragma unroll
    for (int fi = 0; fi < 4; ++fi) {
        const int m0 = bm + wr * 64 + fi * 16 + kg * 4;
        #pragma unroll
        for (int fj = 0; fj < 4; ++fj) {
            const int n = bn + wc * 64 + fj * 16 + fr;
            #pragma unroll
            for (int q = 0; q < 4; ++q)
                C[(size_t)(m0 + q) * ldc + n] = acc[fi][fj][q];
        }
    }
}

// ---------------------------------------------------------------------------
// A fp32 (reg prefetch + cvt after MFMA), B bf16 (gload dbuf). CBF: bf16 C.
template <int CBF>
__global__ __launch_bounds__(256) void gemm_fb(
    const float* __restrict__ A, const unsigned short* __restrict__ B,
    void* __restrict__ Cv, int K, int lda, int ldb, int ldc)
{
    __shared__ unsigned short As[2][128 * 32];
    __shared__ unsigned short Bs[2][128 * 32];
    int id = blockIdx.y * gridDim.x + blockIdx.x;
    const int qq = (gridDim.x * gridDim.y) >> 3;
    id = (id & 7) * qq + (id >> 3);
    const int bm = (id / gridDim.x) * 128, bn = (id % gridDim.x) * 128;

    const int tid = threadIdx.x;
    const int wv = tid >> 6, ln = tid & 63;
    const int wr = wv >> 1, wc = wv & 1;
    const int fr = ln & 15, kg = ln >> 4;
    const int r = tid >> 1, hf = tid & 1;
    const int sr0 = wv * 32 + (ln >> 2);
    const int sr1 = sr0 + 16;
    const int sl = ln & 3;
    const int cg0 = sl ^ ((sr0 >> 1) & 3);
    const int cg1 = sl ^ ((sr1 >> 1) & 3);
    const unsigned short* pb0 = B + (size_t)(bn + sr0) * ldb + cg0 * 8;
    const unsigned short* pb1 = B + (size_t)(bn + sr1) * ldb + cg1 * 8;
    const int ldst0 = (wv * 32 + 0) * 32;
    const int ldst1 = (wv * 32 + 16) * 32;
    const float* ga = A + (size_t)(bm + r) * lda + hf * 16;
    const int pk0 = (2 * hf + 0) ^ ((r >> 1) & 3);
    const int pk1 = (2 * hf + 1) ^ ((r >> 1) & 3);
    int offA[4], offB[4];
    #pragma unroll
    for (int f = 0; f < 4; ++f) {
        const int ra = wr * 64 + f * 16 + fr;
        offA[f] = ra * 32 + ((kg ^ ((ra >> 1) & 3)) * 8);
        const int rb = wc * 64 + f * 16 + fr;
        offB[f] = rb * 32 + ((kg ^ ((rb >> 1) & 3)) * 8);
    }
    f32x4 acc[4][4] = {};

    // prologue: stage k0 = 0
    {
        float4 f0 = *(const float4*)(ga + 0);
        float4 f1 = *(const float4*)(ga + 4);
        float4 f2 = *(const float4*)(ga + 8);
        float4 f3 = *(const float4*)(ga + 12);
        short8 v;
        v[0] = (short)cvt1(f0.x); v[1] = (short)cvt1(f0.y);
        v[2] = (short)cvt1(f0.z); v[3] = (short)cvt1(f0.w);
        v[4] = (short)cvt1(f1.x); v[5] = (short)cvt1(f1.y);
        v[6] = (short)cvt1(f1.z); v[7] = (short)cvt1(f1.w);
        *(short8*)&As[0][r * 32 + pk0 * 8] = v;
        v[0] = (short)cvt1(f2.x); v[1] = (short)cvt1(f2.y);
        v[2] = (short)cvt1(f2.z); v[3] = (short)cvt1(f2.w);
        v[4] = (short)cvt1(f3.x); v[5] = (short)cvt1(f3.y);
        v[6] = (short)cvt1(f3.z); v[7] = (short)cvt1(f3.w);
        *(short8*)&As[0][r * 32 + pk1 * 8] = v;
        gload16(pb0, &Bs[0][ldst0]);
        gload16(pb1, &Bs[0][ldst1]);
    }
    __syncthreads();
    int cur = 0;
    for (int k0 = 0; k0 < K; k0 += 32) {
        const int nxt = cur ^ 1;
        const bool more = (k0 + 32 < K);
        float4 f0, f1, f2, f3;
        if (more) {
            gload16(pb0 + k0 + 32, &Bs[nxt][ldst0]);
            gload16(pb1 + k0 + 32, &Bs[nxt][ldst1]);
            f0 = *(const float4*)(ga + k0 + 32);
            f1 = *(const float4*)(ga + k0 + 36);
            f2 = *(const float4*)(ga + k0 + 40);
            f3 = *(const float4*)(ga + k0 + 44);
        }
        short8 af[4], bw[4];
        #pragma unroll
        for (int f = 0; f < 4; ++f) {
            af[f] = *(const short8*)&As[cur][offA[f]];
            bw[f] = *(const short8*)&Bs[cur][offB[f]];
        }
        #pragma unroll
        for (int fi = 0; fi < 4; ++fi)
            #pragma unroll
            for (int fj = 0; fj < 4; ++fj)
                mfma16(acc[fi][fj], af[fi], bw[fj]);
        if (more) {
            short8 v;
            v[0] = (short)cvt1(f0.x); v[1] = (short)cvt1(f0.y);
            v[2] = (short)cvt1(f0.z); v[3] = (short)cvt1(f0.w);
            v[4] = (short)cvt1(f1.x); v[5] = (short)cvt1(f1.y);
            v[6] = (short)cvt1(f1.z); v[7] = (short)cvt1(f1.w);
            *(short8*)&As[nxt][r * 32 + pk0 * 8] = v;
            v[0] = (short)cvt1(f2.x); v[1] = (short)cvt1(f2.y);
            v[2] = (short)cvt1(f2.z); v[3] = (short)cvt1(f2.w);
            v[4] = (short)cvt1(f3.x); v[5] = (short)cvt1(f3.y);
            v[6] = (short)cvt1(f3.z); v[7] = (short)cvt1(f3.w);
            *(short8*)&As[nxt][r * 32 + pk1 * 8] = v;
        }
        __syncthreads();
        cur = nxt;
    }
    #pragma unroll
    for (int fi = 0; fi < 4; ++fi) {
        const int m0 = bm + wr * 64 + fi * 16 + kg * 4;
        #pragma unroll
        for (int fj = 0; fj < 4; ++fj) {
            const int n = bn + wc * 64 + fj * 16 + fr;
            #pragma unroll
            for (int q = 0; q < 4; ++q) {
                if (CBF) {
                    unsigned short* Cs = (unsigned short*)Cv;
                    Cs[(size_t)(m0 + q) * ldc + n] = cvt1(acc[fi][fj][q]);
                } else {
                    float* Cf = (float*)Cv;
                    Cf[(size_t)(m0 + q) * ldc + n] = acc[fi][fj][q];
                }
            }
        }
    }
}

// ---------------------------------------------------------------------------
// fallback GEMM (fp32 in/out), used only if ws too small
__global__ __launch_bounds__(256) void gemm_mfma(
    const float* __restrict__ A, const float* __restrict__ W,
    float* __restrict__ C, int K, int lda, int ldc)
{
    __shared__ unsigned short As[128 * 32];
    __shared__ unsigned short Ws[128 * 32];
    const int tid = threadIdx.x;
    const int bm = blockIdx.y * 128;
    const int bn = blockIdx.x * 128;
    const int r = tid >> 1;
    const int h = tid & 1;
    const int wv = tid >> 6;
    const int wr = wv >> 1;
    const int wc = wv & 1;
    const int ln = tid & 63;
    const int fr = ln & 15;
    const int kg = ln >> 4;
    f32x4 acc[4][4] = {};
    const float* ga = A + (size_t)(bm + r) * lda + h * 16;
    const float* gw = W + (size_t)(bn + r) * K + h * 16;
    for (int k0 = 0; k0 < K; k0 += 32) {
        #pragma unroll
        for (int p = 0; p < 2; ++p) {
            const int pk = (2 * h + p) ^ ((r >> 1) & 3);
            float4 f0 = *(const float4*)(ga + k0 + p * 8);
            float4 f1 = *(const float4*)(ga + k0 + p * 8 + 4);
            short8 v;
            v[0] = (short)cvt1(f0.x); v[1] = (short)cvt1(f0.y);
            v[2] = (short)cvt1(f0.z); v[3] = (short)cvt1(f0.w);
            v[4] = (short)cvt1(f1.x); v[5] = (short)cvt1(f1.y);
            v[6] = (short)cvt1(f1.z); v[7] = (short)cvt1(f1.w);
            *(short8*)&As[r * 32 + pk * 8] = v;
            f0 = *(const float4*)(gw + k0 + p * 8);
            f1 = *(const float4*)(gw + k0 + p * 8 + 4);
            v[0] = (short)cvt1(f0.x); v[1] = (short)cvt1(f0.y);
            v[2] = (short)cvt1(f0.z); v[3] = (short)cvt1(f0.w);
            v[4] = (short)cvt1(f1.x); v[5] = (short)cvt1(f1.y);
            v[6] = (short)cvt1(f1.z); v[7] = (short)cvt1(f1.w);
            *(short8*)&Ws[r * 32 + pk * 8] = v;
        }
        __syncthreads();
        short8 af[4], bw[4];
        #pragma unroll
        for (int f = 0; f < 4; ++f) {
            const int ra = wr * 64 + f * 16 + fr;
            af[f] = *(const short8*)&As[ra * 32 + ((kg ^ ((ra >> 1) & 3)) * 8)];
            const int rb = wc * 64 + f * 16 + fr;
            bw[f] = *(const short8*)&Ws[rb * 32 + ((kg ^ ((rb >> 1) & 3)) * 8)];
        }
        #pragma unroll
        for (int fi = 0; fi < 4; ++fi)
            #pragma unroll
            for (int fj = 0; fj < 4; ++fj)
                mfma16(acc[fi][fj], af[fi], bw[fj]);
        __syncthreads();
    }
    #pragma unroll
    for (int fi = 0; fi < 4; ++fi) {
        const int m0 = bm + wr * 64 + fi * 16 + kg * 4;
        #pragma unroll
        for (int fj = 0; fj < 4; ++fj) {
            const int n = bn + wc * 64 + fj * 16 + fr;
            #pragma unroll
            for (int q = 0; q < 4; ++q)
                C[(size_t)(m0 + q) * ldc + n] = acc[fi][fj][q];
        }
    }
}

// ---------------------------------------------------------------------------
// dbc = xc @ xp^T, hi/lo-split bf16 MFMA. BM=128, BN=32.
// WRDT: also emit split-bf16 of dt cols (n < 64) to dth/dtl [M,64].
template <int WRDT>
__global__ __launch_bounds__(256) void gemm_xproj(
    const float* __restrict__ A, const float* __restrict__ W,
    float* __restrict__ C, int K, int lda,
    unsigned short* __restrict__ dth, unsigned short* __restrict__ dtl)
{
    __shared__ unsigned short Ah[128 * 32], Al[128 * 32];
    __shared__ unsigned short Wh[32 * 32], Wl[32 * 32];
    const int tid = threadIdx.x;
    const int bm = blockIdx.y * 128;
    const int bn = blockIdx.x * 32;
    const int r = tid >> 1, hf = tid & 1;
    const int wv = tid >> 6;
    const int ln = tid & 63, fr = ln & 15, kg = ln >> 4;
    const int wsr = tid >> 3;
    const int wc4 = (tid & 7) << 2;
    f32x4 acc[2][2] = {};
    const float* ga = A + (size_t)(bm + r) * lda + hf * 16;
    const float* gw = W + (size_t)(bn + wsr) * K + wc4;
    for (int k0 = 0; k0 < K; k0 += 32) {
        #pragma unroll
        for (int j = 0; j < 4; ++j) {
            const int col = hf * 16 + j * 4;
            const int ad = r * 32 + (((col >> 3) ^ ((r >> 1) & 3)) << 3) + (col & 7);
            const float4 fa = *(const float4*)(ga + k0 + j * 4);
            short4v h4, l4;
            #pragma unroll
            for (int e = 0; e < 4; ++e) {
                unsigned short hh, llo;
                split_bf((&fa.x)[e], hh, llo);
                h4[e] = (short)hh; l4[e] = (short)llo;
            }
            *(short4v*)&Ah[ad] = h4;
            *(short4v*)&Al[ad] = l4;
        }
        {
            const int ad = wsr * 32 + (((wc4 >> 3) ^ ((wsr >> 1) & 3)) << 3) + (wc4 & 7);
            const float4 fw = *(const float4*)(gw + k0);
            short4v h4, l4;
            #pragma unroll
            for (int e = 0; e < 4; ++e) {
                unsigned short hh, llo;
                split_bf((&fw.x)[e], hh, llo);
                h4[e] = (short)hh; l4[e] = (short)llo;
            }
            *(short4v*)&Wh[ad] = h4;
            *(short4v*)&Wl[ad] = l4;
        }
        __syncthreads();
        short8 ah[2], alo[2], bh[2], bl[2];
        #pragma unroll
        for (int f = 0; f < 2; ++f) {
            const int ra = wv * 32 + f * 16 + fr;
            const int ao = ra * 32 + ((kg ^ ((ra >> 1) & 3)) * 8);
            ah[f]  = *(const short8*)&Ah[ao];
            alo[f] = *(const short8*)&Al[ao];
            const int rb = f * 16 + fr;
            const int bo = rb * 32 + ((kg ^ ((rb >> 1) & 3)) * 8);
            bh[f] = *(const short8*)&Wh[bo];
            bl[f] = *(const short8*)&Wl[bo];
        }
        #pragma unroll
        for (int fi = 0; fi < 2; ++fi)
            #pragma unroll
            for (int fj = 0; fj < 2; ++fj) {
                mfma16(acc[fi][fj], ah[fi], bh[fj]);
                mfma16(acc[fi][fj], ah[fi], bl[fj]);
                mfma16(acc[fi][fj], alo[fi], bh[fj]);
            }
        __syncthreads();
    }
    #pragma unroll
    for (int fi = 0; fi < 2; ++fi) {
        const int m0 = bm + wv * 32 + fi * 16 + kg * 4;
        #pragma unroll
        for (int fj = 0; fj < 2; ++fj) {
            const int n = bn + fj * 16 + fr;
            #pragma unroll
            for (int q = 0; q < 4; ++q) {
                const float v = acc[fi][fj][q];
                C[(size_t)(m0 + q) * NDBC + n] = v;
                if (WRDT && n < DTR) {
                    unsigned short hh, llo;
                    split_bf(v, hh, llo);
                    dth[(size_t)(m0 + q) * DTR + n] = hh;
                    dtl[(size_t)(m0 + q) * DTR + n] = llo;
                }
            }
        }
    }
}

// ---------------------------------------------------------------------------
// delta (fallback): split in-kernel from fp32 dbc/dtw. K=64.
__global__ __launch_bounds__(256) void gemm_delta(
    const float* __restrict__ A, const float* __restrict__ W,
    float* __restrict__ C, const float* __restrict__ bias)
{
    __shared__ unsigned short Ah[128 * 32], Al[128 * 32];
    __shared__ unsigned short Wh[128 * 32], Wl[128 * 32];
    const int tid = threadIdx.x;
    const int bm = blockIdx.y * 128;
    const int bn = blockIdx.x * 128;
    const int r = tid >> 1, hf = tid & 1;
    const int wv = tid >> 6, wr = wv >> 1, wc = wv & 1;
    const int ln = tid & 63, fr = ln & 15, kg = ln >> 4;
    f32x4 acc[4][4] = {};
    const float* ga = A + (size_t)(bm + r) * NDBC + hf * 16;
    const float* gw = W + (size_t)(bn + r) * DTR + hf * 16;
    for (int k0 = 0; k0 < DTR; k0 += 32) {
        #pragma unroll
        for (int j = 0; j < 4; ++j) {
            const int col = hf * 16 + j * 4;
            const int ad = r * 32 + (((col >> 3) ^ ((r >> 1) & 3)) << 3) + (col & 7);
            const float4 fa = *(const float4*)(ga + k0 + j * 4);
            const float4 fw = *(const float4*)(gw + k0 + j * 4);
            short4v ah4, al4, wh4, wl4;
            #pragma unroll
            for (int e = 0; e < 4; ++e) {
                unsigned short hh, llo;
                split_bf((&fa.x)[e], hh, llo);
                ah4[e] = (short)hh; al4[e] = (short)llo;
                split_bf((&fw.x)[e], hh, llo);
                wh4[e] = (short)hh; wl4[e] = (short)llo;
            }
            *(short4v*)&Ah[ad] = ah4; *(short4v*)&Al[ad] = al4;
            *(short4v*)&Wh[ad] = wh4; *(short4v*)&Wl[ad] = wl4;
        }
        __syncthreads();
        short8 ah[4], alo[4], bh[4], bl[4];
        #pragma unroll
        for (int f = 0; f < 4; ++f) {
            const int ra = wr * 64 + f * 16 + fr;
            const int ao = ra * 32 + ((kg ^ ((ra >> 1) & 3)) * 8);
            ah[f]  = *(const short8*)&Ah[ao];
            alo[f] = *(const short8*)&Al[ao];
            const int rb = wc * 64 + f * 16 + fr;
            const int bo = rb * 32 + ((kg ^ ((rb >> 1) & 3)) * 8);
            bh[f] = *(const short8*)&Wh[bo];
            bl[f] = *(const short8*)&Wl[bo];
        }
        #pragma unroll
        for (int fi = 0; fi < 4; ++fi)
            #pragma unroll
            for (int fj = 0; fj < 4; ++fj) {
                mfma16(acc[fi][fj], ah[fi], bh[fj]);
                mfma16(acc[fi][fj], ah[fi], bl[fj]);
                mfma16(acc[fi][fj], alo[fi], bh[fj]);
            }
        __syncthreads();
    }
    #pragma unroll
    for (int fi = 0; fi < 4; ++fi) {
        const int m0 = bm + wr * 64 + fi * 16 + kg * 4;
        #pragma unroll
        for (int fj = 0; fj < 4; ++fj) {
            const int n = bn + wc * 64 + fj * 16 + fr;
            const float bb = bias[n];
            #pragma unroll
            for (int q = 0; q < 4; ++q) {
                float v = acc[fi][fj][q] + bb;
                v = (v > 20.f) ? v : log1pf(__expf(v));
                C[(size_t)(m0 + q) * NXZ + n] = v;
            }
        }
    }
}

// ---------------------------------------------------------------------------
// delta (fast): all operands pre-split bf16; single stage via gload, K=64.
__global__ __launch_bounds__(256) void gemm_delta_pre(
    const unsigned short* __restrict__ Ahg, const unsigned short* __restrict__ Alg,
    const unsigned short* __restrict__ Whg, const unsigned short* __restrict__ Wlg,
    float* __restrict__ C, const float* __restrict__ bias)
{
    __shared__ unsigned short sAh[128 * 64], sAl[128 * 64];
    __shared__ unsigned short sWh[128 * 64], sWl[128 * 64];
    const int tid = threadIdx.x;
    const int bm = blockIdx.y * 128;
    const int bn = blockIdx.x * 128;
    const int wv = tid >> 6, ln = tid & 63;
    const int wr = wv >> 1, wc = wv & 1;
    const int fr = ln & 15, kg = ln >> 4;
    const int srow = ln >> 3;          // 0..7
    const int g = ln & 7;              // dest col-group (8 elems)
    const int half = g >> 2, sub = g & 3;
    #pragma unroll
    for (int j = 0; j < 4; ++j) {
        const int row = wv * 32 + j * 8 + srow;
        const int sub2 = sub ^ ((row >> 1) & 3);
        const int scol = half * 32 + sub2 * 8;
        const int dst = (wv * 32 + j * 8) * 64;
        gload16(Ahg + (size_t)(bm + row) * DTR + scol, sAh + dst);
        gload16(Alg + (size_t)(bm + row) * DTR + scol, sAl + dst);
        gload16(Whg + (size_t)(bn + row) * DTR + scol, sWh + dst);
        gload16(Wlg + (size_t)(bn + row) * DTR + scol, sWl + dst);
    }
    __syncthreads();
    f32x4 acc[4][4] = {};
    #pragma unroll
    for (int ks = 0; ks < 2; ++ks) {
        short8 ah[4], alo[4], bh[4], bl[4];
        #pragma unroll
        for (int f = 0; f < 4; ++f) {
            const int ra = wr * 64 + f * 16 + fr;
            const int ao = ra * 64 + ks * 32 + ((kg ^ ((ra >> 1) & 3)) * 8);
            ah[f]  = *(const short8*)&sAh[ao];
            alo[f] = *(const short8*)&sAl[ao];
            const int rb = wc * 64 + f * 16 + fr;
            const int bo = rb * 64 + ks * 32 + ((kg ^ ((rb >> 1) & 3)) * 8);
            bh[f] = *(const short8*)&sWh[bo];
            bl[f] = *(const short8*)&sWl[bo];
        }
        #pragma unroll
        for (int fi = 0; fi < 4; ++fi)
            #pragma unroll
            for (int fj = 0; fj < 4; ++fj) {
                mfma16(acc[fi][fj], ah[fi], bh[fj]);
                mfma16(acc[fi][fj], ah[fi], bl[fj]);
                mfma16(acc[fi][fj], alo[fi], bh[fj]);
            }
    }
    #pragma unroll
    for (int fi = 0; fi < 4; ++fi) {
        const int m0 = bm + wr * 64 + fi * 16 + kg * 4;
        #pragma unroll
        for (int fj = 0; fj < 4; ++fj) {
            const int n = bn + wc * 64 + fj * 16 + fr;
            const float bb = bias[n];
            #pragma unroll
            for (int q = 0; q < 4; ++q) {
                float v = acc[fi][fj][q] + bb;
                v = (v > 20.f) ? v : log1pf(__expf(v));
                C[(size_t)(m0 + q) * NXZ + n] = v;
            }
        }
    }
}

// ---------------------------------------------------------------------------
__global__ __launch_bounds__(256) void conv_silu(
    const float* __restrict__ xz, const float* __restrict__ cw,
    const float* __restrict__ cb, float* __restrict__ xc)
{
    const int g = blockIdx.x * 256 + threadIdx.x;
    const int c4 = g & (DI / 4 - 1);
    const int m = g >> 9;
    const int l = m & (SL - 1);
    const int c = c4 << 2;
    const float4 w0 = *(const float4*)(cw + (size_t)(c + 0) * DCONV);
    const float4 w1 = *(const float4*)(cw + (size_t)(c + 1) * DCONV);
    const float4 w2 = *(const float4*)(cw + (size_t)(c + 2) * DCONV);
    const float4 w3 = *(const float4*)(cw + (size_t)(c + 3) * DCONV);
    float4 acc = *(const float4*)(cb + c);
    #pragma unroll
    for (int j = 0; j < DCONV; ++j) {
        const int lj = l - 3 + j;
        if (lj >= 0) {
            const float4 v = *(const float4*)(xz + (size_t)(m - 3 + j) * NXZ + c);
            acc.x = fmaf(v.x, (&w0.x)[j], acc.x);
            acc.y = fmaf(v.y, (&w1.x)[j], acc.y);
            acc.z = fmaf(v.z, (&w2.x)[j], acc.z);
            acc.w = fmaf(v.w, (&w3.x)[j], acc.w);
        }
    }
    acc.x = acc.x / (1.f + __expf(-acc.x));
    acc.y = acc.y / (1.f + __expf(-acc.y));
    acc.z = acc.z / (1.f + __expf(-acc.z));
    acc.w = acc.w / (1.f + __expf(-acc.w));
    *(float4*)(xc + (size_t)m * DI + c) = acc;
}

// ---------------------------------------------------------------------------
// Selective scan v2 (round-5 version, reverted)
__global__ __launch_bounds__(256) void scan_k(
    const float* u, const float* __restrict__ dbc,
    const float* __restrict__ xz, float* y,
    const float* __restrict__ Alog, const float* __restrict__ Dl)
{
    const int b = blockIdx.y;
    const int c0 = blockIdx.x * 16;
    const int tid = threadIdx.x;
    const int ch = tid >> 4;
    const int s = tid & 15;
    const float Aa = -__expf(Alog[(size_t)(c0 + ch) * DS + s]);
    __shared__ float sdl[16][68];
    __shared__ float sxb[16][68];
    __shared__ float sbc[32][68];
    __shared__ float sp0[64][17];
    __shared__ float sp1[64][17];
    __shared__ float sy[64][16];
    __shared__ float sD[16];
    if (tid < 16) sD[tid] = Dl[c0 + tid];
    __syncthreads();
    float h = 0.f;
    const int row = tid >> 2;
    const int q = (tid & 3) << 2;
    for (int t0b = 0; t0b < SL; t0b += 64) {
        const size_t mb = (size_t)b * SL + t0b;
        const float4 dlv = *(const float4*)(xz + (mb + row) * NXZ + c0 + q);
        const float4 uv  = *(const float4*)(u  + (mb + row) * DI + c0 + q);
        const float4 zv  = *(const float4*)(xz + (mb + row) * NXZ + DI + c0 + q);
        float4 p0, p1;
        #pragma unroll
        for (int j = 0; j < 4; ++j) {
            const float dl = (&dlv.x)[j], uu = (&uv.x)[j], zz = (&zv.x)[j];
            const float w = zz / (1.f + __expf(-zz));
            sdl[q + j][row] = dl;
            sxb[q + j][row] = dl * uu;
            (&p1.x)[j] = w;
            (&p0.x)[j] = uu * sD[q + j] * w;
        }
        *(float4*)&sp0[row][q] = p0;
        *(float4*)&sp1[row][q] = p1;
        #pragma unroll
        for (int p = 0; p < 2; ++p) {
            const int idx = p * 256 + tid;
            const int r2 = idx >> 3, q2 = (idx & 7) << 2;
            const float4 v = *(const float4*)(dbc + (mb + r2) * NDBC + DTR + q2);
            sbc[q2 + 0][r2] = v.x; sbc[q2 + 1][r2] = v.y;
            sbc[q2 + 2][r2] = v.z; sbc[q2 + 3][r2] = v.w;
        }
        __syncthreads();
        for (int it = 0; it < 16; ++it) {
            const int t0 = it * 4;
            const float4 dl4 = *(const float4*)&sdl[ch][t0];
            const float4 xb4 = *(const float4*)&sxb[ch][t0];
            const float4 B4  = *(const float4*)&sbc[s][t0];
            const float4 C4  = *(const float4*)&sbc[16 + s][t0];
            float py0, py1, py2, py3;
            {
                const float dA = __expf(dl4.x * Aa);
                h = fmaf(dA, h, xb4.x * B4.x);
                float p = h * C4.x;
                p = dpp_radd<0xB1>(p);  p = dpp_radd<0x4E>(p);
                p = dpp_radd<0x124>(p); p = dpp_radd<0x128>(p);
                py0 = p;
            }
            {
                const float dA = __expf(dl4.y * Aa);
                h = fmaf(dA, h, xb4.y * B4.y);
                float p = h * C4.y;
                p = dpp_radd<0xB1>(p);  p = dpp_radd<0x4E>(p);
                p = dpp_radd<0x124>(p); p = dpp_radd<0x128>(p);
                py1 = p;
            }
            {
                const float dA = __expf(dl4.z * Aa);
                h = fmaf(dA, h, xb4.z * B4.z);
                float p = h * C4.z;
                p = dpp_radd<0xB1>(p);  p = dpp_radd<0x4E>(p);
                p = dpp_radd<0x124>(p); p = dpp_radd<0x128>(p);
                py2 = p;
            }
            {
                const float dA = __expf(dl4.w * Aa);
                h = fmaf(dA, h, xb4.w * B4.w);
                float p = h * C4.w;
                p = dpp_radd<0xB1>(p);  p = dpp_radd<0x4E>(p);
                p = dpp_radd<0x124>(p); p = dpp_radd<0x128>(p);
                py3 = p;
            }
            if (s < 4) {
                const int t = t0 + s;
                const float lo_ = (s & 1) ? py1 : py0;
                const float hi_ = (s & 1) ? py3 : py2;
                const float pysel = (s & 2) ? hi_ : lo_;
                sy[t][ch] = fmaf(pysel, sp1[t][ch], sp0[t][ch]);
            }
        }
        __syncthreads();
        *(float4*)(y + (mb + row) * DI + c0 + q) = *(const float4*)&sy[row][q];
        __syncthreads();
    }
}

// ---------------------------------------------------------------------------
extern "C" void kernel_launch(void* const* d_in, const int* in_sizes, int n_in,
                              void* d_out, int out_size, void* d_ws, size_t ws_size,
                              hipStream_t stream)
{
    const float* x0   = (const float*)d_in[0];
    const float* in_w = (const float*)d_in[1];
    const float* cw   = (const float*)d_in[2];
    const float* cb   = (const float*)d_in[3];
    const float* xpw  = (const float*)d_in[4];
    const float* dtw  = (const float*)d_in[5];
    const float* dtb  = (const float*)d_in[6];
    const float* Alog = (const float*)d_in[7];
    const float* Dp   = (const float*)d_in[8];
    const float* ow   = (const float*)d_in[9];

    const size_t perB = (size_t)SL * (NXZ + DI + NDBC) * sizeof(float); // ~51.1MB
    const size_t wby  = ((size_t)NXZ * DIMK + (size_t)DIMK * DI) * 2;   // 12.6MB
    int nbc = 0, fast = 0;
    if (ws_size >= 4 * perB + wby)      { nbc = 4; fast = 1; }
    else if (ws_size >= 2 * perB + wby) { nbc = 2; fast = 1; }
    else if (ws_size >= perB + wby)     { nbc = 1; fast = 1; }
    else if (ws_size >= 4 * perB)       { nbc = 4; }
    else if (ws_size >= 2 * perB)       { nbc = 2; }
    else if (ws_size >= perB)           { nbc = 1; }
    else return;
    const int nchunks = NB / nbc;
    const int M = nbc * SL;
    // delta fast path needs: dtwh/l (DI*DTR each) + dth/l (M*DTR each), bf16
    const size_t dtby = ((size_t)DI * DTR * 2 + (size_t)M * DTR * 2) * 2;
    const int fastd = fast && (ws_size >= (size_t)nbc * perB + wby + dtby);

    float* xz  = (float*)d_ws;                 // [M, NXZ]; xi half reused as delta
    float* xc  = xz + (size_t)M * NXZ;         // [M, DI];  reused as y
    float* dbc = xc + (size_t)M * DI;          // [M, NDBC]
    unsigned short* wi16 = (unsigned short*)(dbc + (size_t)M * NDBC);
    unsigned short* ow16 = wi16 + (size_t)NXZ * DIMK;
    unsigned short* dtwh = ow16 + (size_t)DIMK * DI;
    unsigned short* dtwl = dtwh + (size_t)DI * DTR;
    unsigned short* dth  = dtwl + (size_t)DI * DTR;
    unsigned short* dtl  = dth + (size_t)M * DTR;

    unsigned short* xb16 = (unsigned short*)d_out + (size_t)MT * DIMK;
    float* xbuf = (float*)d_out;

    const dim3 blk(256);
    if (fast) {
        const int n4x = MT * DIMK / 4;
        cvt_bf16<<<dim3(n4x / 256), blk, 0, stream>>>(x0, xb16, n4x);
    }
    for (int ly = 0; ly < NDEPTH; ++ly) {
        const float* Wi   = in_w + (size_t)ly * NXZ * DIMK;
        const float* cwl  = cw   + (size_t)ly * DI * DCONV;
        const float* cbl  = cb   + (size_t)ly * DI;
        const float* xpl  = xpw  + (size_t)ly * NDBC * DI;
        const float* dtwl_ = dtw + (size_t)ly * DI * DTR;
        const float* dtbl = dtb  + (size_t)ly * DI;
        const float* Al   = Alog + (size_t)ly * DI * DS;
        const float* Dl   = Dp   + (size_t)ly * DI;
        const float* owl  = ow   + (size_t)ly * DIMK * DI;

        if (fast) {
            const int n4w = NXZ * DIMK / 4;
            cvt_bf16<<<dim3(n4w / 256), blk, 0, stream>>>(Wi, wi16, n4w);
            const int n4o = DIMK * DI / 4;
            cvt_bf16<<<dim3(n4o / 256), blk, 0, stream>>>(owl, ow16, n4o);
        }
        if (fastd) {
            const int nel = DI * DTR;
            cvt_split<<<dim3((nel + 255) / 256), blk, 0, stream>>>(
                dtwl_, dtwh, dtwl, nel);
        }

        for (int ck = 0; ck < nchunks; ++ck) {
            if (fast) {
                const unsigned short* xin16 = xb16 + (size_t)ck * M * DIMK;
                gemm_bb<<<dim3(NXZ / 128, M / 128), blk, 0, stream>>>(
                    xin16, wi16, xz, DIMK, DIMK, DIMK, NXZ);
            } else {
                const float* xin = (ly == 0 ? x0 : xbuf) + (size_t)ck * M * DIMK;
                gemm_mfma<<<dim3(NXZ / 128, M / 128), blk, 0, stream>>>(
                    xin, Wi, xz, DIMK, DIMK, NXZ);
            }
            conv_silu<<<dim3(M * (DI / 4) / 256), blk, 0, stream>>>(xz, cwl, cbl, xc);
            if (fastd) {
                gemm_xproj<1><<<dim3(3, M / 128), blk, 0, stream>>>(
                    xc, xpl, dbc, DI, DI, dth, dtl);
                gemm_delta_pre<<<dim3(DI / 128, M / 128), blk, 0, stream>>>(
                    dth, dtl, dtwh, dtwl, xz, dtbl);
            } else {
                gemm_xproj<0><<<dim3(3, M / 128), blk, 0, stream>>>(
                    xc, xpl, dbc, DI, DI, nullptr, nullptr);
                gemm_delta<<<dim3(DI / 128, M / 128), blk, 0, stream>>>(
                    dbc, dtwl_, xz, dtbl);
            }
            scan_k<<<dim3(DI / 16, nbc), blk, 0, stream>>>(
                xc, dbc, xz, xc, Al, Dl);
            if (fast) {
                if (ly < NDEPTH - 1) {
                    gemm_fb<1><<<dim3(DIMK / 128, M / 128), blk, 0, stream>>>(
                        xc, ow16, xb16 + (size_t)ck * M * DIMK, DI, DI, DI, DIMK);
                } else {
                    gemm_fb<0><<<dim3(DIMK / 128, M / 128), blk, 0, stream>>>(
                        xc, ow16, (float*)d_out + (size_t)ck * M * DIMK,
                        DI, DI, DI, DIMK);
                }
            } else {
                float* xdst = (ly == NDEPTH - 1 ? (float*)d_out : xbuf) +
                              (size_t)ck * M * DIMK;
                gemm_mfma<<<dim3(DIMK / 128, M / 128), blk, 0, stream>>>(
                    xc, owl, xdst, DI, DI, DIMK);
            }
        }
    }
}

// Round 8
// 1994.018 us; speedup vs baseline: 1.2153x; 1.1349x over previous
//
#include <hip/hip_runtime.h>
#include <hip/hip_bf16.h>
#include <math.h>

#define DIMK 1024
#define NDEPTH 4
#define DS 16
#define DCONV 4
#define DI 2048
#define DTR 64
#define NB 4
#define SL 2048
#define MT (NB * SL)        // 8192
#define NXZ (2 * DI)        // 4096
#define NDBC (DTR + 2 * DS) // 96

typedef float f32x4 __attribute__((ext_vector_type(4)));
typedef short short8 __attribute__((ext_vector_type(8)));
typedef short short4v __attribute__((ext_vector_type(4)));

__device__ inline unsigned short f2bf(float f) {
    unsigned u = __builtin_bit_cast(unsigned, f);
    unsigned r = (u + 0x7FFFu + ((u >> 16) & 1u)) >> 16;
    return (unsigned short)r;
}
__device__ inline float bf2f(unsigned short h) {
    unsigned u = ((unsigned)h) << 16;
    return __builtin_bit_cast(float, u);
}
__device__ inline void split_bf(float f, unsigned short& hi, unsigned short& lo) {
    hi = f2bf(f);
    lo = f2bf(f - bf2f(hi));
}
__device__ inline unsigned short cvt1(float f) {
    __hip_bfloat16 t = __float2bfloat16(f);
    return __builtin_bit_cast(unsigned short, t);
}
__device__ inline void mfma16(f32x4& d, short8 a, short8 b) {
    asm volatile("v_mfma_f32_16x16x32_bf16 %0, %1, %2, %0"
                 : "+v"(d) : "v"(a), "v"(b));
}
// 16-lane sum via single-inst DPP adds (VALU pipe). All lanes get the sum.
__device__ __forceinline__ float dpp_sum16(float p) {
    asm("v_add_f32_dpp %0, %0, %0 quad_perm:[1,0,3,2] row_mask:0xf bank_mask:0xf bound_ctrl:0" : "+v"(p));
    asm("v_add_f32_dpp %0, %0, %0 quad_perm:[2,3,0,1] row_mask:0xf bank_mask:0xf bound_ctrl:0" : "+v"(p));
    asm("v_add_f32_dpp %0, %0, %0 row_ror:4 row_mask:0xf bank_mask:0xf bound_ctrl:0" : "+v"(p));
    asm("v_add_f32_dpp %0, %0, %0 row_ror:8 row_mask:0xf bank_mask:0xf bound_ctrl:0" : "+v"(p));
    return p;
}
__device__ __forceinline__ float exp2_raw(float x) {
    float r;
    asm("v_exp_f32 %0, %1" : "=v"(r) : "v"(x));
    return r;
}
__device__ __forceinline__ void gload16(const unsigned short* g, unsigned short* l) {
    __builtin_amdgcn_global_load_lds(
        (const __attribute__((address_space(1))) unsigned int*)(g),
        (__attribute__((address_space(3))) unsigned int*)(l),
        16, 0, 0);
}

// ---------------------------------------------------------------------------
__global__ __launch_bounds__(256) void cvt_bf16(
    const float* __restrict__ s, unsigned short* __restrict__ d, int n4)
{
    const int g = blockIdx.x * 256 + threadIdx.x;
    if (g < n4) {
        const float4 f = *(const float4*)(s + (size_t)g * 4);
        short4v v;
        v[0] = (short)cvt1(f.x); v[1] = (short)cvt1(f.y);
        v[2] = (short)cvt1(f.z); v[3] = (short)cvt1(f.w);
        *(short4v*)(d + (size_t)g * 4) = v;
    }
}

__global__ __launch_bounds__(256) void cvt_split(
    const float* __restrict__ s, unsigned short* __restrict__ dh,
    unsigned short* __restrict__ dl, int n)
{
    const int i = blockIdx.x * 256 + threadIdx.x;
    if (i < n) {
        unsigned short h, l;
        split_bf(s[i], h, l);
        dh[i] = h; dl[i] = l;
    }
}

// ---------------------------------------------------------------------------
// C[m,n] = sum_k A[m,k]*B[n,k]; A,B bf16 global. 2-phase dbuf + XCD swizzle.
__global__ __launch_bounds__(256) void gemm_bb(
    const unsigned short* __restrict__ A, const unsigned short* __restrict__ B,
    float* __restrict__ C, int K, int lda, int ldb, int ldc)
{
    __shared__ unsigned short As[2][128 * 32];
    __shared__ unsigned short Bs[2][128 * 32];
    int id = blockIdx.y * gridDim.x + blockIdx.x;
    const int qq = (gridDim.x * gridDim.y) >> 3;
    id = (id & 7) * qq + (id >> 3);
    const int bm = (id / gridDim.x) * 128, bn = (id % gridDim.x) * 128;

    const int tid = threadIdx.x;
    const int wv = tid >> 6, ln = tid & 63;
    const int wr = wv >> 1, wc = wv & 1;
    const int fr = ln & 15, kg = ln >> 4;
    const int sr0 = wv * 32 + (ln >> 2);
    const int sr1 = sr0 + 16;
    const int sl = ln & 3;
    const int cg0 = sl ^ ((sr0 >> 1) & 3);
    const int cg1 = sl ^ ((sr1 >> 1) & 3);
    const unsigned short* pa0 = A + (size_t)(bm + sr0) * lda + cg0 * 8;
    const unsigned short* pa1 = A + (size_t)(bm + sr1) * lda + cg1 * 8;
    const unsigned short* pb0 = B + (size_t)(bn + sr0) * ldb + cg0 * 8;
    const unsigned short* pb1 = B + (size_t)(bn + sr1) * ldb + cg1 * 8;
    const int ldst0 = (wv * 32 + 0) * 32;
    const int ldst1 = (wv * 32 + 16) * 32;
    int offA[4], offB[4];
    #pragma unroll
    for (int f = 0; f < 4; ++f) {
        const int ra = wr * 64 + f * 16 + fr;
        offA[f] = ra * 32 + ((kg ^ ((ra >> 1) & 3)) * 8);
        const int rb = wc * 64 + f * 16 + fr;
        offB[f] = rb * 32 + ((kg ^ ((rb >> 1) & 3)) * 8);
    }
    f32x4 acc[4][4] = {};
    gload16(pa0, &As[0][ldst0]);
    gload16(pa1, &As[0][ldst1]);
    gload16(pb0, &Bs[0][ldst0]);
    gload16(pb1, &Bs[0][ldst1]);
    __syncthreads();
    int cur = 0;
    for (int k0 = 0; k0 < K; k0 += 32) {
        const int nxt = cur ^ 1;
        if (k0 + 32 < K) {
            gload16(pa0 + k0 + 32, &As[nxt][ldst0]);
            gload16(pa1 + k0 + 32, &As[nxt][ldst1]);
            gload16(pb0 + k0 + 32, &Bs[nxt][ldst0]);
            gload16(pb1 + k0 + 32, &Bs[nxt][ldst1]);
        }
        short8 af[4], bw[4];
        #pragma unroll
        for (int f = 0; f < 4; ++f) {
            af[f] = *(const short8*)&As[cur][offA[f]];
            bw[f] = *(const short8*)&Bs[cur][offB[f]];
        }
        #pragma unroll
        for (int fi = 0; fi < 4; ++fi)
            #pragma unroll
            for (int fj = 0; fj < 4; ++fj)
                mfma16(acc[fi][fj], af[fi], bw[fj]);
        __syncthreads();
        cur = nxt;
    }
    #pragma unroll
    for (int fi = 0; fi < 4; ++fi) {
        const int m0 = bm + wr * 64 + fi * 16 + kg * 4;
        #pragma unroll
        for (int fj = 0; fj < 4; ++fj) {
            const int n = bn + wc * 64 + fj * 16 + fr;
            #pragma unroll
            for (int q = 0; q < 4; ++q)
                C[(size_t)(m0 + q) * ldc + n] = acc[fi][fj][q];
        }
    }
}

// ---------------------------------------------------------------------------
// A fp32 (reg prefetch + cvt after MFMA), B bf16 (gload dbuf). CBF: bf16 C.
template <int CBF>
__global__ __launch_bounds__(256) void gemm_fb(
    const float* __restrict__ A, const unsigned short* __restrict__ B,
    void* __restrict__ Cv, int K, int lda, int ldb, int ldc)
{
    __shared__ unsigned short As[2][128 * 32];
    __shared__ unsigned short Bs[2][128 * 32];
    int id = blockIdx.y * gridDim.x + blockIdx.x;
    const int qq = (gridDim.x * gridDim.y) >> 3;
    id = (id & 7) * qq + (id >> 3);
    const int bm = (id / gridDim.x) * 128, bn = (id % gridDim.x) * 128;

    const int tid = threadIdx.x;
    const int wv = tid >> 6, ln = tid & 63;
    const int wr = wv >> 1, wc = wv & 1;
    const int fr = ln & 15, kg = ln >> 4;
    const int r = tid >> 1, hf = tid & 1;
    const int sr0 = wv * 32 + (ln >> 2);
    const int sr1 = sr0 + 16;
    const int sl = ln & 3;
    const int cg0 = sl ^ ((sr0 >> 1) & 3);
    const int cg1 = sl ^ ((sr1 >> 1) & 3);
    const unsigned short* pb0 = B + (size_t)(bn + sr0) * ldb + cg0 * 8;
    const unsigned short* pb1 = B + (size_t)(bn + sr1) * ldb + cg1 * 8;
    const int ldst0 = (wv * 32 + 0) * 32;
    const int ldst1 = (wv * 32 + 16) * 32;
    const float* ga = A + (size_t)(bm + r) * lda + hf * 16;
    const int pk0 = (2 * hf + 0) ^ ((r >> 1) & 3);
    const int pk1 = (2 * hf + 1) ^ ((r >> 1) & 3);
    int offA[4], offB[4];
    #pragma unroll
    for (int f = 0; f < 4; ++f) {
        const int ra = wr * 64 + f * 16 + fr;
        offA[f] = ra * 32 + ((kg ^ ((ra >> 1) & 3)) * 8);
        const int rb = wc * 64 + f * 16 + fr;
        offB[f] = rb * 32 + ((kg ^ ((rb >> 1) & 3)) * 8);
    }
    f32x4 acc[4][4] = {};
    {
        float4 f0 = *(const float4*)(ga + 0);
        float4 f1 = *(const float4*)(ga + 4);
        float4 f2 = *(const float4*)(ga + 8);
        float4 f3 = *(const float4*)(ga + 12);
        short8 v;
        v[0] = (short)cvt1(f0.x); v[1] = (short)cvt1(f0.y);
        v[2] = (short)cvt1(f0.z); v[3] = (short)cvt1(f0.w);
        v[4] = (short)cvt1(f1.x); v[5] = (short)cvt1(f1.y);
        v[6] = (short)cvt1(f1.z); v[7] = (short)cvt1(f1.w);
        *(short8*)&As[0][r * 32 + pk0 * 8] = v;
        v[0] = (short)cvt1(f2.x); v[1] = (short)cvt1(f2.y);
        v[2] = (short)cvt1(f2.z); v[3] = (short)cvt1(f2.w);
        v[4] = (short)cvt1(f3.x); v[5] = (short)cvt1(f3.y);
        v[6] = (short)cvt1(f3.z); v[7] = (short)cvt1(f3.w);
        *(short8*)&As[0][r * 32 + pk1 * 8] = v;
        gload16(pb0, &Bs[0][ldst0]);
        gload16(pb1, &Bs[0][ldst1]);
    }
    __syncthreads();
    int cur = 0;
    for (int k0 = 0; k0 < K; k0 += 32) {
        const int nxt = cur ^ 1;
        const bool more = (k0 + 32 < K);
        float4 f0, f1, f2, f3;
        if (more) {
            gload16(pb0 + k0 + 32, &Bs[nxt][ldst0]);
            gload16(pb1 + k0 + 32, &Bs[nxt][ldst1]);
            f0 = *(const float4*)(ga + k0 + 32);
            f1 = *(const float4*)(ga + k0 + 36);
            f2 = *(const float4*)(ga + k0 + 40);
            f3 = *(const float4*)(ga + k0 + 44);
        }
        short8 af[4], bw[4];
        #pragma unroll
        for (int f = 0; f < 4; ++f) {
            af[f] = *(const short8*)&As[cur][offA[f]];
            bw[f] = *(const short8*)&Bs[cur][offB[f]];
        }
        #pragma unroll
        for (int fi = 0; fi < 4; ++fi)
            #pragma unroll
            for (int fj = 0; fj < 4; ++fj)
                mfma16(acc[fi][fj], af[fi], bw[fj]);
        if (more) {
            short8 v;
            v[0] = (short)cvt1(f0.x); v[1] = (short)cvt1(f0.y);
            v[2] = (short)cvt1(f0.z); v[3] = (short)cvt1(f0.w);
            v[4] = (short)cvt1(f1.x); v[5] = (short)cvt1(f1.y);
            v[6] = (short)cvt1(f1.z); v[7] = (short)cvt1(f1.w);
            *(short8*)&As[nxt][r * 32 + pk0 * 8] = v;
            v[0] = (short)cvt1(f2.x); v[1] = (short)cvt1(f2.y);
            v[2] = (short)cvt1(f2.z); v[3] = (short)cvt1(f2.w);
            v[4] = (short)cvt1(f3.x); v[5] = (short)cvt1(f3.y);
            v[6] = (short)cvt1(f3.z); v[7] = (short)cvt1(f3.w);
            *(short8*)&As[nxt][r * 32 + pk1 * 8] = v;
        }
        __syncthreads();
        cur = nxt;
    }
    #pragma unroll
    for (int fi = 0; fi < 4; ++fi) {
        const int m0 = bm + wr * 64 + fi * 16 + kg * 4;
        #pragma unroll
        for (int fj = 0; fj < 4; ++fj) {
            const int n = bn + wc * 64 + fj * 16 + fr;
            #pragma unroll
            for (int q = 0; q < 4; ++q) {
                if (CBF) {
                    unsigned short* Cs = (unsigned short*)Cv;
                    Cs[(size_t)(m0 + q) * ldc + n] = cvt1(acc[fi][fj][q]);
                } else {
                    float* Cf = (float*)Cv;
                    Cf[(size_t)(m0 + q) * ldc + n] = acc[fi][fj][q];
                }
            }
        }
    }
}

// ---------------------------------------------------------------------------
// fallback GEMM (fp32 in/out), used only if ws too small
__global__ __launch_bounds__(256) void gemm_mfma(
    const float* __restrict__ A, const float* __restrict__ W,
    float* __restrict__ C, int K, int lda, int ldc)
{
    __shared__ unsigned short As[128 * 32];
    __shared__ unsigned short Ws[128 * 32];
    const int tid = threadIdx.x;
    const int bm = blockIdx.y * 128;
    const int bn = blockIdx.x * 128;
    const int r = tid >> 1;
    const int h = tid & 1;
    const int wv = tid >> 6;
    const int wr = wv >> 1;
    const int wc = wv & 1;
    const int ln = tid & 63;
    const int fr = ln & 15;
    const int kg = ln >> 4;
    f32x4 acc[4][4] = {};
    const float* ga = A + (size_t)(bm + r) * lda + h * 16;
    const float* gw = W + (size_t)(bn + r) * K + h * 16;
    for (int k0 = 0; k0 < K; k0 += 32) {
        #pragma unroll
        for (int p = 0; p < 2; ++p) {
            const int pk = (2 * h + p) ^ ((r >> 1) & 3);
            float4 f0 = *(const float4*)(ga + k0 + p * 8);
            float4 f1 = *(const float4*)(ga + k0 + p * 8 + 4);
            short8 v;
            v[0] = (short)cvt1(f0.x); v[1] = (short)cvt1(f0.y);
            v[2] = (short)cvt1(f0.z); v[3] = (short)cvt1(f0.w);
            v[4] = (short)cvt1(f1.x); v[5] = (short)cvt1(f1.y);
            v[6] = (short)cvt1(f1.z); v[7] = (short)cvt1(f1.w);
            *(short8*)&As[r * 32 + pk * 8] = v;
            f0 = *(const float4*)(gw + k0 + p * 8);
            f1 = *(const float4*)(gw + k0 + p * 8 + 4);
            v[0] = (short)cvt1(f0.x); v[1] = (short)cvt1(f0.y);
            v[2] = (short)cvt1(f0.z); v[3] = (short)cvt1(f0.w);
            v[4] = (short)cvt1(f1.x); v[5] = (short)cvt1(f1.y);
            v[6] = (short)cvt1(f1.z); v[7] = (short)cvt1(f1.w);
            *(short8*)&Ws[r * 32 + pk * 8] = v;
        }
        __syncthreads();
        short8 af[4], bw[4];
        #pragma unroll
        for (int f = 0; f < 4; ++f) {
            const int ra = wr * 64 + f * 16 + fr;
            af[f] = *(const short8*)&As[ra * 32 + ((kg ^ ((ra >> 1) & 3)) * 8)];
            const int rb = wc * 64 + f * 16 + fr;
            bw[f] = *(const short8*)&Ws[rb * 32 + ((kg ^ ((rb >> 1) & 3)) * 8)];
        }
        #pragma unroll
        for (int fi = 0; fi < 4; ++fi)
            #pragma unroll
            for (int fj = 0; fj < 4; ++fj)
                mfma16(acc[fi][fj], af[fi], bw[fj]);
        __syncthreads();
    }
    #pragma unroll
    for (int fi = 0; fi < 4; ++fi) {
        const int m0 = bm + wr * 64 + fi * 16 + kg * 4;
        #pragma unroll
        for (int fj = 0; fj < 4; ++fj) {
            const int n = bn + wc * 64 + fj * 16 + fr;
            #pragma unroll
            for (int q = 0; q < 4; ++q)
                C[(size_t)(m0 + q) * ldc + n] = acc[fi][fj][q];
        }
    }
}

// ---------------------------------------------------------------------------
// dbc = xc @ xp^T, hi/lo-split bf16 MFMA. BM=128, BN=32.
template <int WRDT>
__global__ __launch_bounds__(256) void gemm_xproj(
    const float* __restrict__ A, const float* __restrict__ W,
    float* __restrict__ C, int K, int lda,
    unsigned short* __restrict__ dth, unsigned short* __restrict__ dtl)
{
    __shared__ unsigned short Ah[128 * 32], Al[128 * 32];
    __shared__ unsigned short Wh[32 * 32], Wl[32 * 32];
    const int tid = threadIdx.x;
    const int bm = blockIdx.y * 128;
    const int bn = blockIdx.x * 32;
    const int r = tid >> 1, hf = tid & 1;
    const int wv = tid >> 6;
    const int ln = tid & 63, fr = ln & 15, kg = ln >> 4;
    const int wsr = tid >> 3;
    const int wc4 = (tid & 7) << 2;
    f32x4 acc[2][2] = {};
    const float* ga = A + (size_t)(bm + r) * lda + hf * 16;
    const float* gw = W + (size_t)(bn + wsr) * K + wc4;
    for (int k0 = 0; k0 < K; k0 += 32) {
        #pragma unroll
        for (int j = 0; j < 4; ++j) {
            const int col = hf * 16 + j * 4;
            const int ad = r * 32 + (((col >> 3) ^ ((r >> 1) & 3)) << 3) + (col & 7);
            const float4 fa = *(const float4*)(ga + k0 + j * 4);
            short4v h4, l4;
            #pragma unroll
            for (int e = 0; e < 4; ++e) {
                unsigned short hh, llo;
                split_bf((&fa.x)[e], hh, llo);
                h4[e] = (short)hh; l4[e] = (short)llo;
            }
            *(short4v*)&Ah[ad] = h4;
            *(short4v*)&Al[ad] = l4;
        }
        {
            const int ad = wsr * 32 + (((wc4 >> 3) ^ ((wsr >> 1) & 3)) << 3) + (wc4 & 7);
            const float4 fw = *(const float4*)(gw + k0);
            short4v h4, l4;
            #pragma unroll
            for (int e = 0; e < 4; ++e) {
                unsigned short hh, llo;
                split_bf((&fw.x)[e], hh, llo);
                h4[e] = (short)hh; l4[e] = (short)llo;
            }
            *(short4v*)&Wh[ad] = h4;
            *(short4v*)&Wl[ad] = l4;
        }
        __syncthreads();
        short8 ah[2], alo[2], bh[2], bl[2];
        #pragma unroll
        for (int f = 0; f < 2; ++f) {
            const int ra = wv * 32 + f * 16 + fr;
            const int ao = ra * 32 + ((kg ^ ((ra >> 1) & 3)) * 8);
            ah[f]  = *(const short8*)&Ah[ao];
            alo[f] = *(const short8*)&Al[ao];
            const int rb = f * 16 + fr;
            const int bo = rb * 32 + ((kg ^ ((rb >> 1) & 3)) * 8);
            bh[f] = *(const short8*)&Wh[bo];
            bl[f] = *(const short8*)&Wl[bo];
        }
        #pragma unroll
        for (int fi = 0; fi < 2; ++fi)
            #pragma unroll
            for (int fj = 0; fj < 2; ++fj) {
                mfma16(acc[fi][fj], ah[fi], bh[fj]);
                mfma16(acc[fi][fj], ah[fi], bl[fj]);
                mfma16(acc[fi][fj], alo[fi], bh[fj]);
            }
        __syncthreads();
    }
    #pragma unroll
    for (int fi = 0; fi < 2; ++fi) {
        const int m0 = bm + wv * 32 + fi * 16 + kg * 4;
        #pragma unroll
        for (int fj = 0; fj < 2; ++fj) {
            const int n = bn + fj * 16 + fr;
            #pragma unroll
            for (int q = 0; q < 4; ++q) {
                const float v = acc[fi][fj][q];
                C[(size_t)(m0 + q) * NDBC + n] = v;
                if (WRDT && n < DTR) {
                    unsigned short hh, llo;
                    split_bf(v, hh, llo);
                    dth[(size_t)(m0 + q) * DTR + n] = hh;
                    dtl[(size_t)(m0 + q) * DTR + n] = llo;
                }
            }
        }
    }
}

// ---------------------------------------------------------------------------
// delta (fallback): split in-kernel from fp32 dbc/dtw. K=64.
__global__ __launch_bounds__(256) void gemm_delta(
    const float* __restrict__ A, const float* __restrict__ W,
    float* __restrict__ C, const float* __restrict__ bias)
{
    __shared__ unsigned short Ah[128 * 32], Al[128 * 32];
    __shared__ unsigned short Wh[128 * 32], Wl[128 * 32];
    const int tid = threadIdx.x;
    const int bm = blockIdx.y * 128;
    const int bn = blockIdx.x * 128;
    const int r = tid >> 1, hf = tid & 1;
    const int wv = tid >> 6, wr = wv >> 1, wc = wv & 1;
    const int ln = tid & 63, fr = ln & 15, kg = ln >> 4;
    f32x4 acc[4][4] = {};
    const float* ga = A + (size_t)(bm + r) * NDBC + hf * 16;
    const float* gw = W + (size_t)(bn + r) * DTR + hf * 16;
    for (int k0 = 0; k0 < DTR; k0 += 32) {
        #pragma unroll
        for (int j = 0; j < 4; ++j) {
            const int col = hf * 16 + j * 4;
            const int ad = r * 32 + (((col >> 3) ^ ((r >> 1) & 3)) << 3) + (col & 7);
            const float4 fa = *(const float4*)(ga + k0 + j * 4);
            const float4 fw = *(const float4*)(gw + k0 + j * 4);
            short4v ah4, al4, wh4, wl4;
            #pragma unroll
            for (int e = 0; e < 4; ++e) {
                unsigned short hh, llo;
                split_bf((&fa.x)[e], hh, llo);
                ah4[e] = (short)hh; al4[e] = (short)llo;
                split_bf((&fw.x)[e], hh, llo);
                wh4[e] = (short)hh; wl4[e] = (short)llo;
            }
            *(short4v*)&Ah[ad] = ah4; *(short4v*)&Al[ad] = al4;
            *(short4v*)&Wh[ad] = wh4; *(short4v*)&Wl[ad] = wl4;
        }
        __syncthreads();
        short8 ah[4], alo[4], bh[4], bl[4];
        #pragma unroll
        for (int f = 0; f < 4; ++f) {
            const int ra = wr * 64 + f * 16 + fr;
            const int ao = ra * 32 + ((kg ^ ((ra >> 1) & 3)) * 8);
            ah[f]  = *(const short8*)&Ah[ao];
            alo[f] = *(const short8*)&Al[ao];
            const int rb = wc * 64 + f * 16 + fr;
            const int bo = rb * 32 + ((kg ^ ((rb >> 1) & 3)) * 8);
            bh[f] = *(const short8*)&Wh[bo];
            bl[f] = *(const short8*)&Wl[bo];
        }
        #pragma unroll
        for (int fi = 0; fi < 4; ++fi)
            #pragma unroll
            for (int fj = 0; fj < 4; ++fj) {
                mfma16(acc[fi][fj], ah[fi], bh[fj]);
                mfma16(acc[fi][fj], ah[fi], bl[fj]);
                mfma16(acc[fi][fj], alo[fi], bh[fj]);
            }
        __syncthreads();
    }
    #pragma unroll
    for (int fi = 0; fi < 4; ++fi) {
        const int m0 = bm + wr * 64 + fi * 16 + kg * 4;
        #pragma unroll
        for (int fj = 0; fj < 4; ++fj) {
            const int n = bn + wc * 64 + fj * 16 + fr;
            const float bb = bias[n];
            #pragma unroll
            for (int q = 0; q < 4; ++q) {
                float v = acc[fi][fj][q] + bb;
                v = (v > 20.f) ? v : log1pf(__expf(v));
                C[(size_t)(m0 + q) * NXZ + n] = v;
            }
        }
    }
}

// ---------------------------------------------------------------------------
// delta (fast): all operands pre-split bf16; single stage via gload, K=64.
__global__ __launch_bounds__(256) void gemm_delta_pre(
    const unsigned short* __restrict__ Ahg, const unsigned short* __restrict__ Alg,
    const unsigned short* __restrict__ Whg, const unsigned short* __restrict__ Wlg,
    float* __restrict__ C, const float* __restrict__ bias)
{
    __shared__ unsigned short sAh[128 * 64], sAl[128 * 64];
    __shared__ unsigned short sWh[128 * 64], sWl[128 * 64];
    const int tid = threadIdx.x;
    const int bm = blockIdx.y * 128;
    const int bn = blockIdx.x * 128;
    const int wv = tid >> 6, ln = tid & 63;
    const int wr = wv >> 1, wc = wv & 1;
    const int fr = ln & 15, kg = ln >> 4;
    const int srow = ln >> 3;
    const int g = ln & 7;
    const int half = g >> 2, sub = g & 3;
    #pragma unroll
    for (int j = 0; j < 4; ++j) {
        const int row = wv * 32 + j * 8 + srow;
        const int sub2 = sub ^ ((row >> 1) & 3);
        const int scol = half * 32 + sub2 * 8;
        const int dst = (wv * 32 + j * 8) * 64;
        gload16(Ahg + (size_t)(bm + row) * DTR + scol, sAh + dst);
        gload16(Alg + (size_t)(bm + row) * DTR + scol, sAl + dst);
        gload16(Whg + (size_t)(bn + row) * DTR + scol, sWh + dst);
        gload16(Wlg + (size_t)(bn + row) * DTR + scol, sWl + dst);
    }
    __syncthreads();
    f32x4 acc[4][4] = {};
    #pragma unroll
    for (int ks = 0; ks < 2; ++ks) {
        short8 ah[4], alo[4], bh[4], bl[4];
        #pragma unroll
        for (int f = 0; f < 4; ++f) {
            const int ra = wr * 64 + f * 16 + fr;
            const int ao = ra * 64 + ks * 32 + ((kg ^ ((ra >> 1) & 3)) * 8);
            ah[f]  = *(const short8*)&sAh[ao];
            alo[f] = *(const short8*)&sAl[ao];
            const int rb = wc * 64 + f * 16 + fr;
            const int bo = rb * 64 + ks * 32 + ((kg ^ ((rb >> 1) & 3)) * 8);
            bh[f] = *(const short8*)&sWh[bo];
            bl[f] = *(const short8*)&sWl[bo];
        }
        #pragma unroll
        for (int fi = 0; fi < 4; ++fi)
            #pragma unroll
            for (int fj = 0; fj < 4; ++fj) {
                mfma16(acc[fi][fj], ah[fi], bh[fj]);
                mfma16(acc[fi][fj], ah[fi], bl[fj]);
                mfma16(acc[fi][fj], alo[fi], bh[fj]);
            }
    }
    #pragma unroll
    for (int fi = 0; fi < 4; ++fi) {
        const int m0 = bm + wr * 64 + fi * 16 + kg * 4;
        #pragma unroll
        for (int fj = 0; fj < 4; ++fj) {
            const int n = bn + wc * 64 + fj * 16 + fr;
            const float bb = bias[n];
            #pragma unroll
            for (int q = 0; q < 4; ++q) {
                float v = acc[fi][fj][q] + bb;
                v = (v > 20.f) ? v : log1pf(__expf(v));
                C[(size_t)(m0 + q) * NXZ + n] = v;
            }
        }
    }
}

// ---------------------------------------------------------------------------
// conv+silu: 4 consecutive timesteps per thread (7 row-loads for 4 outputs).
// fma with zeroed out-of-range rows is bit-identical to skipping them.
__global__ __launch_bounds__(256) void conv_silu(
    const float* __restrict__ xz, const float* __restrict__ cw,
    const float* __restrict__ cb, float* __restrict__ xc)
{
    const int g = blockIdx.x * 256 + threadIdx.x;   // 0 .. M*DI/16
    const int c4 = g & (DI / 4 - 1);
    const int mq = g >> 9;
    const int m0 = mq << 2;
    const int l0 = m0 & (SL - 1);
    const int c = c4 << 2;
    const float4 w0 = *(const float4*)(cw + (size_t)(c + 0) * DCONV);
    const float4 w1 = *(const float4*)(cw + (size_t)(c + 1) * DCONV);
    const float4 w2 = *(const float4*)(cw + (size_t)(c + 2) * DCONV);
    const float4 w3 = *(const float4*)(cw + (size_t)(c + 3) * DCONV);
    const float4 cb4 = *(const float4*)(cb + c);
    float4 x[7];
    #pragma unroll
    for (int i = 0; i < 7; ++i) {
        if (l0 - 3 + i >= 0)
            x[i] = *(const float4*)(xz + (size_t)(m0 - 3 + i) * NXZ + c);
        else
            x[i] = make_float4(0.f, 0.f, 0.f, 0.f);
    }
    #pragma unroll
    for (int j = 0; j < 4; ++j) {
        float4 acc = cb4;
        #pragma unroll
        for (int k = 0; k < DCONV; ++k) {
            const float4 v = x[j + k];
            acc.x = fmaf(v.x, (&w0.x)[k], acc.x);
            acc.y = fmaf(v.y, (&w1.x)[k], acc.y);
            acc.z = fmaf(v.z, (&w2.x)[k], acc.z);
            acc.w = fmaf(v.w, (&w3.x)[k], acc.w);
        }
        acc.x = acc.x / (1.f + __expf(-acc.x));
        acc.y = acc.y / (1.f + __expf(-acc.y));
        acc.z = acc.z / (1.f + __expf(-acc.z));
        acc.w = acc.w / (1.f + __expf(-acc.w));
        *(float4*)(xc + (size_t)(m0 + j) * DI + c) = acc;
    }
}

// ---------------------------------------------------------------------------
// Selective scan v2 + single-inst DPP reduce + exp2 with prefolded log2e.
__global__ __launch_bounds__(256) void scan_k(
    const float* u, const float* __restrict__ dbc,
    const float* __restrict__ xz, float* y,
    const float* __restrict__ Alog, const float* __restrict__ Dl)
{
    const int b = blockIdx.y;
    const int c0 = blockIdx.x * 16;
    const int tid = threadIdx.x;
    const int ch = tid >> 4;
    const int s = tid & 15;
    const float Aa = -__expf(Alog[(size_t)(c0 + ch) * DS + s]) * 1.44269504088896f;
    __shared__ float sdl[16][68];
    __shared__ float sxb[16][68];
    __shared__ float sbc[32][68];
    __shared__ float sp0[64][17];
    __shared__ float sp1[64][17];
    __shared__ float sy[64][16];
    __shared__ float sD[16];
    if (tid < 16) sD[tid] = Dl[c0 + tid];
    __syncthreads();
    float h = 0.f;
    const int row = tid >> 2;
    const int q = (tid & 3) << 2;
    for (int t0b = 0; t0b < SL; t0b += 64) {
        const size_t mb = (size_t)b * SL + t0b;
        const float4 dlv = *(const float4*)(xz + (mb + row) * NXZ + c0 + q);
        const float4 uv  = *(const float4*)(u  + (mb + row) * DI + c0 + q);
        const float4 zv  = *(const float4*)(xz + (mb + row) * NXZ + DI + c0 + q);
        float4 p0, p1;
        #pragma unroll
        for (int j = 0; j < 4; ++j) {
            const float dl = (&dlv.x)[j], uu = (&uv.x)[j], zz = (&zv.x)[j];
            const float w = zz / (1.f + __expf(-zz));
            sdl[q + j][row] = dl;
            sxb[q + j][row] = dl * uu;
            (&p1.x)[j] = w;
            (&p0.x)[j] = uu * sD[q + j] * w;
        }
        *(float4*)&sp0[row][q] = p0;
        *(float4*)&sp1[row][q] = p1;
        #pragma unroll
        for (int p = 0; p < 2; ++p) {
            const int idx = p * 256 + tid;
            const int r2 = idx >> 3, q2 = (idx & 7) << 2;
            const float4 v = *(const float4*)(dbc + (mb + r2) * NDBC + DTR + q2);
            sbc[q2 + 0][r2] = v.x; sbc[q2 + 1][r2] = v.y;
            sbc[q2 + 2][r2] = v.z; sbc[q2 + 3][r2] = v.w;
        }
        __syncthreads();
        for (int it = 0; it < 16; ++it) {
            const int t0 = it * 4;
            const float4 dl4 = *(const float4*)&sdl[ch][t0];
            const float4 xb4 = *(const float4*)&sxb[ch][t0];
            const float4 B4  = *(const float4*)&sbc[s][t0];
            const float4 C4  = *(const float4*)&sbc[16 + s][t0];
            float py0, py1, py2, py3;
            {
                const float dA = exp2_raw(dl4.x * Aa);
                h = fmaf(dA, h, xb4.x * B4.x);
                py0 = dpp_sum16(h * C4.x);
            }
            {
                const float dA = exp2_raw(dl4.y * Aa);
                h = fmaf(dA, h, xb4.y * B4.y);
                py1 = dpp_sum16(h * C4.y);
            }
            {
                const float dA = exp2_raw(dl4.z * Aa);
                h = fmaf(dA, h, xb4.z * B4.z);
                py2 = dpp_sum16(h * C4.z);
            }
            {
                const float dA = exp2_raw(dl4.w * Aa);
                h = fmaf(dA, h, xb4.w * B4.w);
                py3 = dpp_sum16(h * C4.w);
            }
            if (s < 4) {
                const int t = t0 + s;
                const float lo_ = (s & 1) ? py1 : py0;
                const float hi_ = (s & 1) ? py3 : py2;
                const float pysel = (s & 2) ? hi_ : lo_;
                sy[t][ch] = fmaf(pysel, sp1[t][ch], sp0[t][ch]);
            }
        }
        __syncthreads();
        *(float4*)(y + (mb + row) * DI + c0 + q) = *(const float4*)&sy[row][q];
        __syncthreads();
    }
}

// ---------------------------------------------------------------------------
extern "C" void kernel_launch(void* const* d_in, const int* in_sizes, int n_in,
                              void* d_out, int out_size, void* d_ws, size_t ws_size,
                              hipStream_t stream)
{
    const float* x0   = (const float*)d_in[0];
    const float* in_w = (const float*)d_in[1];
    const float* cw   = (const float*)d_in[2];
    const float* cb   = (const float*)d_in[3];
    const float* xpw  = (const float*)d_in[4];
    const float* dtw  = (const float*)d_in[5];
    const float* dtb  = (const float*)d_in[6];
    const float* Alog = (const float*)d_in[7];
    const float* Dp   = (const float*)d_in[8];
    const float* ow   = (const float*)d_in[9];

    const size_t perB = (size_t)SL * (NXZ + DI + NDBC) * sizeof(float); // ~51.1MB
    const size_t wby  = ((size_t)NXZ * DIMK + (size_t)DIMK * DI) * 2;   // 12.6MB
    int nbc = 0, fast = 0;
    if (ws_size >= 4 * perB + wby)      { nbc = 4; fast = 1; }
    else if (ws_size >= 2 * perB + wby) { nbc = 2; fast = 1; }
    else if (ws_size >= perB + wby)     { nbc = 1; fast = 1; }
    else if (ws_size >= 4 * perB)       { nbc = 4; }
    else if (ws_size >= 2 * perB)       { nbc = 2; }
    else if (ws_size >= perB)           { nbc = 1; }
    else return;
    const int nchunks = NB / nbc;
    const int M = nbc * SL;
    const size_t dtby = ((size_t)DI * DTR * 2 + (size_t)M * DTR * 2) * 2;
    const int fastd = fast && (ws_size >= (size_t)nbc * perB + wby + dtby);

    float* xz  = (float*)d_ws;
    float* xc  = xz + (size_t)M * NXZ;
    float* dbc = xc + (size_t)M * DI;
    unsigned short* wi16 = (unsigned short*)(dbc + (size_t)M * NDBC);
    unsigned short* ow16 = wi16 + (size_t)NXZ * DIMK;
    unsigned short* dtwh = ow16 + (size_t)DIMK * DI;
    unsigned short* dtwl = dtwh + (size_t)DI * DTR;
    unsigned short* dth  = dtwl + (size_t)DI * DTR;
    unsigned short* dtl  = dth + (size_t)M * DTR;

    unsigned short* xb16 = (unsigned short*)d_out + (size_t)MT * DIMK;
    float* xbuf = (float*)d_out;

    const dim3 blk(256);
    if (fast) {
        const int n4x = MT * DIMK / 4;
        cvt_bf16<<<dim3(n4x / 256), blk, 0, stream>>>(x0, xb16, n4x);
    }
    for (int ly = 0; ly < NDEPTH; ++ly) {
        const float* Wi   = in_w + (size_t)ly * NXZ * DIMK;
        const float* cwl  = cw   + (size_t)ly * DI * DCONV;
        const float* cbl  = cb   + (size_t)ly * DI;
        const float* xpl  = xpw  + (size_t)ly * NDBC * DI;
        const float* dtwl_ = dtw + (size_t)ly * DI * DTR;
        const float* dtbl = dtb  + (size_t)ly * DI;
        const float* Al   = Alog + (size_t)ly * DI * DS;
        const float* Dl   = Dp   + (size_t)ly * DI;
        const float* owl  = ow   + (size_t)ly * DIMK * DI;

        if (fast) {
            const int n4w = NXZ * DIMK / 4;
            cvt_bf16<<<dim3(n4w / 256), blk, 0, stream>>>(Wi, wi16, n4w);
            const int n4o = DIMK * DI / 4;
            cvt_bf16<<<dim3(n4o / 256), blk, 0, stream>>>(owl, ow16, n4o);
        }
        if (fastd) {
            const int nel = DI * DTR;
            cvt_split<<<dim3((nel + 255) / 256), blk, 0, stream>>>(
                dtwl_, dtwh, dtwl, nel);
        }

        for (int ck = 0; ck < nchunks; ++ck) {
            if (fast) {
                const unsigned short* xin16 = xb16 + (size_t)ck * M * DIMK;
                gemm_bb<<<dim3(NXZ / 128, M / 128), blk, 0, stream>>>(
                    xin16, wi16, xz, DIMK, DIMK, DIMK, NXZ);
            } else {
                const float* xin = (ly == 0 ? x0 : xbuf) + (size_t)ck * M * DIMK;
                gemm_mfma<<<dim3(NXZ / 128, M / 128), blk, 0, stream>>>(
                    xin, Wi, xz, DIMK, DIMK, NXZ);
            }
            conv_silu<<<dim3(M * (DI / 16) / 256), blk, 0, stream>>>(xz, cwl, cbl, xc);
            if (fastd) {
                gemm_xproj<1><<<dim3(3, M / 128), blk, 0, stream>>>(
                    xc, xpl, dbc, DI, DI, dth, dtl);
                gemm_delta_pre<<<dim3(DI / 128, M / 128), blk, 0, stream>>>(
                    dth, dtl, dtwh, dtwl, xz, dtbl);
            } else {
                gemm_xproj<0><<<dim3(3, M / 128), blk, 0, stream>>>(
                    xc, xpl, dbc, DI, DI, nullptr, nullptr);
                gemm_delta<<<dim3(DI / 128, M / 128), blk, 0, stream>>>(
                    dbc, dtwl_, xz, dtbl);
            }
            scan_k<<<dim3(DI / 16, nbc), blk, 0, stream>>>(
                xc, dbc, xz, xc, Al, Dl);
            if (fast) {
                if (ly < NDEPTH - 1) {
                    gemm_fb<1><<<dim3(DIMK / 128, M / 128), blk, 0, stream>>>(
                        xc, ow16, xb16 + (size_t)ck * M * DIMK, DI, DI, DI, DIMK);
                } else {
                    gemm_fb<0><<<dim3(DIMK / 128, M / 128), blk, 0, stream>>>(
                        xc, ow16, (float*)d_out + (size_t)ck * M * DIMK,
                        DI, DI, DI, DIMK);
                }
            } else {
                float* xdst = (ly == NDEPTH - 1 ? (float*)d_out : xbuf) +
                              (size_t)ck * M * DIMK;
                gemm_mfma<<<dim3(DIMK / 128, M / 128), blk, 0, stream>>>(
                    xc, owl, xdst, DI, DI, DIMK);
            }
        }
    }
}

// Round 9
// 1989.833 us; speedup vs baseline: 1.2178x; 1.0021x over previous
//
#include <hip/hip_runtime.h>
#include <hip/hip_bf16.h>
#include <math.h>

#define DIMK 1024
#define NDEPTH 4
#define DS 16
#define DCONV 4
#define DI 2048
#define DTR 64
#define NB 4
#define SL 2048
#define MT (NB * SL)        // 8192
#define NXZ (2 * DI)        // 4096
#define NDBC (DTR + 2 * DS) // 96

typedef float f32x4 __attribute__((ext_vector_type(4)));
typedef short short8 __attribute__((ext_vector_type(8)));
typedef short short4v __attribute__((ext_vector_type(4)));

__device__ inline unsigned short f2bf(float f) {
    unsigned u = __builtin_bit_cast(unsigned, f);
    unsigned r = (u + 0x7FFFu + ((u >> 16) & 1u)) >> 16;
    return (unsigned short)r;
}
__device__ inline float bf2f(unsigned short h) {
    unsigned u = ((unsigned)h) << 16;
    return __builtin_bit_cast(float, u);
}
__device__ inline void split_bf(float f, unsigned short& hi, unsigned short& lo) {
    hi = f2bf(f);
    lo = f2bf(f - bf2f(hi));
}
__device__ inline unsigned short cvt1(float f) {
    __hip_bfloat16 t = __float2bfloat16(f);
    return __builtin_bit_cast(unsigned short, t);
}
__device__ inline void mfma16(f32x4& d, short8 a, short8 b) {
    asm volatile("v_mfma_f32_16x16x32_bf16 %0, %1, %2, %0"
                 : "+v"(d) : "v"(a), "v"(b));
}
__device__ __forceinline__ float dpp_sum16(float p) {
    asm("v_add_f32_dpp %0, %0, %0 quad_perm:[1,0,3,2] row_mask:0xf bank_mask:0xf bound_ctrl:0" : "+v"(p));
    asm("v_add_f32_dpp %0, %0, %0 quad_perm:[2,3,0,1] row_mask:0xf bank_mask:0xf bound_ctrl:0" : "+v"(p));
    asm("v_add_f32_dpp %0, %0, %0 row_ror:4 row_mask:0xf bank_mask:0xf bound_ctrl:0" : "+v"(p));
    asm("v_add_f32_dpp %0, %0, %0 row_ror:8 row_mask:0xf bank_mask:0xf bound_ctrl:0" : "+v"(p));
    return p;
}
__device__ __forceinline__ float exp2_raw(float x) {
    float r;
    asm("v_exp_f32 %0, %1" : "=v"(r) : "v"(x));
    return r;
}
__device__ __forceinline__ void gload16(const unsigned short* g, unsigned short* l) {
    __builtin_amdgcn_global_load_lds(
        (const __attribute__((address_space(1))) unsigned int*)(g),
        (__attribute__((address_space(3))) unsigned int*)(l),
        16, 0, 0);
}

// ---------------------------------------------------------------------------
__global__ __launch_bounds__(256) void cvt_bf16(
    const float* __restrict__ s, unsigned short* __restrict__ d, int n4)
{
    const int g = blockIdx.x * 256 + threadIdx.x;
    if (g < n4) {
        const float4 f = *(const float4*)(s + (size_t)g * 4);
        short4v v;
        v[0] = (short)cvt1(f.x); v[1] = (short)cvt1(f.y);
        v[2] = (short)cvt1(f.z); v[3] = (short)cvt1(f.w);
        *(short4v*)(d + (size_t)g * 4) = v;
    }
}

// merged per-layer weight conversions: wi->bf16, ow->bf16, dtw->split
__global__ __launch_bounds__(256) void cvt_layer(
    const float* __restrict__ wi, const float* __restrict__ owp,
    const float* __restrict__ dtwp,
    unsigned short* __restrict__ wi16, unsigned short* __restrict__ ow16,
    unsigned short* __restrict__ dtwh, unsigned short* __restrict__ dtwl,
    int fastd)
{
    int g = blockIdx.x * 256 + threadIdx.x;
    const int n4w = NXZ * DIMK / 4;
    const int n4o = DIMK * DI / 4;
    const int n4d = DI * DTR / 4;
    if (g < n4w) {
        const float4 f = *(const float4*)(wi + (size_t)g * 4);
        short4v v;
        v[0] = (short)cvt1(f.x); v[1] = (short)cvt1(f.y);
        v[2] = (short)cvt1(f.z); v[3] = (short)cvt1(f.w);
        *(short4v*)(wi16 + (size_t)g * 4) = v;
        return;
    }
    g -= n4w;
    if (g < n4o) {
        const float4 f = *(const float4*)(owp + (size_t)g * 4);
        short4v v;
        v[0] = (short)cvt1(f.x); v[1] = (short)cvt1(f.y);
        v[2] = (short)cvt1(f.z); v[3] = (short)cvt1(f.w);
        *(short4v*)(ow16 + (size_t)g * 4) = v;
        return;
    }
    g -= n4o;
    if (g < n4d && fastd) {
        const float4 f = *(const float4*)(dtwp + (size_t)g * 4);
        short4v h4, l4;
        #pragma unroll
        for (int e = 0; e < 4; ++e) {
            unsigned short h, l;
            split_bf((&f.x)[e], h, l);
            h4[e] = (short)h; l4[e] = (short)l;
        }
        *(short4v*)(dtwh + (size_t)g * 4) = h4;
        *(short4v*)(dtwl + (size_t)g * 4) = l4;
    }
}

// gather boundary x rows (128k-3..128k-1) into compact [256,1024] bf16
__global__ __launch_bounds__(256) void gather_bnd(
    const unsigned short* __restrict__ x16, unsigned short* __restrict__ cmp,
    int tiles)
{
    const int idx = blockIdx.x * 256 + threadIdx.x;
    const int j = idx >> 7;
    const int c8 = (idx & 127) * 8;
    if (j < 3 * tiles) {
        const int k = j / 3, i = j - 3 * k;
        int src = 128 * k - 3 + i;
        if (src < 0) src = 0;
        *(short8*)&cmp[(size_t)j * DIMK + c8] =
            *(const short8*)&x16[(size_t)src * DIMK + c8];
    }
}

// ---------------------------------------------------------------------------
// C[m,n] = sum_k A[m,k]*B[n,k]; A,B bf16 global. 2-phase dbuf + XCD swizzle.
__global__ __launch_bounds__(256) void gemm_bb(
    const unsigned short* __restrict__ A, const unsigned short* __restrict__ B,
    float* __restrict__ C, int K, int lda, int ldb, int ldc)
{
    __shared__ unsigned short As[2][128 * 32];
    __shared__ unsigned short Bs[2][128 * 32];
    int id = blockIdx.y * gridDim.x + blockIdx.x;
    const int qq = (gridDim.x * gridDim.y) >> 3;
    id = (id & 7) * qq + (id >> 3);
    const int bm = (id / gridDim.x) * 128, bn = (id % gridDim.x) * 128;

    const int tid = threadIdx.x;
    const int wv = tid >> 6, ln = tid & 63;
    const int wr = wv >> 1, wc = wv & 1;
    const int fr = ln & 15, kg = ln >> 4;
    const int sr0 = wv * 32 + (ln >> 2);
    const int sr1 = sr0 + 16;
    const int sl = ln & 3;
    const int cg0 = sl ^ ((sr0 >> 1) & 3);
    const int cg1 = sl ^ ((sr1 >> 1) & 3);
    const unsigned short* pa0 = A + (size_t)(bm + sr0) * lda + cg0 * 8;
    const unsigned short* pa1 = A + (size_t)(bm + sr1) * lda + cg1 * 8;
    const unsigned short* pb0 = B + (size_t)(bn + sr0) * ldb + cg0 * 8;
    const unsigned short* pb1 = B + (size_t)(bn + sr1) * ldb + cg1 * 8;
    const int ldst0 = (wv * 32 + 0) * 32;
    const int ldst1 = (wv * 32 + 16) * 32;
    int offA[4], offB[4];
    #pragma unroll
    for (int f = 0; f < 4; ++f) {
        const int ra = wr * 64 + f * 16 + fr;
        offA[f] = ra * 32 + ((kg ^ ((ra >> 1) & 3)) * 8);
        const int rb = wc * 64 + f * 16 + fr;
        offB[f] = rb * 32 + ((kg ^ ((rb >> 1) & 3)) * 8);
    }
    f32x4 acc[4][4] = {};
    gload16(pa0, &As[0][ldst0]);
    gload16(pa1, &As[0][ldst1]);
    gload16(pb0, &Bs[0][ldst0]);
    gload16(pb1, &Bs[0][ldst1]);
    __syncthreads();
    int cur = 0;
    for (int k0 = 0; k0 < K; k0 += 32) {
        const int nxt = cur ^ 1;
        if (k0 + 32 < K) {
            gload16(pa0 + k0 + 32, &As[nxt][ldst0]);
            gload16(pa1 + k0 + 32, &As[nxt][ldst1]);
            gload16(pb0 + k0 + 32, &Bs[nxt][ldst0]);
            gload16(pb1 + k0 + 32, &Bs[nxt][ldst1]);
        }
        short8 af[4], bw[4];
        #pragma unroll
        for (int f = 0; f < 4; ++f) {
            af[f] = *(const short8*)&As[cur][offA[f]];
            bw[f] = *(const short8*)&Bs[cur][offB[f]];
        }
        #pragma unroll
        for (int fi = 0; fi < 4; ++fi)
            #pragma unroll
            for (int fj = 0; fj < 4; ++fj)
                mfma16(acc[fi][fj], af[fi], bw[fj]);
        __syncthreads();
        cur = nxt;
    }
    #pragma unroll
    for (int fi = 0; fi < 4; ++fi) {
        const int m0 = bm + wr * 64 + fi * 16 + kg * 4;
        #pragma unroll
        for (int fj = 0; fj < 4; ++fj) {
            const int n = bn + wc * 64 + fj * 16 + fr;
            #pragma unroll
            for (int q = 0; q < 4; ++q)
                C[(size_t)(m0 + q) * ldc + n] = acc[fi][fj][q];
        }
    }
}

// ---------------------------------------------------------------------------
// in_proj xi-half + fused causal conv + SiLU. K=1024 fixed, lda=ldb=1024.
// Boundary rows (bm-3..bm-1) from bnd (compact 3 rows per 128-tile) or zeros.
__global__ __launch_bounds__(256) void gemm_in(
    const unsigned short* __restrict__ A, const unsigned short* __restrict__ B,
    float* __restrict__ xc, const float* __restrict__ bnd,
    const float* __restrict__ cw, const float* __restrict__ cb)
{
    __shared__ __align__(16) char smem[96 * 132 * 4];  // 50688B; aliases staging
    unsigned short (*As)[128 * 32] = (unsigned short (*)[128 * 32])smem;
    unsigned short (*Bs)[128 * 32] = (unsigned short (*)[128 * 32])(smem + 16384);
    float* xiT = (float*)smem;   // [96][132] slots, used after K loop

    int id = blockIdx.y * gridDim.x + blockIdx.x;
    const int qq = (gridDim.x * gridDim.y) >> 3;
    id = (id & 7) * qq + (id >> 3);
    const int bm = (id / gridDim.x) * 128, bn = (id % gridDim.x) * 128;

    const int tid = threadIdx.x;
    const int wv = tid >> 6, ln = tid & 63;
    const int wr = wv >> 1, wc = wv & 1;
    const int fr = ln & 15, kg = ln >> 4;
    const int sr0 = wv * 32 + (ln >> 2);
    const int sr1 = sr0 + 16;
    const int sl = ln & 3;
    const int cg0 = sl ^ ((sr0 >> 1) & 3);
    const int cg1 = sl ^ ((sr1 >> 1) & 3);
    const unsigned short* pa0 = A + (size_t)(bm + sr0) * DIMK + cg0 * 8;
    const unsigned short* pa1 = A + (size_t)(bm + sr1) * DIMK + cg1 * 8;
    const unsigned short* pb0 = B + (size_t)(bn + sr0) * DIMK + cg0 * 8;
    const unsigned short* pb1 = B + (size_t)(bn + sr1) * DIMK + cg1 * 8;
    const int ldst0 = (wv * 32 + 0) * 32;
    const int ldst1 = (wv * 32 + 16) * 32;
    int offA[4], offB[4];
    #pragma unroll
    for (int f = 0; f < 4; ++f) {
        const int ra = wr * 64 + f * 16 + fr;
        offA[f] = ra * 32 + ((kg ^ ((ra >> 1) & 3)) * 8);
        const int rb = wc * 64 + f * 16 + fr;
        offB[f] = rb * 32 + ((kg ^ ((rb >> 1) & 3)) * 8);
    }
    f32x4 acc[4][4] = {};
    gload16(pa0, &As[0][ldst0]);
    gload16(pa1, &As[0][ldst1]);
    gload16(pb0, &Bs[0][ldst0]);
    gload16(pb1, &Bs[0][ldst1]);
    __syncthreads();
    int cur = 0;
    for (int k0 = 0; k0 < DIMK; k0 += 32) {
        const int nxt = cur ^ 1;
        if (k0 + 32 < DIMK) {
            gload16(pa0 + k0 + 32, &As[nxt][ldst0]);
            gload16(pa1 + k0 + 32, &As[nxt][ldst1]);
            gload16(pb0 + k0 + 32, &Bs[nxt][ldst0]);
            gload16(pb1 + k0 + 32, &Bs[nxt][ldst1]);
        }
        short8 af[4], bw[4];
        #pragma unroll
        for (int f = 0; f < 4; ++f) {
            af[f] = *(const short8*)&As[cur][offA[f]];
            bw[f] = *(const short8*)&Bs[cur][offB[f]];
        }
        #pragma unroll
        for (int fi = 0; fi < 4; ++fi)
            #pragma unroll
            for (int fj = 0; fj < 4; ++fj)
                mfma16(acc[fi][fj], af[fi], bw[fj]);
        __syncthreads();
        cur = nxt;
    }
    // ---- epilogue: exchange q=1..3 rows via LDS slots, then conv+silu ----
    #pragma unroll
    for (int fi = 0; fi < 4; ++fi) {
        const int Bb = wr * 16 + fi * 4 + kg;   // base index 0..31
        #pragma unroll
        for (int fj = 0; fj < 4; ++fj) {
            const int cl = wc * 64 + fj * 16 + fr;
            #pragma unroll
            for (int q = 1; q < 4; ++q)
                xiT[(size_t)(Bb * 3 + q - 1) * 132 + cl] = acc[fi][fj][q];
        }
    }
    __syncthreads();
    const int l0zero = ((bm & (SL - 1)) == 0);
    const int kb = bm >> 7;
    #pragma unroll
    for (int fj = 0; fj < 4; ++fj) {
        const int cl = wc * 64 + fj * 16 + fr;
        const int cg = bn + cl;                 // global channel
        const float4 w4 = *(const float4*)(cw + (size_t)cg * DCONV);
        const float cbv = cb[cg];
        #pragma unroll
        for (int fi = 0; fi < 4; ++fi) {
            const int Bb = wr * 16 + fi * 4 + kg;
            float X[7];
            if (Bb == 0) {
                if (l0zero) { X[0] = 0.f; X[1] = 0.f; X[2] = 0.f; }
                else {
                    #pragma unroll
                    for (int i = 0; i < 3; ++i)
                        X[i] = bnd[(size_t)(3 * kb + i) * DI + cg];
                }
            } else {
                #pragma unroll
                for (int i = 0; i < 3; ++i)
                    X[i] = xiT[(size_t)((Bb - 1) * 3 + i) * 132 + cl];
            }
            #pragma unroll
            for (int q = 0; q < 4; ++q) X[3 + q] = acc[fi][fj][q];
            const int m0 = bm + wr * 64 + fi * 16 + kg * 4;
            #pragma unroll
            for (int q = 0; q < 4; ++q) {
                float a = cbv;
                #pragma unroll
                for (int k = 0; k < DCONV; ++k)
                    a = fmaf(X[q + k], (&w4.x)[k], a);
                a = a / (1.f + __expf(-a));
                xc[(size_t)(m0 + q) * DI + cg] = a;
            }
        }
    }
}

// ---------------------------------------------------------------------------
// A fp32 (reg prefetch + cvt after MFMA), B bf16 (gload dbuf). CBF: bf16 C.
template <int CBF>
__global__ __launch_bounds__(256) void gemm_fb(
    const float* __restrict__ A, const unsigned short* __restrict__ B,
    void* __restrict__ Cv, int K, int lda, int ldb, int ldc)
{
    __shared__ unsigned short As[2][128 * 32];
    __shared__ unsigned short Bs[2][128 * 32];
    int id = blockIdx.y * gridDim.x + blockIdx.x;
    const int qq = (gridDim.x * gridDim.y) >> 3;
    id = (id & 7) * qq + (id >> 3);
    const int bm = (id / gridDim.x) * 128, bn = (id % gridDim.x) * 128;

    const int tid = threadIdx.x;
    const int wv = tid >> 6, ln = tid & 63;
    const int wr = wv >> 1, wc = wv & 1;
    const int fr = ln & 15, kg = ln >> 4;
    const int r = tid >> 1, hf = tid & 1;
    const int sr0 = wv * 32 + (ln >> 2);
    const int sr1 = sr0 + 16;
    const int sl = ln & 3;
    const int cg0 = sl ^ ((sr0 >> 1) & 3);
    const int cg1 = sl ^ ((sr1 >> 1) & 3);
    const unsigned short* pb0 = B + (size_t)(bn + sr0) * ldb + cg0 * 8;
    const unsigned short* pb1 = B + (size_t)(bn + sr1) * ldb + cg1 * 8;
    const int ldst0 = (wv * 32 + 0) * 32;
    const int ldst1 = (wv * 32 + 16) * 32;
    const float* ga = A + (size_t)(bm + r) * lda + hf * 16;
    const int pk0 = (2 * hf + 0) ^ ((r >> 1) & 3);
    const int pk1 = (2 * hf + 1) ^ ((r >> 1) & 3);
    int offA[4], offB[4];
    #pragma unroll
    for (int f = 0; f < 4; ++f) {
        const int ra = wr * 64 + f * 16 + fr;
        offA[f] = ra * 32 + ((kg ^ ((ra >> 1) & 3)) * 8);
        const int rb = wc * 64 + f * 16 + fr;
        offB[f] = rb * 32 + ((kg ^ ((rb >> 1) & 3)) * 8);
    }
    f32x4 acc[4][4] = {};
    {
        float4 f0 = *(const float4*)(ga + 0);
        float4 f1 = *(const float4*)(ga + 4);
        float4 f2 = *(const float4*)(ga + 8);
        float4 f3 = *(const float4*)(ga + 12);
        short8 v;
        v[0] = (short)cvt1(f0.x); v[1] = (short)cvt1(f0.y);
        v[2] = (short)cvt1(f0.z); v[3] = (short)cvt1(f0.w);
        v[4] = (short)cvt1(f1.x); v[5] = (short)cvt1(f1.y);
        v[6] = (short)cvt1(f1.z); v[7] = (short)cvt1(f1.w);
        *(short8*)&As[0][r * 32 + pk0 * 8] = v;
        v[0] = (short)cvt1(f2.x); v[1] = (short)cvt1(f2.y);
        v[2] = (short)cvt1(f2.z); v[3] = (short)cvt1(f2.w);
        v[4] = (short)cvt1(f3.x); v[5] = (short)cvt1(f3.y);
        v[6] = (short)cvt1(f3.z); v[7] = (short)cvt1(f3.w);
        *(short8*)&As[0][r * 32 + pk1 * 8] = v;
        gload16(pb0, &Bs[0][ldst0]);
        gload16(pb1, &Bs[0][ldst1]);
    }
    __syncthreads();
    int cur = 0;
    for (int k0 = 0; k0 < K; k0 += 32) {
        const int nxt = cur ^ 1;
        const bool more = (k0 + 32 < K);
        float4 f0, f1, f2, f3;
        if (more) {
            gload16(pb0 + k0 + 32, &Bs[nxt][ldst0]);
            gload16(pb1 + k0 + 32, &Bs[nxt][ldst1]);
            f0 = *(const float4*)(ga + k0 + 32);
            f1 = *(const float4*)(ga + k0 + 36);
            f2 = *(const float4*)(ga + k0 + 40);
            f3 = *(const float4*)(ga + k0 + 44);
        }
        short8 af[4], bw[4];
        #pragma unroll
        for (int f = 0; f < 4; ++f) {
            af[f] = *(const short8*)&As[cur][offA[f]];
            bw[f] = *(const short8*)&Bs[cur][offB[f]];
        }
        #pragma unroll
        for (int fi = 0; fi < 4; ++fi)
            #pragma unroll
            for (int fj = 0; fj < 4; ++fj)
                mfma16(acc[fi][fj], af[fi], bw[fj]);
        if (more) {
            short8 v;
            v[0] = (short)cvt1(f0.x); v[1] = (short)cvt1(f0.y);
            v[2] = (short)cvt1(f0.z); v[3] = (short)cvt1(f0.w);
            v[4] = (short)cvt1(f1.x); v[5] = (short)cvt1(f1.y);
            v[6] = (short)cvt1(f1.z); v[7] = (short)cvt1(f1.w);
            *(short8*)&As[nxt][r * 32 + pk0 * 8] = v;
            v[0] = (short)cvt1(f2.x); v[1] = (short)cvt1(f2.y);
            v[2] = (short)cvt1(f2.z); v[3] = (short)cvt1(f2.w);
            v[4] = (short)cvt1(f3.x); v[5] = (short)cvt1(f3.y);
            v[6] = (short)cvt1(f3.z); v[7] = (short)cvt1(f3.w);
            *(short8*)&As[nxt][r * 32 + pk1 * 8] = v;
        }
        __syncthreads();
        cur = nxt;
    }
    #pragma unroll
    for (int fi = 0; fi < 4; ++fi) {
        const int m0 = bm + wr * 64 + fi * 16 + kg * 4;
        #pragma unroll
        for (int fj = 0; fj < 4; ++fj) {
            const int n = bn + wc * 64 + fj * 16 + fr;
            #pragma unroll
            for (int q = 0; q < 4; ++q) {
                if (CBF) {
                    unsigned short* Cs = (unsigned short*)Cv;
                    Cs[(size_t)(m0 + q) * ldc + n] = cvt1(acc[fi][fj][q]);
                } else {
                    float* Cf = (float*)Cv;
                    Cf[(size_t)(m0 + q) * ldc + n] = acc[fi][fj][q];
                }
            }
        }
    }
}

// ---------------------------------------------------------------------------
// fallback GEMM (fp32 in/out), used only if ws too small
__global__ __launch_bounds__(256) void gemm_mfma(
    const float* __restrict__ A, const float* __restrict__ W,
    float* __restrict__ C, int K, int lda, int ldc)
{
    __shared__ unsigned short As[128 * 32];
    __shared__ unsigned short Ws[128 * 32];
    const int tid = threadIdx.x;
    const int bm = blockIdx.y * 128;
    const int bn = blockIdx.x * 128;
    const int r = tid >> 1;
    const int h = tid & 1;
    const int wv = tid >> 6;
    const int wr = wv >> 1;
    const int wc = wv & 1;
    const int ln = tid & 63;
    const int fr = ln & 15;
    const int kg = ln >> 4;
    f32x4 acc[4][4] = {};
    const float* ga = A + (size_t)(bm + r) * lda + h * 16;
    const float* gw = W + (size_t)(bn + r) * K + h * 16;
    for (int k0 = 0; k0 < K; k0 += 32) {
        #pragma unroll
        for (int p = 0; p < 2; ++p) {
            const int pk = (2 * h + p) ^ ((r >> 1) & 3);
            float4 f0 = *(const float4*)(ga + k0 + p * 8);
            float4 f1 = *(const float4*)(ga + k0 + p * 8 + 4);
            short8 v;
            v[0] = (short)cvt1(f0.x); v[1] = (short)cvt1(f0.y);
            v[2] = (short)cvt1(f0.z); v[3] = (short)cvt1(f0.w);
            v[4] = (short)cvt1(f1.x); v[5] = (short)cvt1(f1.y);
            v[6] = (short)cvt1(f1.z); v[7] = (short)cvt1(f1.w);
            *(short8*)&As[r * 32 + pk * 8] = v;
            f0 = *(const float4*)(gw + k0 + p * 8);
            f1 = *(const float4*)(gw + k0 + p * 8 + 4);
            v[0] = (short)cvt1(f0.x); v[1] = (short)cvt1(f0.y);
            v[2] = (short)cvt1(f0.z); v[3] = (short)cvt1(f0.w);
            v[4] = (short)cvt1(f1.x); v[5] = (short)cvt1(f1.y);
            v[6] = (short)cvt1(f1.z); v[7] = (short)cvt1(f1.w);
            *(short8*)&Ws[r * 32 + pk * 8] = v;
        }
        __syncthreads();
        short8 af[4], bw[4];
        #pragma unroll
        for (int f = 0; f < 4; ++f) {
            const int ra = wr * 64 + f * 16 + fr;
            af[f] = *(const short8*)&As[ra * 32 + ((kg ^ ((ra >> 1) & 3)) * 8)];
            const int rb = wc * 64 + f * 16 + fr;
            bw[f] = *(const short8*)&Ws[rb * 32 + ((kg ^ ((rb >> 1) & 3)) * 8)];
        }
        #pragma unroll
        for (int fi = 0; fi < 4; ++fi)
            #pragma unroll
            for (int fj = 0; fj < 4; ++fj)
                mfma16(acc[fi][fj], af[fi], bw[fj]);
        __syncthreads();
    }
    #pragma unroll
    for (int fi = 0; fi < 4; ++fi) {
        const int m0 = bm + wr * 64 + fi * 16 + kg * 4;
        #pragma unroll
        for (int fj = 0; fj < 4; ++fj) {
            const int n = bn + wc * 64 + fj * 16 + fr;
            #pragma unroll
            for (int q = 0; q < 4; ++q)
                C[(size_t)(m0 + q) * ldc + n] = acc[fi][fj][q];
        }
    }
}

// ---------------------------------------------------------------------------
// dbc = xc @ xp^T, hi/lo-split bf16 MFMA. BM=128, BN=32.
template <int WRDT>
__global__ __launch_bounds__(256) void gemm_xproj(
    const float* __restrict__ A, const float* __restrict__ W,
    float* __restrict__ C, int K, int lda,
    unsigned short* __restrict__ dth, unsigned short* __restrict__ dtl)
{
    __shared__ unsigned short Ah[128 * 32], Al[128 * 32];
    __shared__ unsigned short Wh[32 * 32], Wl[32 * 32];
    const int tid = threadIdx.x;
    const int bm = blockIdx.y * 128;
    const int bn = blockIdx.x * 32;
    const int r = tid >> 1, hf = tid & 1;
    const int wv = tid >> 6;
    const int ln = tid & 63, fr = ln & 15, kg = ln >> 4;
    const int wsr = tid >> 3;
    const int wc4 = (tid & 7) << 2;
    f32x4 acc[2][2] = {};
    const float* ga = A + (size_t)(bm + r) * lda + hf * 16;
    const float* gw = W + (size_t)(bn + wsr) * K + wc4;
    for (int k0 = 0; k0 < K; k0 += 32) {
        #pragma unroll
        for (int j = 0; j < 4; ++j) {
            const int col = hf * 16 + j * 4;
            const int ad = r * 32 + (((col >> 3) ^ ((r >> 1) & 3)) << 3) + (col & 7);
            const float4 fa = *(const float4*)(ga + k0 + j * 4);
            short4v h4, l4;
            #pragma unroll
            for (int e = 0; e < 4; ++e) {
                unsigned short hh, llo;
                split_bf((&fa.x)[e], hh, llo);
                h4[e] = (short)hh; l4[e] = (short)llo;
            }
            *(short4v*)&Ah[ad] = h4;
            *(short4v*)&Al[ad] = l4;
        }
        {
            const int ad = wsr * 32 + (((wc4 >> 3) ^ ((wsr >> 1) & 3)) << 3) + (wc4 & 7);
            const float4 fw = *(const float4*)(gw + k0);
            short4v h4, l4;
            #pragma unroll
            for (int e = 0; e < 4; ++e) {
                unsigned short hh, llo;
                split_bf((&fw.x)[e], hh, llo);
                h4[e] = (short)hh; l4[e] = (short)llo;
            }
            *(short4v*)&Wh[ad] = h4;
            *(short4v*)&Wl[ad] = l4;
        }
        __syncthreads();
        short8 ah[2], alo[2], bh[2], bl[2];
        #pragma unroll
        for (int f = 0; f < 2; ++f) {
            const int ra = wv * 32 + f * 16 + fr;
            const int ao = ra * 32 + ((kg ^ ((ra >> 1) & 3)) * 8);
            ah[f]  = *(const short8*)&Ah[ao];
            alo[f] = *(const short8*)&Al[ao];
            const int rb = f * 16 + fr;
            const int bo = rb * 32 + ((kg ^ ((rb >> 1) & 3)) * 8);
            bh[f] = *(const short8*)&Wh[bo];
            bl[f] = *(const short8*)&Wl[bo];
        }
        #pragma unroll
        for (int fi = 0; fi < 2; ++fi)
            #pragma unroll
            for (int fj = 0; fj < 2; ++fj) {
                mfma16(acc[fi][fj], ah[fi], bh[fj]);
                mfma16(acc[fi][fj], ah[fi], bl[fj]);
                mfma16(acc[fi][fj], alo[fi], bh[fj]);
            }
        __syncthreads();
    }
    #pragma unroll
    for (int fi = 0; fi < 2; ++fi) {
        const int m0 = bm + wv * 32 + fi * 16 + kg * 4;
        #pragma unroll
        for (int fj = 0; fj < 2; ++fj) {
            const int n = bn + fj * 16 + fr;
            #pragma unroll
            for (int q = 0; q < 4; ++q) {
                const float v = acc[fi][fj][q];
                C[(size_t)(m0 + q) * NDBC + n] = v;
                if (WRDT && n < DTR) {
                    unsigned short hh, llo;
                    split_bf(v, hh, llo);
                    dth[(size_t)(m0 + q) * DTR + n] = hh;
                    dtl[(size_t)(m0 + q) * DTR + n] = llo;
                }
            }
        }
    }
}

// ---------------------------------------------------------------------------
// delta (fallback): split in-kernel from fp32 dbc/dtw. K=64.
__global__ __launch_bounds__(256) void gemm_delta(
    const float* __restrict__ A, const float* __restrict__ W,
    float* __restrict__ C, const float* __restrict__ bias)
{
    __shared__ unsigned short Ah[128 * 32], Al[128 * 32];
    __shared__ unsigned short Wh[128 * 32], Wl[128 * 32];
    const int tid = threadIdx.x;
    const int bm = blockIdx.y * 128;
    const int bn = blockIdx.x * 128;
    const int r = tid >> 1, hf = tid & 1;
    const int wv = tid >> 6, wr = wv >> 1, wc = wv & 1;
    const int ln = tid & 63, fr = ln & 15, kg = ln >> 4;
    f32x4 acc[4][4] = {};
    const float* ga = A + (size_t)(bm + r) * NDBC + hf * 16;
    const float* gw = W + (size_t)(bn + r) * DTR + hf * 16;
    for (int k0 = 0; k0 < DTR; k0 += 32) {
        #pragma unroll
        for (int j = 0; j < 4; ++j) {
            const int col = hf * 16 + j * 4;
            const int ad = r * 32 + (((col >> 3) ^ ((r >> 1) & 3)) << 3) + (col & 7);
            const float4 fa = *(const float4*)(ga + k0 + j * 4);
            const float4 fw = *(const float4*)(gw + k0 + j * 4);
            short4v ah4, al4, wh4, wl4;
            #pragma unroll
            for (int e = 0; e < 4; ++e) {
                unsigned short hh, llo;
                split_bf((&fa.x)[e], hh, llo);
                ah4[e] = (short)hh; al4[e] = (short)llo;
                split_bf((&fw.x)[e], hh, llo);
                wh4[e] = (short)hh; wl4[e] = (short)llo;
            }
            *(short4v*)&Ah[ad] = ah4; *(short4v*)&Al[ad] = al4;
            *(short4v*)&Wh[ad] = wh4; *(short4v*)&Wl[ad] = wl4;
        }
        __syncthreads();
        short8 ah[4], alo[4], bh[4], bl[4];
        #pragma unroll
        for (int f = 0; f < 4; ++f) {
            const int ra = wr * 64 + f * 16 + fr;
            const int ao = ra * 32 + ((kg ^ ((ra >> 1) & 3)) * 8);
            ah[f]  = *(const short8*)&Ah[ao];
            alo[f] = *(const short8*)&Al[ao];
            const int rb = wc * 64 + f * 16 + fr;
            const int bo = rb * 32 + ((kg ^ ((rb >> 1) & 3)) * 8);
            bh[f] = *(const short8*)&Wh[bo];
            bl[f] = *(const short8*)&Wl[bo];
        }
        #pragma unroll
        for (int fi = 0; fi < 4; ++fi)
            #pragma unroll
            for (int fj = 0; fj < 4; ++fj) {
                mfma16(acc[fi][fj], ah[fi], bh[fj]);
                mfma16(acc[fi][fj], ah[fi], bl[fj]);
                mfma16(acc[fi][fj], alo[fi], bh[fj]);
            }
        __syncthreads();
    }
    #pragma unroll
    for (int fi = 0; fi < 4; ++fi) {
        const int m0 = bm + wr * 64 + fi * 16 + kg * 4;
        #pragma unroll
        for (int fj = 0; fj < 4; ++fj) {
            const int n = bn + wc * 64 + fj * 16 + fr;
            const float bb = bias[n];
            #pragma unroll
            for (int q = 0; q < 4; ++q) {
                float v = acc[fi][fj][q] + bb;
                v = (v > 20.f) ? v : log1pf(__expf(v));
                C[(size_t)(m0 + q) * NXZ + n] = v;
            }
        }
    }
}

// ---------------------------------------------------------------------------
// delta (fast): all operands pre-split bf16; single stage via gload, K=64.
__global__ __launch_bounds__(256) void gemm_delta_pre(
    const unsigned short* __restrict__ Ahg, const unsigned short* __restrict__ Alg,
    const unsigned short* __restrict__ Whg, const unsigned short* __restrict__ Wlg,
    float* __restrict__ C, const float* __restrict__ bias)
{
    __shared__ unsigned short sAh[128 * 64], sAl[128 * 64];
    __shared__ unsigned short sWh[128 * 64], sWl[128 * 64];
    const int tid = threadIdx.x;
    const int bm = blockIdx.y * 128;
    const int bn = blockIdx.x * 128;
    const int wv = tid >> 6, ln = tid & 63;
    const int wr = wv >> 1, wc = wv & 1;
    const int fr = ln & 15, kg = ln >> 4;
    const int srow = ln >> 3;
    const int g = ln & 7;
    const int half = g >> 2, sub = g & 3;
    #pragma unroll
    for (int j = 0; j < 4; ++j) {
        const int row = wv * 32 + j * 8 + srow;
        const int sub2 = sub ^ ((row >> 1) & 3);
        const int scol = half * 32 + sub2 * 8;
        const int dst = (wv * 32 + j * 8) * 64;
        gload16(Ahg + (size_t)(bm + row) * DTR + scol, sAh + dst);
        gload16(Alg + (size_t)(bm + row) * DTR + scol, sAl + dst);
        gload16(Whg + (size_t)(bn + row) * DTR + scol, sWh + dst);
        gload16(Wlg + (size_t)(bn + row) * DTR + scol, sWl + dst);
    }
    __syncthreads();
    f32x4 acc[4][4] = {};
    #pragma unroll
    for (int ks = 0; ks < 2; ++ks) {
        short8 ah[4], alo[4], bh[4], bl[4];
        #pragma unroll
        for (int f = 0; f < 4; ++f) {
            const int ra = wr * 64 + f * 16 + fr;
            const int ao = ra * 64 + ks * 32 + ((kg ^ ((ra >> 1) & 3)) * 8);
            ah[f]  = *(const short8*)&sAh[ao];
            alo[f] = *(const short8*)&sAl[ao];
            const int rb = wc * 64 + f * 16 + fr;
            const int bo = rb * 64 + ks * 32 + ((kg ^ ((rb >> 1) & 3)) * 8);
            bh[f] = *(const short8*)&sWh[bo];
            bl[f] = *(const short8*)&sWl[bo];
        }
        #pragma unroll
        for (int fi = 0; fi < 4; ++fi)
            #pragma unroll
            for (int fj = 0; fj < 4; ++fj) {
                mfma16(acc[fi][fj], ah[fi], bh[fj]);
                mfma16(acc[fi][fj], ah[fi], bl[fj]);
                mfma16(acc[fi][fj], alo[fi], bh[fj]);
            }
    }
    #pragma unroll
    for (int fi = 0; fi < 4; ++fi) {
        const int m0 = bm + wr * 64 + fi * 16 + kg * 4;
        #pragma unroll
        for (int fj = 0; fj < 4; ++fj) {
            const int n = bn + wc * 64 + fj * 16 + fr;
            const float bb = bias[n];
            #pragma unroll
            for (int q = 0; q < 4; ++q) {
                float v = acc[fi][fj][q] + bb;
                v = (v > 20.f) ? v : log1pf(__expf(v));
                C[(size_t)(m0 + q) * NXZ + n] = v;
            }
        }
    }
}

// ---------------------------------------------------------------------------
// conv+silu standalone (fallback path only)
__global__ __launch_bounds__(256) void conv_silu(
    const float* __restrict__ xz, const float* __restrict__ cw,
    const float* __restrict__ cb, float* __restrict__ xc)
{
    const int g = blockIdx.x * 256 + threadIdx.x;
    const int c4 = g & (DI / 4 - 1);
    const int mq = g >> 9;
    const int m0 = mq << 2;
    const int l0 = m0 & (SL - 1);
    const int c = c4 << 2;
    const float4 w0 = *(const float4*)(cw + (size_t)(c + 0) * DCONV);
    const float4 w1 = *(const float4*)(cw + (size_t)(c + 1) * DCONV);
    const float4 w2 = *(const float4*)(cw + (size_t)(c + 2) * DCONV);
    const float4 w3 = *(const float4*)(cw + (size_t)(c + 3) * DCONV);
    const float4 cb4 = *(const float4*)(cb + c);
    float4 x[7];
    #pragma unroll
    for (int i = 0; i < 7; ++i) {
        if (l0 - 3 + i >= 0)
            x[i] = *(const float4*)(xz + (size_t)(m0 - 3 + i) * NXZ + c);
        else
            x[i] = make_float4(0.f, 0.f, 0.f, 0.f);
    }
    #pragma unroll
    for (int j = 0; j < 4; ++j) {
        float4 acc = cb4;
        #pragma unroll
        for (int k = 0; k < DCONV; ++k) {
            const float4 v = x[j + k];
            acc.x = fmaf(v.x, (&w0.x)[k], acc.x);
            acc.y = fmaf(v.y, (&w1.x)[k], acc.y);
            acc.z = fmaf(v.z, (&w2.x)[k], acc.z);
            acc.w = fmaf(v.w, (&w3.x)[k], acc.w);
        }
        acc.x = acc.x / (1.f + __expf(-acc.x));
        acc.y = acc.y / (1.f + __expf(-acc.y));
        acc.z = acc.z / (1.f + __expf(-acc.z));
        acc.w = acc.w / (1.f + __expf(-acc.w));
        *(float4*)(xc + (size_t)(m0 + j) * DI + c) = acc;
    }
}

// ---------------------------------------------------------------------------
// Selective scan: DPP reduce, p0/p1 in registers, sy double-buffered.
__global__ __launch_bounds__(256) void scan_k(
    const float* u, const float* __restrict__ dbc,
    const float* __restrict__ xz, float* y,
    const float* __restrict__ Alog, const float* __restrict__ Dl)
{
    const int b = blockIdx.y;
    const int c0 = blockIdx.x * 16;
    const int tid = threadIdx.x;
    const int ch = tid >> 4;
    const int s = tid & 15;
    const float Aa = -__expf(Alog[(size_t)(c0 + ch) * DS + s]) * 1.44269504088896f;
    __shared__ float sdl[16][68];
    __shared__ float sxb[16][68];
    __shared__ float sbc[32][68];
    __shared__ float sy[2][64][16];
    __shared__ float sD[16];
    if (tid < 16) sD[tid] = Dl[c0 + tid];
    __syncthreads();
    float h = 0.f;
    const int row = tid >> 2;
    const int q = (tid & 3) << 2;
    int pp = 0;
    for (int t0b = 0; t0b < SL; t0b += 64) {
        const size_t mb = (size_t)b * SL + t0b;
        const float4 dlv = *(const float4*)(xz + (mb + row) * NXZ + c0 + q);
        const float4 uv  = *(const float4*)(u  + (mb + row) * DI + c0 + q);
        const float4 zv  = *(const float4*)(xz + (mb + row) * NXZ + DI + c0 + q);
        float4 p0, p1;
        #pragma unroll
        for (int j = 0; j < 4; ++j) {
            const float dl = (&dlv.x)[j], uu = (&uv.x)[j], zz = (&zv.x)[j];
            const float w = zz / (1.f + __expf(-zz));
            sdl[q + j][row] = dl;
            sxb[q + j][row] = dl * uu;
            (&p1.x)[j] = w;
            (&p0.x)[j] = uu * sD[q + j] * w;
        }
        #pragma unroll
        for (int p = 0; p < 2; ++p) {
            const int idx = p * 256 + tid;
            const int r2 = idx >> 3, q2 = (idx & 7) << 2;
            const float4 v = *(const float4*)(dbc + (mb + r2) * NDBC + DTR + q2);
            sbc[q2 + 0][r2] = v.x; sbc[q2 + 1][r2] = v.y;
            sbc[q2 + 2][r2] = v.z; sbc[q2 + 3][r2] = v.w;
        }
        __syncthreads();
        for (int it = 0; it < 16; ++it) {
            const int t0 = it * 4;
            const float4 dl4 = *(const float4*)&sdl[ch][t0];
            const float4 xb4 = *(const float4*)&sxb[ch][t0];
            const float4 B4  = *(const float4*)&sbc[s][t0];
            const float4 C4  = *(const float4*)&sbc[16 + s][t0];
            float py0, py1, py2, py3;
            {
                const float dA = exp2_raw(dl4.x * Aa);
                h = fmaf(dA, h, xb4.x * B4.x);
                py0 = dpp_sum16(h * C4.x);
            }
            {
                const float dA = exp2_raw(dl4.y * Aa);
                h = fmaf(dA, h, xb4.y * B4.y);
                py1 = dpp_sum16(h * C4.y);
            }
            {
                const float dA = exp2_raw(dl4.z * Aa);
                h = fmaf(dA, h, xb4.z * B4.z);
                py2 = dpp_sum16(h * C4.z);
            }
            {
                const float dA = exp2_raw(dl4.w * Aa);
                h = fmaf(dA, h, xb4.w * B4.w);
                py3 = dpp_sum16(h * C4.w);
            }
            if (s < 4) {
                const int t = t0 + s;
                const float lo_ = (s & 1) ? py1 : py0;
                const float hi_ = (s & 1) ? py3 : py2;
                sy[pp][t][ch] = (s & 2) ? hi_ : lo_;
            }
        }
        __syncthreads();
        float4 yv;
        #pragma unroll
        for (int e = 0; e < 4; ++e)
            (&yv.x)[e] = fmaf(sy[pp][row][q + e], (&p1.x)[e], (&p0.x)[e]);
        *(float4*)(y + (mb + row) * DI + c0 + q) = yv;
        pp ^= 1;
    }
}

// ---------------------------------------------------------------------------
extern "C" void kernel_launch(void* const* d_in, const int* in_sizes, int n_in,
                              void* d_out, int out_size, void* d_ws, size_t ws_size,
                              hipStream_t stream)
{
    const float* x0   = (const float*)d_in[0];
    const float* in_w = (const float*)d_in[1];
    const float* cw   = (const float*)d_in[2];
    const float* cb   = (const float*)d_in[3];
    const float* xpw  = (const float*)d_in[4];
    const float* dtw  = (const float*)d_in[5];
    const float* dtb  = (const float*)d_in[6];
    const float* Alog = (const float*)d_in[7];
    const float* Dp   = (const float*)d_in[8];
    const float* ow   = (const float*)d_in[9];

    const size_t perB = (size_t)SL * (NXZ + DI + NDBC) * sizeof(float); // ~51.1MB
    const size_t wby  = ((size_t)NXZ * DIMK + (size_t)DIMK * DI) * 2;   // 12.6MB
    int nbc = 0, fast = 0;
    if (ws_size >= 4 * perB + wby)      { nbc = 4; fast = 1; }
    else if (ws_size >= 2 * perB + wby) { nbc = 2; fast = 1; }
    else if (ws_size >= perB + wby)     { nbc = 1; fast = 1; }
    else if (ws_size >= 4 * perB)       { nbc = 4; }
    else if (ws_size >= 2 * perB)       { nbc = 2; }
    else if (ws_size >= perB)           { nbc = 1; }
    else return;
    const int nchunks = NB / nbc;
    const int M = nbc * SL;
    const int tiles = M / 128;
    const size_t dtby = ((size_t)DI * DTR * 2 + (size_t)M * DTR * 2) * 2;
    const size_t cby  = (size_t)256 * DI * 4 + (size_t)256 * DIMK * 2; // bnd+compact
    const size_t base = (size_t)nbc * perB + wby;
    const int fastd = fast && (ws_size >= base + dtby);
    const int fastc = fastd && (ws_size >= base + dtby + cby);

    float* xz  = (float*)d_ws;
    float* xc  = xz + (size_t)M * NXZ;
    float* dbc = xc + (size_t)M * DI;
    unsigned short* wi16 = (unsigned short*)(dbc + (size_t)M * NDBC);
    unsigned short* ow16 = wi16 + (size_t)NXZ * DIMK;
    unsigned short* dtwh = ow16 + (size_t)DIMK * DI;
    unsigned short* dtwl = dtwh + (size_t)DI * DTR;
    unsigned short* dth  = dtwl + (size_t)DI * DTR;
    unsigned short* dtl  = dth + (size_t)M * DTR;
    float* bnd_out = (float*)(dtl + (size_t)M * DTR);
    unsigned short* cmp16 = (unsigned short*)(bnd_out + (size_t)256 * DI);

    unsigned short* xb16 = (unsigned short*)d_out + (size_t)MT * DIMK;
    float* xbuf = (float*)d_out;

    const dim3 blk(256);
    if (fast) {
        const int n4x = MT * DIMK / 4;
        cvt_bf16<<<dim3(n4x / 256), blk, 0, stream>>>(x0, xb16, n4x);
    }
    const int ncv = (NXZ * DIMK / 4) + (DIMK * DI / 4) + (DI * DTR / 4);
    for (int ly = 0; ly < NDEPTH; ++ly) {
        const float* Wi   = in_w + (size_t)ly * NXZ * DIMK;
        const float* cwl  = cw   + (size_t)ly * DI * DCONV;
        const float* cbl  = cb   + (size_t)ly * DI;
        const float* xpl  = xpw  + (size_t)ly * NDBC * DI;
        const float* dtwl_ = dtw + (size_t)ly * DI * DTR;
        const float* dtbl = dtb  + (size_t)ly * DI;
        const float* Al   = Alog + (size_t)ly * DI * DS;
        const float* Dl   = Dp   + (size_t)ly * DI;
        const float* owl  = ow   + (size_t)ly * DIMK * DI;

        if (fast)
            cvt_layer<<<dim3((ncv + 255) / 256), blk, 0, stream>>>(
                Wi, owl, dtwl_, wi16, ow16, dtwh, dtwl, fastd);

        for (int ck = 0; ck < nchunks; ++ck) {
            const unsigned short* xin16 = xb16 + (size_t)ck * M * DIMK;
            if (fast && fastc) {
                // boundary rows prepass + fused in_proj(xi)+conv+silu, z-half
                gather_bnd<<<dim3((3 * tiles * 128 + 255) / 256), blk, 0, stream>>>(
                    xin16, cmp16, tiles);
                gemm_bb<<<dim3(DI / 128, 2), blk, 0, stream>>>(
                    cmp16, wi16, bnd_out, DIMK, DIMK, DIMK, DI);
                gemm_in<<<dim3(DI / 128, M / 128), blk, 0, stream>>>(
                    xin16, wi16, xc, bnd_out, cwl, cbl);
                gemm_bb<<<dim3(DI / 128, M / 128), blk, 0, stream>>>(
                    xin16, wi16 + (size_t)DI * DIMK, xz + DI,
                    DIMK, DIMK, DIMK, NXZ);
            } else if (fast) {
                gemm_bb<<<dim3(NXZ / 128, M / 128), blk, 0, stream>>>(
                    xin16, wi16, xz, DIMK, DIMK, DIMK, NXZ);
                conv_silu<<<dim3(M * (DI / 16) / 256), blk, 0, stream>>>(
                    xz, cwl, cbl, xc);
            } else {
                const float* xin = (ly == 0 ? x0 : xbuf) + (size_t)ck * M * DIMK;
                gemm_mfma<<<dim3(NXZ / 128, M / 128), blk, 0, stream>>>(
                    xin, Wi, xz, DIMK, DIMK, NXZ);
                conv_silu<<<dim3(M * (DI / 16) / 256), blk, 0, stream>>>(
                    xz, cwl, cbl, xc);
            }
            if (fastd) {
                gemm_xproj<1><<<dim3(3, M / 128), blk, 0, stream>>>(
                    xc, xpl, dbc, DI, DI, dth, dtl);
                gemm_delta_pre<<<dim3(DI / 128, M / 128), blk, 0, stream>>>(
                    dth, dtl, dtwh, dtwl, xz, dtbl);
            } else {
                gemm_xproj<0><<<dim3(3, M / 128), blk, 0, stream>>>(
                    xc, xpl, dbc, DI, DI, nullptr, nullptr);
                gemm_delta<<<dim3(DI / 128, M / 128), blk, 0, stream>>>(
                    dbc, dtwl_, xz, dtbl);
            }
            scan_k<<<dim3(DI / 16, nbc), blk, 0, stream>>>(
                xc, dbc, xz, xc, Al, Dl);
            if (fast) {
                if (ly < NDEPTH - 1) {
                    gemm_fb<1><<<dim3(DIMK / 128, M / 128), blk, 0, stream>>>(
                        xc, ow16, xb16 + (size_t)ck * M * DIMK, DI, DI, DI, DIMK);
                } else {
                    gemm_fb<0><<<dim3(DIMK / 128, M / 128), blk, 0, stream>>>(
                        xc, ow16, (float*)d_out + (size_t)ck * M * DIMK,
                        DI, DI, DI, DIMK);
                }
            } else {
                float* xdst = (ly == NDEPTH - 1 ? (float*)d_out : xbuf) +
                              (size_t)ck * M * DIMK;
                gemm_mfma<<<dim3(DIMK / 128, M / 128), blk, 0, stream>>>(
                    xc, owl, xdst, DI, DI, DIMK);
            }
        }
    }
}

// Round 10
// 1921.492 us; speedup vs baseline: 1.2611x; 1.0356x over previous
//
#include <hip/hip_runtime.h>
#include <hip/hip_bf16.h>
#include <math.h>

#define DIMK 1024
#define NDEPTH 4
#define DS 16
#define DCONV 4
#define DI 2048
#define DTR 64
#define NB 4
#define SL 2048
#define MT (NB * SL)        // 8192
#define NXZ (2 * DI)        // 4096
#define NDBC (DTR + 2 * DS) // 96

typedef float f32x4 __attribute__((ext_vector_type(4)));
typedef short short8 __attribute__((ext_vector_type(8)));
typedef short short4v __attribute__((ext_vector_type(4)));

__device__ inline unsigned short f2bf(float f) {
    unsigned u = __builtin_bit_cast(unsigned, f);
    unsigned r = (u + 0x7FFFu + ((u >> 16) & 1u)) >> 16;
    return (unsigned short)r;
}
__device__ inline float bf2f(unsigned short h) {
    unsigned u = ((unsigned)h) << 16;
    return __builtin_bit_cast(float, u);
}
__device__ inline void split_bf(float f, unsigned short& hi, unsigned short& lo) {
    hi = f2bf(f);
    lo = f2bf(f - bf2f(hi));
}
__device__ inline unsigned short cvt1(float f) {
    __hip_bfloat16 t = __float2bfloat16(f);
    return __builtin_bit_cast(unsigned short, t);
}
__device__ inline void mfma16(f32x4& d, short8 a, short8 b) {
    asm volatile("v_mfma_f32_16x16x32_bf16 %0, %1, %2, %0"
                 : "+v"(d) : "v"(a), "v"(b));
}
__device__ __forceinline__ float dpp_sum16(float p) {
    asm("v_add_f32_dpp %0, %0, %0 quad_perm:[1,0,3,2] row_mask:0xf bank_mask:0xf bound_ctrl:0" : "+v"(p));
    asm("v_add_f32_dpp %0, %0, %0 quad_perm:[2,3,0,1] row_mask:0xf bank_mask:0xf bound_ctrl:0" : "+v"(p));
    asm("v_add_f32_dpp %0, %0, %0 row_ror:4 row_mask:0xf bank_mask:0xf bound_ctrl:0" : "+v"(p));
    asm("v_add_f32_dpp %0, %0, %0 row_ror:8 row_mask:0xf bank_mask:0xf bound_ctrl:0" : "+v"(p));
    return p;
}
__device__ __forceinline__ float exp2_raw(float x) {
    float r;
    asm("v_exp_f32 %0, %1" : "=v"(r) : "v"(x));
    return r;
}
__device__ __forceinline__ void gload16(const unsigned short* g, unsigned short* l) {
    __builtin_amdgcn_global_load_lds(
        (const __attribute__((address_space(1))) unsigned int*)(g),
        (__attribute__((address_space(3))) unsigned int*)(l),
        16, 0, 0);
}

// ---------------------------------------------------------------------------
__global__ __launch_bounds__(256) void cvt_bf16(
    const float* __restrict__ s, unsigned short* __restrict__ d, int n4)
{
    const int g = blockIdx.x * 256 + threadIdx.x;
    if (g < n4) {
        const float4 f = *(const float4*)(s + (size_t)g * 4);
        short4v v;
        v[0] = (short)cvt1(f.x); v[1] = (short)cvt1(f.y);
        v[2] = (short)cvt1(f.z); v[3] = (short)cvt1(f.w);
        *(short4v*)(d + (size_t)g * 4) = v;
    }
}

// merged per-layer weight conversions: wi->bf16, ow->bf16, dtw->split
__global__ __launch_bounds__(256) void cvt_layer(
    const float* __restrict__ wi, const float* __restrict__ owp,
    const float* __restrict__ dtwp,
    unsigned short* __restrict__ wi16, unsigned short* __restrict__ ow16,
    unsigned short* __restrict__ dtwh, unsigned short* __restrict__ dtwl,
    int fastd)
{
    int g = blockIdx.x * 256 + threadIdx.x;
    const int n4w = NXZ * DIMK / 4;
    const int n4o = DIMK * DI / 4;
    const int n4d = DI * DTR / 4;
    if (g < n4w) {
        const float4 f = *(const float4*)(wi + (size_t)g * 4);
        short4v v;
        v[0] = (short)cvt1(f.x); v[1] = (short)cvt1(f.y);
        v[2] = (short)cvt1(f.z); v[3] = (short)cvt1(f.w);
        *(short4v*)(wi16 + (size_t)g * 4) = v;
        return;
    }
    g -= n4w;
    if (g < n4o) {
        const float4 f = *(const float4*)(owp + (size_t)g * 4);
        short4v v;
        v[0] = (short)cvt1(f.x); v[1] = (short)cvt1(f.y);
        v[2] = (short)cvt1(f.z); v[3] = (short)cvt1(f.w);
        *(short4v*)(ow16 + (size_t)g * 4) = v;
        return;
    }
    g -= n4o;
    if (g < n4d && fastd) {
        const float4 f = *(const float4*)(dtwp + (size_t)g * 4);
        short4v h4, l4;
        #pragma unroll
        for (int e = 0; e < 4; ++e) {
            unsigned short h, l;
            split_bf((&f.x)[e], h, l);
            h4[e] = (short)h; l4[e] = (short)l;
        }
        *(short4v*)(dtwh + (size_t)g * 4) = h4;
        *(short4v*)(dtwl + (size_t)g * 4) = l4;
    }
}

// ---------------------------------------------------------------------------
// C[m,n] = sum_k A[m,k]*B[n,k]; A,B bf16 global. 2-phase dbuf + XCD swizzle.
// CBF: 1 -> bf16 C out, 0 -> fp32.
template <int CBF>
__global__ __launch_bounds__(256) void gemm_bb(
    const unsigned short* __restrict__ A, const unsigned short* __restrict__ B,
    void* __restrict__ Cv, int K, int lda, int ldb, int ldc)
{
    __shared__ unsigned short As[2][128 * 32];
    __shared__ unsigned short Bs[2][128 * 32];
    int id = blockIdx.y * gridDim.x + blockIdx.x;
    const int qq = (gridDim.x * gridDim.y) >> 3;
    id = (id & 7) * qq + (id >> 3);
    const int bm = (id / gridDim.x) * 128, bn = (id % gridDim.x) * 128;

    const int tid = threadIdx.x;
    const int wv = tid >> 6, ln = tid & 63;
    const int wr = wv >> 1, wc = wv & 1;
    const int fr = ln & 15, kg = ln >> 4;
    const int sr0 = wv * 32 + (ln >> 2);
    const int sr1 = sr0 + 16;
    const int sl = ln & 3;
    const int cg0 = sl ^ ((sr0 >> 1) & 3);
    const int cg1 = sl ^ ((sr1 >> 1) & 3);
    const unsigned short* pa0 = A + (size_t)(bm + sr0) * lda + cg0 * 8;
    const unsigned short* pa1 = A + (size_t)(bm + sr1) * lda + cg1 * 8;
    const unsigned short* pb0 = B + (size_t)(bn + sr0) * ldb + cg0 * 8;
    const unsigned short* pb1 = B + (size_t)(bn + sr1) * ldb + cg1 * 8;
    const int ldst0 = (wv * 32 + 0) * 32;
    const int ldst1 = (wv * 32 + 16) * 32;
    int offA[4], offB[4];
    #pragma unroll
    for (int f = 0; f < 4; ++f) {
        const int ra = wr * 64 + f * 16 + fr;
        offA[f] = ra * 32 + ((kg ^ ((ra >> 1) & 3)) * 8);
        const int rb = wc * 64 + f * 16 + fr;
        offB[f] = rb * 32 + ((kg ^ ((rb >> 1) & 3)) * 8);
    }
    f32x4 acc[4][4] = {};
    gload16(pa0, &As[0][ldst0]);
    gload16(pa1, &As[0][ldst1]);
    gload16(pb0, &Bs[0][ldst0]);
    gload16(pb1, &Bs[0][ldst1]);
    __syncthreads();
    int cur = 0;
    for (int k0 = 0; k0 < K; k0 += 32) {
        const int nxt = cur ^ 1;
        if (k0 + 32 < K) {
            gload16(pa0 + k0 + 32, &As[nxt][ldst0]);
            gload16(pa1 + k0 + 32, &As[nxt][ldst1]);
            gload16(pb0 + k0 + 32, &Bs[nxt][ldst0]);
            gload16(pb1 + k0 + 32, &Bs[nxt][ldst1]);
        }
        short8 af[4], bw[4];
        #pragma unroll
        for (int f = 0; f < 4; ++f) {
            af[f] = *(const short8*)&As[cur][offA[f]];
            bw[f] = *(const short8*)&Bs[cur][offB[f]];
        }
        #pragma unroll
        for (int fi = 0; fi < 4; ++fi)
            #pragma unroll
            for (int fj = 0; fj < 4; ++fj)
                mfma16(acc[fi][fj], af[fi], bw[fj]);
        __syncthreads();
        cur = nxt;
    }
    #pragma unroll
    for (int fi = 0; fi < 4; ++fi) {
        const int m0 = bm + wr * 64 + fi * 16 + kg * 4;
        #pragma unroll
        for (int fj = 0; fj < 4; ++fj) {
            const int n = bn + wc * 64 + fj * 16 + fr;
            #pragma unroll
            for (int q = 0; q < 4; ++q) {
                if (CBF) {
                    unsigned short* Cs = (unsigned short*)Cv;
                    Cs[(size_t)(m0 + q) * ldc + n] = cvt1(acc[fi][fj][q]);
                } else {
                    float* Cf = (float*)Cv;
                    Cf[(size_t)(m0 + q) * ldc + n] = acc[fi][fj][q];
                }
            }
        }
    }
}

// ---------------------------------------------------------------------------
// A fp32 (reg prefetch + cvt after MFMA), B bf16 (gload dbuf). CBF: bf16 C.
template <int CBF>
__global__ __launch_bounds__(256) void gemm_fb(
    const float* __restrict__ A, const unsigned short* __restrict__ B,
    void* __restrict__ Cv, int K, int lda, int ldb, int ldc)
{
    __shared__ unsigned short As[2][128 * 32];
    __shared__ unsigned short Bs[2][128 * 32];
    int id = blockIdx.y * gridDim.x + blockIdx.x;
    const int qq = (gridDim.x * gridDim.y) >> 3;
    id = (id & 7) * qq + (id >> 3);
    const int bm = (id / gridDim.x) * 128, bn = (id % gridDim.x) * 128;

    const int tid = threadIdx.x;
    const int wv = tid >> 6, ln = tid & 63;
    const int wr = wv >> 1, wc = wv & 1;
    const int fr = ln & 15, kg = ln >> 4;
    const int r = tid >> 1, hf = tid & 1;
    const int sr0 = wv * 32 + (ln >> 2);
    const int sr1 = sr0 + 16;
    const int sl = ln & 3;
    const int cg0 = sl ^ ((sr0 >> 1) & 3);
    const int cg1 = sl ^ ((sr1 >> 1) & 3);
    const unsigned short* pb0 = B + (size_t)(bn + sr0) * ldb + cg0 * 8;
    const unsigned short* pb1 = B + (size_t)(bn + sr1) * ldb + cg1 * 8;
    const int ldst0 = (wv * 32 + 0) * 32;
    const int ldst1 = (wv * 32 + 16) * 32;
    const float* ga = A + (size_t)(bm + r) * lda + hf * 16;
    const int pk0 = (2 * hf + 0) ^ ((r >> 1) & 3);
    const int pk1 = (2 * hf + 1) ^ ((r >> 1) & 3);
    int offA[4], offB[4];
    #pragma unroll
    for (int f = 0; f < 4; ++f) {
        const int ra = wr * 64 + f * 16 + fr;
        offA[f] = ra * 32 + ((kg ^ ((ra >> 1) & 3)) * 8);
        const int rb = wc * 64 + f * 16 + fr;
        offB[f] = rb * 32 + ((kg ^ ((rb >> 1) & 3)) * 8);
    }
    f32x4 acc[4][4] = {};
    {
        float4 f0 = *(const float4*)(ga + 0);
        float4 f1 = *(const float4*)(ga + 4);
        float4 f2 = *(const float4*)(ga + 8);
        float4 f3 = *(const float4*)(ga + 12);
        short8 v;
        v[0] = (short)cvt1(f0.x); v[1] = (short)cvt1(f0.y);
        v[2] = (short)cvt1(f0.z); v[3] = (short)cvt1(f0.w);
        v[4] = (short)cvt1(f1.x); v[5] = (short)cvt1(f1.y);
        v[6] = (short)cvt1(f1.z); v[7] = (short)cvt1(f1.w);
        *(short8*)&As[0][r * 32 + pk0 * 8] = v;
        v[0] = (short)cvt1(f2.x); v[1] = (short)cvt1(f2.y);
        v[2] = (short)cvt1(f2.z); v[3] = (short)cvt1(f2.w);
        v[4] = (short)cvt1(f3.x); v[5] = (short)cvt1(f3.y);
        v[6] = (short)cvt1(f3.z); v[7] = (short)cvt1(f3.w);
        *(short8*)&As[0][r * 32 + pk1 * 8] = v;
        gload16(pb0, &Bs[0][ldst0]);
        gload16(pb1, &Bs[0][ldst1]);
    }
    __syncthreads();
    int cur = 0;
    for (int k0 = 0; k0 < K; k0 += 32) {
        const int nxt = cur ^ 1;
        const bool more = (k0 + 32 < K);
        float4 f0, f1, f2, f3;
        if (more) {
            gload16(pb0 + k0 + 32, &Bs[nxt][ldst0]);
            gload16(pb1 + k0 + 32, &Bs[nxt][ldst1]);
            f0 = *(const float4*)(ga + k0 + 32);
            f1 = *(const float4*)(ga + k0 + 36);
            f2 = *(const float4*)(ga + k0 + 40);
            f3 = *(const float4*)(ga + k0 + 44);
        }
        short8 af[4], bw[4];
        #pragma unroll
        for (int f = 0; f < 4; ++f) {
            af[f] = *(const short8*)&As[cur][offA[f]];
            bw[f] = *(const short8*)&Bs[cur][offB[f]];
        }
        #pragma unroll
        for (int fi = 0; fi < 4; ++fi)
            #pragma unroll
            for (int fj = 0; fj < 4; ++fj)
                mfma16(acc[fi][fj], af[fi], bw[fj]);
        if (more) {
            short8 v;
            v[0] = (short)cvt1(f0.x); v[1] = (short)cvt1(f0.y);
            v[2] = (short)cvt1(f0.z); v[3] = (short)cvt1(f0.w);
            v[4] = (short)cvt1(f1.x); v[5] = (short)cvt1(f1.y);
            v[6] = (short)cvt1(f1.z); v[7] = (short)cvt1(f1.w);
            *(short8*)&As[nxt][r * 32 + pk0 * 8] = v;
            v[0] = (short)cvt1(f2.x); v[1] = (short)cvt1(f2.y);
            v[2] = (short)cvt1(f2.z); v[3] = (short)cvt1(f2.w);
            v[4] = (short)cvt1(f3.x); v[5] = (short)cvt1(f3.y);
            v[6] = (short)cvt1(f3.z); v[7] = (short)cvt1(f3.w);
            *(short8*)&As[nxt][r * 32 + pk1 * 8] = v;
        }
        __syncthreads();
        cur = nxt;
    }
    #pragma unroll
    for (int fi = 0; fi < 4; ++fi) {
        const int m0 = bm + wr * 64 + fi * 16 + kg * 4;
        #pragma unroll
        for (int fj = 0; fj < 4; ++fj) {
            const int n = bn + wc * 64 + fj * 16 + fr;
            #pragma unroll
            for (int q = 0; q < 4; ++q) {
                if (CBF) {
                    unsigned short* Cs = (unsigned short*)Cv;
                    Cs[(size_t)(m0 + q) * ldc + n] = cvt1(acc[fi][fj][q]);
                } else {
                    float* Cf = (float*)Cv;
                    Cf[(size_t)(m0 + q) * ldc + n] = acc[fi][fj][q];
                }
            }
        }
    }
}

// ---------------------------------------------------------------------------
// fallback GEMM (fp32 in/out), used only if ws too small
__global__ __launch_bounds__(256) void gemm_mfma(
    const float* __restrict__ A, const float* __restrict__ W,
    float* __restrict__ C, int K, int lda, int ldc)
{
    __shared__ unsigned short As[128 * 32];
    __shared__ unsigned short Ws[128 * 32];
    const int tid = threadIdx.x;
    const int bm = blockIdx.y * 128;
    const int bn = blockIdx.x * 128;
    const int r = tid >> 1;
    const int h = tid & 1;
    const int wv = tid >> 6;
    const int wr = wv >> 1;
    const int wc = wv & 1;
    const int ln = tid & 63;
    const int fr = ln & 15;
    const int kg = ln >> 4;
    f32x4 acc[4][4] = {};
    const float* ga = A + (size_t)(bm + r) * lda + h * 16;
    const float* gw = W + (size_t)(bn + r) * K + h * 16;
    for (int k0 = 0; k0 < K; k0 += 32) {
        #pragma unroll
        for (int p = 0; p < 2; ++p) {
            const int pk = (2 * h + p) ^ ((r >> 1) & 3);
            float4 f0 = *(const float4*)(ga + k0 + p * 8);
            float4 f1 = *(const float4*)(ga + k0 + p * 8 + 4);
            short8 v;
            v[0] = (short)cvt1(f0.x); v[1] = (short)cvt1(f0.y);
            v[2] = (short)cvt1(f0.z); v[3] = (short)cvt1(f0.w);
            v[4] = (short)cvt1(f1.x); v[5] = (short)cvt1(f1.y);
            v[6] = (short)cvt1(f1.z); v[7] = (short)cvt1(f1.w);
            *(short8*)&As[r * 32 + pk * 8] = v;
            f0 = *(const float4*)(gw + k0 + p * 8);
            f1 = *(const float4*)(gw + k0 + p * 8 + 4);
            v[0] = (short)cvt1(f0.x); v[1] = (short)cvt1(f0.y);
            v[2] = (short)cvt1(f0.z); v[3] = (short)cvt1(f0.w);
            v[4] = (short)cvt1(f1.x); v[5] = (short)cvt1(f1.y);
            v[6] = (short)cvt1(f1.z); v[7] = (short)cvt1(f1.w);
            *(short8*)&Ws[r * 32 + pk * 8] = v;
        }
        __syncthreads();
        short8 af[4], bw[4];
        #pragma unroll
        for (int f = 0; f < 4; ++f) {
            const int ra = wr * 64 + f * 16 + fr;
            af[f] = *(const short8*)&As[ra * 32 + ((kg ^ ((ra >> 1) & 3)) * 8)];
            const int rb = wc * 64 + f * 16 + fr;
            bw[f] = *(const short8*)&Ws[rb * 32 + ((kg ^ ((rb >> 1) & 3)) * 8)];
        }
        #pragma unroll
        for (int fi = 0; fi < 4; ++fi)
            #pragma unroll
            for (int fj = 0; fj < 4; ++fj)
                mfma16(acc[fi][fj], af[fi], bw[fj]);
        __syncthreads();
    }
    #pragma unroll
    for (int fi = 0; fi < 4; ++fi) {
        const int m0 = bm + wr * 64 + fi * 16 + kg * 4;
        #pragma unroll
        for (int fj = 0; fj < 4; ++fj) {
            const int n = bn + wc * 64 + fj * 16 + fr;
            #pragma unroll
            for (int q = 0; q < 4; ++q)
                C[(size_t)(m0 + q) * ldc + n] = acc[fi][fj][q];
        }
    }
}

// ---------------------------------------------------------------------------
// dbc = xc @ xp^T, hi/lo-split bf16 MFMA. BM=128, BN=32.
template <int WRDT>
__global__ __launch_bounds__(256) void gemm_xproj(
    const float* __restrict__ A, const float* __restrict__ W,
    float* __restrict__ C, int K, int lda,
    unsigned short* __restrict__ dth, unsigned short* __restrict__ dtl)
{
    __shared__ unsigned short Ah[128 * 32], Al[128 * 32];
    __shared__ unsigned short Wh[32 * 32], Wl[32 * 32];
    const int tid = threadIdx.x;
    const int bm = blockIdx.y * 128;
    const int bn = blockIdx.x * 32;
    const int r = tid >> 1, hf = tid & 1;
    const int wv = tid >> 6;
    const int ln = tid & 63, fr = ln & 15, kg = ln >> 4;
    const int wsr = tid >> 3;
    const int wc4 = (tid & 7) << 2;
    f32x4 acc[2][2] = {};
    const float* ga = A + (size_t)(bm + r) * lda + hf * 16;
    const float* gw = W + (size_t)(bn + wsr) * K + wc4;
    for (int k0 = 0; k0 < K; k0 += 32) {
        #pragma unroll
        for (int j = 0; j < 4; ++j) {
            const int col = hf * 16 + j * 4;
            const int ad = r * 32 + (((col >> 3) ^ ((r >> 1) & 3)) << 3) + (col & 7);
            const float4 fa = *(const float4*)(ga + k0 + j * 4);
            short4v h4, l4;
            #pragma unroll
            for (int e = 0; e < 4; ++e) {
                unsigned short hh, llo;
                split_bf((&fa.x)[e], hh, llo);
                h4[e] = (short)hh; l4[e] = (short)llo;
            }
            *(short4v*)&Ah[ad] = h4;
            *(short4v*)&Al[ad] = l4;
        }
        {
            const int ad = wsr * 32 + (((wc4 >> 3) ^ ((wsr >> 1) & 3)) << 3) + (wc4 & 7);
            const float4 fw = *(const float4*)(gw + k0);
            short4v h4, l4;
            #pragma unroll
            for (int e = 0; e < 4; ++e) {
                unsigned short hh, llo;
                split_bf((&fw.x)[e], hh, llo);
                h4[e] = (short)hh; l4[e] = (short)llo;
            }
            *(short4v*)&Wh[ad] = h4;
            *(short4v*)&Wl[ad] = l4;
        }
        __syncthreads();
        short8 ah[2], alo[2], bh[2], bl[2];
        #pragma unroll
        for (int f = 0; f < 2; ++f) {
            const int ra = wv * 32 + f * 16 + fr;
            const int ao = ra * 32 + ((kg ^ ((ra >> 1) & 3)) * 8);
            ah[f]  = *(const short8*)&Ah[ao];
            alo[f] = *(const short8*)&Al[ao];
            const int rb = f * 16 + fr;
            const int bo = rb * 32 + ((kg ^ ((rb >> 1) & 3)) * 8);
            bh[f] = *(const short8*)&Wh[bo];
            bl[f] = *(const short8*)&Wl[bo];
        }
        #pragma unroll
        for (int fi = 0; fi < 2; ++fi)
            #pragma unroll
            for (int fj = 0; fj < 2; ++fj) {
                mfma16(acc[fi][fj], ah[fi], bh[fj]);
                mfma16(acc[fi][fj], ah[fi], bl[fj]);
                mfma16(acc[fi][fj], alo[fi], bh[fj]);
            }
        __syncthreads();
    }
    #pragma unroll
    for (int fi = 0; fi < 2; ++fi) {
        const int m0 = bm + wv * 32 + fi * 16 + kg * 4;
        #pragma unroll
        for (int fj = 0; fj < 2; ++fj) {
            const int n = bn + fj * 16 + fr;
            #pragma unroll
            for (int q = 0; q < 4; ++q) {
                const float v = acc[fi][fj][q];
                C[(size_t)(m0 + q) * NDBC + n] = v;
                if (WRDT && n < DTR) {
                    unsigned short hh, llo;
                    split_bf(v, hh, llo);
                    dth[(size_t)(m0 + q) * DTR + n] = hh;
                    dtl[(size_t)(m0 + q) * DTR + n] = llo;
                }
            }
        }
    }
}

// ---------------------------------------------------------------------------
// delta (fallback): split in-kernel from fp32 dbc/dtw. K=64.
__global__ __launch_bounds__(256) void gemm_delta(
    const float* __restrict__ A, const float* __restrict__ W,
    float* __restrict__ C, const float* __restrict__ bias)
{
    __shared__ unsigned short Ah[128 * 32], Al[128 * 32];
    __shared__ unsigned short Wh[128 * 32], Wl[128 * 32];
    const int tid = threadIdx.x;
    const int bm = blockIdx.y * 128;
    const int bn = blockIdx.x * 128;
    const int r = tid >> 1, hf = tid & 1;
    const int wv = tid >> 6, wr = wv >> 1, wc = wv & 1;
    const int ln = tid & 63, fr = ln & 15, kg = ln >> 4;
    f32x4 acc[4][4] = {};
    const float* ga = A + (size_t)(bm + r) * NDBC + hf * 16;
    const float* gw = W + (size_t)(bn + r) * DTR + hf * 16;
    for (int k0 = 0; k0 < DTR; k0 += 32) {
        #pragma unroll
        for (int j = 0; j < 4; ++j) {
            const int col = hf * 16 + j * 4;
            const int ad = r * 32 + (((col >> 3) ^ ((r >> 1) & 3)) << 3) + (col & 7);
            const float4 fa = *(const float4*)(ga + k0 + j * 4);
            const float4 fw = *(const float4*)(gw + k0 + j * 4);
            short4v ah4, al4, wh4, wl4;
            #pragma unroll
            for (int e = 0; e < 4; ++e) {
                unsigned short hh, llo;
                split_bf((&fa.x)[e], hh, llo);
                ah4[e] = (short)hh; al4[e] = (short)llo;
                split_bf((&fw.x)[e], hh, llo);
                wh4[e] = (short)hh; wl4[e] = (short)llo;
            }
            *(short4v*)&Ah[ad] = ah4; *(short4v*)&Al[ad] = al4;
            *(short4v*)&Wh[ad] = wh4; *(short4v*)&Wl[ad] = wl4;
        }
        __syncthreads();
        short8 ah[4], alo[4], bh[4], bl[4];
        #pragma unroll
        for (int f = 0; f < 4; ++f) {
            const int ra = wr * 64 + f * 16 + fr;
            const int ao = ra * 32 + ((kg ^ ((ra >> 1) & 3)) * 8);
            ah[f]  = *(const short8*)&Ah[ao];
            alo[f] = *(const short8*)&Al[ao];
            const int rb = wc * 64 + f * 16 + fr;
            const int bo = rb * 32 + ((kg ^ ((rb >> 1) & 3)) * 8);
            bh[f] = *(const short8*)&Wh[bo];
            bl[f] = *(const short8*)&Wl[bo];
        }
        #pragma unroll
        for (int fi = 0; fi < 4; ++fi)
            #pragma unroll
            for (int fj = 0; fj < 4; ++fj) {
                mfma16(acc[fi][fj], ah[fi], bh[fj]);
                mfma16(acc[fi][fj], ah[fi], bl[fj]);
                mfma16(acc[fi][fj], alo[fi], bh[fj]);
            }
        __syncthreads();
    }
    #pragma unroll
    for (int fi = 0; fi < 4; ++fi) {
        const int m0 = bm + wr * 64 + fi * 16 + kg * 4;
        #pragma unroll
        for (int fj = 0; fj < 4; ++fj) {
            const int n = bn + wc * 64 + fj * 16 + fr;
            const float bb = bias[n];
            #pragma unroll
            for (int q = 0; q < 4; ++q) {
                float v = acc[fi][fj][q] + bb;
                v = (v > 20.f) ? v : log1pf(__expf(v));
                C[(size_t)(m0 + q) * NXZ + n] = v;
            }
        }
    }
}

// ---------------------------------------------------------------------------
// delta (fast): all operands pre-split bf16; single stage via gload, K=64.
__global__ __launch_bounds__(256) void gemm_delta_pre(
    const unsigned short* __restrict__ Ahg, const unsigned short* __restrict__ Alg,
    const unsigned short* __restrict__ Whg, const unsigned short* __restrict__ Wlg,
    float* __restrict__ C, const float* __restrict__ bias)
{
    __shared__ unsigned short sAh[128 * 64], sAl[128 * 64];
    __shared__ unsigned short sWh[128 * 64], sWl[128 * 64];
    const int tid = threadIdx.x;
    const int bm = blockIdx.y * 128;
    const int bn = blockIdx.x * 128;
    const int wv = tid >> 6, ln = tid & 63;
    const int wr = wv >> 1, wc = wv & 1;
    const int fr = ln & 15, kg = ln >> 4;
    const int srow = ln >> 3;
    const int g = ln & 7;
    const int half = g >> 2, sub = g & 3;
    #pragma unroll
    for (int j = 0; j < 4; ++j) {
        const int row = wv * 32 + j * 8 + srow;
        const int sub2 = sub ^ ((row >> 1) & 3);
        const int scol = half * 32 + sub2 * 8;
        const int dst = (wv * 32 + j * 8) * 64;
        gload16(Ahg + (size_t)(bm + row) * DTR + scol, sAh + dst);
        gload16(Alg + (size_t)(bm + row) * DTR + scol, sAl + dst);
        gload16(Whg + (size_t)(bn + row) * DTR + scol, sWh + dst);
        gload16(Wlg + (size_t)(bn + row) * DTR + scol, sWl + dst);
    }
    __syncthreads();
    f32x4 acc[4][4] = {};
    #pragma unroll
    for (int ks = 0; ks < 2; ++ks) {
        short8 ah[4], alo[4], bh[4], bl[4];
        #pragma unroll
        for (int f = 0; f < 4; ++f) {
            const int ra = wr * 64 + f * 16 + fr;
            const int ao = ra * 64 + ks * 32 + ((kg ^ ((ra >> 1) & 3)) * 8);
            ah[f]  = *(const short8*)&sAh[ao];
            alo[f] = *(const short8*)&sAl[ao];
            const int rb = wc * 64 + f * 16 + fr;
            const int bo = rb * 64 + ks * 32 + ((kg ^ ((rb >> 1) & 3)) * 8);
            bh[f] = *(const short8*)&sWh[bo];
            bl[f] = *(const short8*)&sWl[bo];
        }
        #pragma unroll
        for (int fi = 0; fi < 4; ++fi)
            #pragma unroll
            for (int fj = 0; fj < 4; ++fj) {
                mfma16(acc[fi][fj], ah[fi], bh[fj]);
                mfma16(acc[fi][fj], ah[fi], bl[fj]);
                mfma16(acc[fi][fj], alo[fi], bh[fj]);
            }
    }
    #pragma unroll
    for (int fi = 0; fi < 4; ++fi) {
        const int m0 = bm + wr * 64 + fi * 16 + kg * 4;
        #pragma unroll
        for (int fj = 0; fj < 4; ++fj) {
            const int n = bn + wc * 64 + fj * 16 + fr;
            const float bb = bias[n];
            #pragma unroll
            for (int q = 0; q < 4; ++q) {
                float v = acc[fi][fj][q] + bb;
                v = (v > 20.f) ? v : log1pf(__expf(v));
                C[(size_t)(m0 + q) * NXZ + n] = v;
            }
        }
    }
}

// ---------------------------------------------------------------------------
// conv+silu: 4 consecutive timesteps per thread.
__global__ __launch_bounds__(256) void conv_silu(
    const float* __restrict__ xz, const float* __restrict__ cw,
    const float* __restrict__ cb, float* __restrict__ xc)
{
    const int g = blockIdx.x * 256 + threadIdx.x;
    const int c4 = g & (DI / 4 - 1);
    const int mq = g >> 9;
    const int m0 = mq << 2;
    const int l0 = m0 & (SL - 1);
    const int c = c4 << 2;
    const float4 w0 = *(const float4*)(cw + (size_t)(c + 0) * DCONV);
    const float4 w1 = *(const float4*)(cw + (size_t)(c + 1) * DCONV);
    const float4 w2 = *(const float4*)(cw + (size_t)(c + 2) * DCONV);
    const float4 w3 = *(const float4*)(cw + (size_t)(c + 3) * DCONV);
    const float4 cb4 = *(const float4*)(cb + c);
    float4 x[7];
    #pragma unroll
    for (int i = 0; i < 7; ++i) {
        if (l0 - 3 + i >= 0)
            x[i] = *(const float4*)(xz + (size_t)(m0 - 3 + i) * NXZ + c);
        else
            x[i] = make_float4(0.f, 0.f, 0.f, 0.f);
    }
    #pragma unroll
    for (int j = 0; j < 4; ++j) {
        float4 acc = cb4;
        #pragma unroll
        for (int k = 0; k < DCONV; ++k) {
            const float4 v = x[j + k];
            acc.x = fmaf(v.x, (&w0.x)[k], acc.x);
            acc.y = fmaf(v.y, (&w1.x)[k], acc.y);
            acc.z = fmaf(v.z, (&w2.x)[k], acc.z);
            acc.w = fmaf(v.w, (&w3.x)[k], acc.w);
        }
        acc.x = acc.x / (1.f + __expf(-acc.x));
        acc.y = acc.y / (1.f + __expf(-acc.y));
        acc.z = acc.z / (1.f + __expf(-acc.z));
        acc.w = acc.w / (1.f + __expf(-acc.w));
        *(float4*)(xc + (size_t)(m0 + j) * DI + c) = acc;
    }
}

// ---------------------------------------------------------------------------
// Selective scan: DPP reduce, p0/p1 in registers, sy double-buffered.
// YBF=1: write y as bf16 (same cvt1 RNE out_proj staging would apply).
template <int YBF>
__global__ __launch_bounds__(256) void scan_k(
    const float* u, const float* __restrict__ dbc,
    const float* __restrict__ xz, void* __restrict__ yv,
    const float* __restrict__ Alog, const float* __restrict__ Dl)
{
    const int b = blockIdx.y;
    const int c0 = blockIdx.x * 16;
    const int tid = threadIdx.x;
    const int ch = tid >> 4;
    const int s = tid & 15;
    const float Aa = -__expf(Alog[(size_t)(c0 + ch) * DS + s]) * 1.44269504088896f;
    __shared__ float sdl[16][68];
    __shared__ float sxb[16][68];
    __shared__ float sbc[32][68];
    __shared__ float sy[2][64][16];
    __shared__ float sD[16];
    if (tid < 16) sD[tid] = Dl[c0 + tid];
    __syncthreads();
    float h = 0.f;
    const int row = tid >> 2;
    const int q = (tid & 3) << 2;
    int pp = 0;
    for (int t0b = 0; t0b < SL; t0b += 64) {
        const size_t mb = (size_t)b * SL + t0b;
        const float4 dlv = *(const float4*)(xz + (mb + row) * NXZ + c0 + q);
        const float4 uv  = *(const float4*)(u  + (mb + row) * DI + c0 + q);
        const float4 zv  = *(const float4*)(xz + (mb + row) * NXZ + DI + c0 + q);
        float4 p0, p1;
        #pragma unroll
        for (int j = 0; j < 4; ++j) {
            const float dl = (&dlv.x)[j], uu = (&uv.x)[j], zz = (&zv.x)[j];
            const float w = zz / (1.f + __expf(-zz));
            sdl[q + j][row] = dl;
            sxb[q + j][row] = dl * uu;
            (&p1.x)[j] = w;
            (&p0.x)[j] = uu * sD[q + j] * w;
        }
        #pragma unroll
        for (int p = 0; p < 2; ++p) {
            const int idx = p * 256 + tid;
            const int r2 = idx >> 3, q2 = (idx & 7) << 2;
            const float4 v = *(const float4*)(dbc + (mb + r2) * NDBC + DTR + q2);
            sbc[q2 + 0][r2] = v.x; sbc[q2 + 1][r2] = v.y;
            sbc[q2 + 2][r2] = v.z; sbc[q2 + 3][r2] = v.w;
        }
        __syncthreads();
        for (int it = 0; it < 16; ++it) {
            const int t0 = it * 4;
            const float4 dl4 = *(const float4*)&sdl[ch][t0];
            const float4 xb4 = *(const float4*)&sxb[ch][t0];
            const float4 B4  = *(const float4*)&sbc[s][t0];
            const float4 C4  = *(const float4*)&sbc[16 + s][t0];
            float py0, py1, py2, py3;
            {
                const float dA = exp2_raw(dl4.x * Aa);
                h = fmaf(dA, h, xb4.x * B4.x);
                py0 = dpp_sum16(h * C4.x);
            }
            {
                const float dA = exp2_raw(dl4.y * Aa);
                h = fmaf(dA, h, xb4.y * B4.y);
                py1 = dpp_sum16(h * C4.y);
            }
            {
                const float dA = exp2_raw(dl4.z * Aa);
                h = fmaf(dA, h, xb4.z * B4.z);
                py2 = dpp_sum16(h * C4.z);
            }
            {
                const float dA = exp2_raw(dl4.w * Aa);
                h = fmaf(dA, h, xb4.w * B4.w);
                py3 = dpp_sum16(h * C4.w);
            }
            if (s < 4) {
                const int t = t0 + s;
                const float lo_ = (s & 1) ? py1 : py0;
                const float hi_ = (s & 1) ? py3 : py2;
                sy[pp][t][ch] = (s & 2) ? hi_ : lo_;
            }
        }
        __syncthreads();
        if (YBF) {
            unsigned short* y16 = (unsigned short*)yv;
            short4v s4;
            #pragma unroll
            for (int e = 0; e < 4; ++e)
                s4[e] = (short)cvt1(fmaf(sy[pp][row][q + e],
                                         (&p1.x)[e], (&p0.x)[e]));
            *(short4v*)(y16 + (mb + row) * DI + c0 + q) = s4;
        } else {
            float* y = (float*)yv;
            float4 yvv;
            #pragma unroll
            for (int e = 0; e < 4; ++e)
                (&yvv.x)[e] = fmaf(sy[pp][row][q + e], (&p1.x)[e], (&p0.x)[e]);
            *(float4*)(y + (mb + row) * DI + c0 + q) = yvv;
        }
        pp ^= 1;
    }
}

// ---------------------------------------------------------------------------
extern "C" void kernel_launch(void* const* d_in, const int* in_sizes, int n_in,
                              void* d_out, int out_size, void* d_ws, size_t ws_size,
                              hipStream_t stream)
{
    const float* x0   = (const float*)d_in[0];
    const float* in_w = (const float*)d_in[1];
    const float* cw   = (const float*)d_in[2];
    const float* cb   = (const float*)d_in[3];
    const float* xpw  = (const float*)d_in[4];
    const float* dtw  = (const float*)d_in[5];
    const float* dtb  = (const float*)d_in[6];
    const float* Alog = (const float*)d_in[7];
    const float* Dp   = (const float*)d_in[8];
    const float* ow   = (const float*)d_in[9];

    const size_t perB = (size_t)SL * (NXZ + DI + NDBC) * sizeof(float); // ~51.1MB
    const size_t wby  = ((size_t)NXZ * DIMK + (size_t)DIMK * DI) * 2;   // 12.6MB
    int nbc = 0, fast = 0;
    if (ws_size >= 4 * perB + wby)      { nbc = 4; fast = 1; }
    else if (ws_size >= 2 * perB + wby) { nbc = 2; fast = 1; }
    else if (ws_size >= perB + wby)     { nbc = 1; fast = 1; }
    else if (ws_size >= 4 * perB)       { nbc = 4; }
    else if (ws_size >= 2 * perB)       { nbc = 2; }
    else if (ws_size >= perB)           { nbc = 1; }
    else return;
    const int nchunks = NB / nbc;
    const int M = nbc * SL;
    const size_t dtby = ((size_t)DI * DTR * 2 + (size_t)M * DTR * 2) * 2;
    const size_t yby  = (size_t)M * DI * 2;          // y16 buffer
    const size_t base = (size_t)nbc * perB + wby;
    const int fastd = fast && (ws_size >= base + dtby);
    const int fasty = fastd && (ws_size >= base + dtby + yby);

    float* xz  = (float*)d_ws;
    float* xc  = xz + (size_t)M * NXZ;
    float* dbc = xc + (size_t)M * DI;
    unsigned short* wi16 = (unsigned short*)(dbc + (size_t)M * NDBC);
    unsigned short* ow16 = wi16 + (size_t)NXZ * DIMK;
    unsigned short* dtwh = ow16 + (size_t)DIMK * DI;
    unsigned short* dtwl = dtwh + (size_t)DI * DTR;
    unsigned short* dth  = dtwl + (size_t)DI * DTR;
    unsigned short* dtl  = dth + (size_t)M * DTR;
    unsigned short* y16  = dtl + (size_t)M * DTR;

    unsigned short* xb16 = (unsigned short*)d_out + (size_t)MT * DIMK;
    float* xbuf = (float*)d_out;

    const dim3 blk(256);
    const int ncv = (NXZ * DIMK / 4) + (DIMK * DI / 4) + (DI * DTR / 4);
    for (int ly = 0; ly < NDEPTH; ++ly) {
        const float* Wi   = in_w + (size_t)ly * NXZ * DIMK;
        const float* cwl  = cw   + (size_t)ly * DI * DCONV;
        const float* cbl  = cb   + (size_t)ly * DI;
        const float* xpl  = xpw  + (size_t)ly * NDBC * DI;
        const float* dtwl_ = dtw + (size_t)ly * DI * DTR;
        const float* dtbl = dtb  + (size_t)ly * DI;
        const float* Al   = Alog + (size_t)ly * DI * DS;
        const float* Dl   = Dp   + (size_t)ly * DI;
        const float* owl  = ow   + (size_t)ly * DIMK * DI;

        if (fast)
            cvt_layer<<<dim3((ncv + 255) / 256), blk, 0, stream>>>(
                Wi, owl, dtwl_, wi16, ow16, dtwh, dtwl, fastd);

        for (int ck = 0; ck < nchunks; ++ck) {
            if (fast) {
                // 1. xz = x @ Wi^T. Layer 0 takes fp32 x0 directly (gemm_fb);
                //    later layers take bf16 x from out_proj (gemm_bb).
                if (ly == 0) {
                    const float* xin = x0 + (size_t)ck * M * DIMK;
                    gemm_fb<0><<<dim3(NXZ / 128, M / 128), blk, 0, stream>>>(
                        xin, wi16, xz, DIMK, DIMK, DIMK, NXZ);
                } else {
                    const unsigned short* xin16 = xb16 + (size_t)ck * M * DIMK;
                    gemm_bb<0><<<dim3(NXZ / 128, M / 128), blk, 0, stream>>>(
                        xin16, wi16, xz, DIMK, DIMK, DIMK, NXZ);
                }
                conv_silu<<<dim3(M * (DI / 16) / 256), blk, 0, stream>>>(
                    xz, cwl, cbl, xc);
            } else {
                const float* xin = (ly == 0 ? x0 : xbuf) + (size_t)ck * M * DIMK;
                gemm_mfma<<<dim3(NXZ / 128, M / 128), blk, 0, stream>>>(
                    xin, Wi, xz, DIMK, DIMK, NXZ);
                conv_silu<<<dim3(M * (DI / 16) / 256), blk, 0, stream>>>(
                    xz, cwl, cbl, xc);
            }
            // 2. x_proj + delta
            if (fastd) {
                gemm_xproj<1><<<dim3(3, M / 128), blk, 0, stream>>>(
                    xc, xpl, dbc, DI, DI, dth, dtl);
                gemm_delta_pre<<<dim3(DI / 128, M / 128), blk, 0, stream>>>(
                    dth, dtl, dtwh, dtwl, xz, dtbl);
            } else {
                gemm_xproj<0><<<dim3(3, M / 128), blk, 0, stream>>>(
                    xc, xpl, dbc, DI, DI, nullptr, nullptr);
                gemm_delta<<<dim3(DI / 128, M / 128), blk, 0, stream>>>(
                    dbc, dtwl_, xz, dtbl);
            }
            // 3. scan
            if (fasty) {
                scan_k<1><<<dim3(DI / 16, nbc), blk, 0, stream>>>(
                    xc, dbc, xz, y16, Al, Dl);
            } else {
                scan_k<0><<<dim3(DI / 16, nbc), blk, 0, stream>>>(
                    xc, dbc, xz, xc, Al, Dl);
            }
            // 4. out_proj
            if (fast) {
                void* dst = (ly < NDEPTH - 1)
                    ? (void*)(xb16 + (size_t)ck * M * DIMK)
                    : (void*)((float*)d_out + (size_t)ck * M * DIMK);
                if (fasty) {
                    if (ly < NDEPTH - 1)
                        gemm_bb<1><<<dim3(DIMK / 128, M / 128), blk, 0, stream>>>(
                            y16, ow16, dst, DI, DI, DI, DIMK);
                    else
                        gemm_bb<0><<<dim3(DIMK / 128, M / 128), blk, 0, stream>>>(
                            y16, ow16, dst, DI, DI, DI, DIMK);
                } else {
                    if (ly < NDEPTH - 1)
                        gemm_fb<1><<<dim3(DIMK / 128, M / 128), blk, 0, stream>>>(
                            xc, ow16, dst, DI, DI, DI, DIMK);
                    else
                        gemm_fb<0><<<dim3(DIMK / 128, M / 128), blk, 0, stream>>>(
                            xc, ow16, dst, DI, DI, DI, DIMK);
                }
            } else {
                float* xdst = (ly == NDEPTH - 1 ? (float*)d_out : xbuf) +
                              (size_t)ck * M * DIMK;
                gemm_mfma<<<dim3(DIMK / 128, M / 128), blk, 0, stream>>>(
                    xc, owl, xdst, DI, DI, DIMK);
            }
        }
    }
}

// Round 11
// 1650.321 us; speedup vs baseline: 1.4684x; 1.1643x over previous
//
#include <hip/hip_runtime.h>
#include <hip/hip_bf16.h>
#include <math.h>

#define DIMK 1024
#define NDEPTH 4
#define DS 16
#define DCONV 4
#define DI 2048
#define DTR 64
#define NB 4
#define SL 2048
#define MT (NB * SL)        // 8192
#define NXZ (2 * DI)        // 4096
#define NDBC (DTR + 2 * DS) // 96

typedef float f32x4 __attribute__((ext_vector_type(4)));
typedef short short8 __attribute__((ext_vector_type(8)));
typedef short short4v __attribute__((ext_vector_type(4)));

__device__ inline unsigned short f2bf(float f) {
    unsigned u = __builtin_bit_cast(unsigned, f);
    unsigned r = (u + 0x7FFFu + ((u >> 16) & 1u)) >> 16;
    return (unsigned short)r;
}
__device__ inline float bf2f(unsigned short h) {
    unsigned u = ((unsigned)h) << 16;
    return __builtin_bit_cast(float, u);
}
__device__ inline void split_bf(float f, unsigned short& hi, unsigned short& lo) {
    hi = f2bf(f);
    lo = f2bf(f - bf2f(hi));
}
__device__ inline unsigned short cvt1(float f) {
    __hip_bfloat16 t = __float2bfloat16(f);
    return __builtin_bit_cast(unsigned short, t);
}
__device__ inline void mfma16(f32x4& d, short8 a, short8 b) {
    asm volatile("v_mfma_f32_16x16x32_bf16 %0, %1, %2, %0"
                 : "+v"(d) : "v"(a), "v"(b));
}
__device__ __forceinline__ float dpp_sum16(float p) {
    asm("v_add_f32_dpp %0, %0, %0 quad_perm:[1,0,3,2] row_mask:0xf bank_mask:0xf bound_ctrl:0" : "+v"(p));
    asm("v_add_f32_dpp %0, %0, %0 quad_perm:[2,3,0,1] row_mask:0xf bank_mask:0xf bound_ctrl:0" : "+v"(p));
    asm("v_add_f32_dpp %0, %0, %0 row_ror:4 row_mask:0xf bank_mask:0xf bound_ctrl:0" : "+v"(p));
    asm("v_add_f32_dpp %0, %0, %0 row_ror:8 row_mask:0xf bank_mask:0xf bound_ctrl:0" : "+v"(p));
    return p;
}
__device__ __forceinline__ float exp2_raw(float x) {
    float r;
    asm("v_exp_f32 %0, %1" : "=v"(r) : "v"(x));
    return r;
}
__device__ __forceinline__ void gload16(const unsigned short* g, unsigned short* l) {
    __builtin_amdgcn_global_load_lds(
        (const __attribute__((address_space(1))) unsigned int*)(g),
        (__attribute__((address_space(3))) unsigned int*)(l),
        16, 0, 0);
}

// ---------------------------------------------------------------------------
__global__ __launch_bounds__(256) void cvt_bf16(
    const float* __restrict__ s, unsigned short* __restrict__ d, int n4)
{
    const int g = blockIdx.x * 256 + threadIdx.x;
    if (g < n4) {
        const float4 f = *(const float4*)(s + (size_t)g * 4);
        short4v v;
        v[0] = (short)cvt1(f.x); v[1] = (short)cvt1(f.y);
        v[2] = (short)cvt1(f.z); v[3] = (short)cvt1(f.w);
        *(short4v*)(d + (size_t)g * 4) = v;
    }
}

// merged per-layer weight conversions: wi, ow -> bf16; dtw, xpw -> split
__global__ __launch_bounds__(256) void cvt_layer(
    const float* __restrict__ wi, const float* __restrict__ owp,
    const float* __restrict__ dtwp, const float* __restrict__ xpwp,
    unsigned short* __restrict__ wi16, unsigned short* __restrict__ ow16,
    unsigned short* __restrict__ dtwh, unsigned short* __restrict__ dtwl,
    unsigned short* __restrict__ xpwh, unsigned short* __restrict__ xpwl,
    int fastd, int fastx)
{
    int g = blockIdx.x * 256 + threadIdx.x;
    const int n4w = NXZ * DIMK / 4;
    const int n4o = DIMK * DI / 4;
    const int n4d = DI * DTR / 4;
    const int n4x = NDBC * DI / 4;
    if (g < n4w) {
        const float4 f = *(const float4*)(wi + (size_t)g * 4);
        short4v v;
        v[0] = (short)cvt1(f.x); v[1] = (short)cvt1(f.y);
        v[2] = (short)cvt1(f.z); v[3] = (short)cvt1(f.w);
        *(short4v*)(wi16 + (size_t)g * 4) = v;
        return;
    }
    g -= n4w;
    if (g < n4o) {
        const float4 f = *(const float4*)(owp + (size_t)g * 4);
        short4v v;
        v[0] = (short)cvt1(f.x); v[1] = (short)cvt1(f.y);
        v[2] = (short)cvt1(f.z); v[3] = (short)cvt1(f.w);
        *(short4v*)(ow16 + (size_t)g * 4) = v;
        return;
    }
    g -= n4o;
    if (g < n4d) {
        if (fastd) {
            const float4 f = *(const float4*)(dtwp + (size_t)g * 4);
            short4v h4, l4;
            #pragma unroll
            for (int e = 0; e < 4; ++e) {
                unsigned short h, l;
                split_bf((&f.x)[e], h, l);
                h4[e] = (short)h; l4[e] = (short)l;
            }
            *(short4v*)(dtwh + (size_t)g * 4) = h4;
            *(short4v*)(dtwl + (size_t)g * 4) = l4;
        }
        return;
    }
    g -= n4d;
    if (g < n4x && fastx) {
        const float4 f = *(const float4*)(xpwp + (size_t)g * 4);
        short4v h4, l4;
        #pragma unroll
        for (int e = 0; e < 4; ++e) {
            unsigned short h, l;
            split_bf((&f.x)[e], h, l);
            h4[e] = (short)h; l4[e] = (short)l;
        }
        *(short4v*)(xpwh + (size_t)g * 4) = h4;
        *(short4v*)(xpwl + (size_t)g * 4) = l4;
    }
}

// ---------------------------------------------------------------------------
// C[m,n] = sum_k A[m,k]*B[n,k]; A,B bf16 global. 2-phase dbuf + XCD swizzle.
template <int CBF>
__global__ __launch_bounds__(256) void gemm_bb(
    const unsigned short* __restrict__ A, const unsigned short* __restrict__ B,
    void* __restrict__ Cv, int K, int lda, int ldb, int ldc)
{
    __shared__ unsigned short As[2][128 * 32];
    __shared__ unsigned short Bs[2][128 * 32];
    int id = blockIdx.y * gridDim.x + blockIdx.x;
    const int qq = (gridDim.x * gridDim.y) >> 3;
    id = (id & 7) * qq + (id >> 3);
    const int bm = (id / gridDim.x) * 128, bn = (id % gridDim.x) * 128;

    const int tid = threadIdx.x;
    const int wv = tid >> 6, ln = tid & 63;
    const int wr = wv >> 1, wc = wv & 1;
    const int fr = ln & 15, kg = ln >> 4;
    const int sr0 = wv * 32 + (ln >> 2);
    const int sr1 = sr0 + 16;
    const int sl = ln & 3;
    const int cg0 = sl ^ ((sr0 >> 1) & 3);
    const int cg1 = sl ^ ((sr1 >> 1) & 3);
    const unsigned short* pa0 = A + (size_t)(bm + sr0) * lda + cg0 * 8;
    const unsigned short* pa1 = A + (size_t)(bm + sr1) * lda + cg1 * 8;
    const unsigned short* pb0 = B + (size_t)(bn + sr0) * ldb + cg0 * 8;
    const unsigned short* pb1 = B + (size_t)(bn + sr1) * ldb + cg1 * 8;
    const int ldst0 = (wv * 32 + 0) * 32;
    const int ldst1 = (wv * 32 + 16) * 32;
    int offA[4], offB[4];
    #pragma unroll
    for (int f = 0; f < 4; ++f) {
        const int ra = wr * 64 + f * 16 + fr;
        offA[f] = ra * 32 + ((kg ^ ((ra >> 1) & 3)) * 8);
        const int rb = wc * 64 + f * 16 + fr;
        offB[f] = rb * 32 + ((kg ^ ((rb >> 1) & 3)) * 8);
    }
    f32x4 acc[4][4] = {};
    gload16(pa0, &As[0][ldst0]);
    gload16(pa1, &As[0][ldst1]);
    gload16(pb0, &Bs[0][ldst0]);
    gload16(pb1, &Bs[0][ldst1]);
    __syncthreads();
    int cur = 0;
    for (int k0 = 0; k0 < K; k0 += 32) {
        const int nxt = cur ^ 1;
        if (k0 + 32 < K) {
            gload16(pa0 + k0 + 32, &As[nxt][ldst0]);
            gload16(pa1 + k0 + 32, &As[nxt][ldst1]);
            gload16(pb0 + k0 + 32, &Bs[nxt][ldst0]);
            gload16(pb1 + k0 + 32, &Bs[nxt][ldst1]);
        }
        short8 af[4], bw[4];
        #pragma unroll
        for (int f = 0; f < 4; ++f) {
            af[f] = *(const short8*)&As[cur][offA[f]];
            bw[f] = *(const short8*)&Bs[cur][offB[f]];
        }
        #pragma unroll
        for (int fi = 0; fi < 4; ++fi)
            #pragma unroll
            for (int fj = 0; fj < 4; ++fj)
                mfma16(acc[fi][fj], af[fi], bw[fj]);
        __syncthreads();
        cur = nxt;
    }
    #pragma unroll
    for (int fi = 0; fi < 4; ++fi) {
        const int m0 = bm + wr * 64 + fi * 16 + kg * 4;
        #pragma unroll
        for (int fj = 0; fj < 4; ++fj) {
            const int n = bn + wc * 64 + fj * 16 + fr;
            #pragma unroll
            for (int q = 0; q < 4; ++q) {
                if (CBF) {
                    unsigned short* Cs = (unsigned short*)Cv;
                    Cs[(size_t)(m0 + q) * ldc + n] = cvt1(acc[fi][fj][q]);
                } else {
                    float* Cf = (float*)Cv;
                    Cf[(size_t)(m0 + q) * ldc + n] = acc[fi][fj][q];
                }
            }
        }
    }
}

// ---------------------------------------------------------------------------
// A fp32 (reg prefetch + cvt after MFMA), B bf16 (gload dbuf). CBF: bf16 C.
template <int CBF>
__global__ __launch_bounds__(256) void gemm_fb(
    const float* __restrict__ A, const unsigned short* __restrict__ B,
    void* __restrict__ Cv, int K, int lda, int ldb, int ldc)
{
    __shared__ unsigned short As[2][128 * 32];
    __shared__ unsigned short Bs[2][128 * 32];
    int id = blockIdx.y * gridDim.x + blockIdx.x;
    const int qq = (gridDim.x * gridDim.y) >> 3;
    id = (id & 7) * qq + (id >> 3);
    const int bm = (id / gridDim.x) * 128, bn = (id % gridDim.x) * 128;

    const int tid = threadIdx.x;
    const int wv = tid >> 6, ln = tid & 63;
    const int wr = wv >> 1, wc = wv & 1;
    const int fr = ln & 15, kg = ln >> 4;
    const int r = tid >> 1, hf = tid & 1;
    const int sr0 = wv * 32 + (ln >> 2);
    const int sr1 = sr0 + 16;
    const int sl = ln & 3;
    const int cg0 = sl ^ ((sr0 >> 1) & 3);
    const int cg1 = sl ^ ((sr1 >> 1) & 3);
    const unsigned short* pb0 = B + (size_t)(bn + sr0) * ldb + cg0 * 8;
    const unsigned short* pb1 = B + (size_t)(bn + sr1) * ldb + cg1 * 8;
    const int ldst0 = (wv * 32 + 0) * 32;
    const int ldst1 = (wv * 32 + 16) * 32;
    const float* ga = A + (size_t)(bm + r) * lda + hf * 16;
    const int pk0 = (2 * hf + 0) ^ ((r >> 1) & 3);
    const int pk1 = (2 * hf + 1) ^ ((r >> 1) & 3);
    int offA[4], offB[4];
    #pragma unroll
    for (int f = 0; f < 4; ++f) {
        const int ra = wr * 64 + f * 16 + fr;
        offA[f] = ra * 32 + ((kg ^ ((ra >> 1) & 3)) * 8);
        const int rb = wc * 64 + f * 16 + fr;
        offB[f] = rb * 32 + ((kg ^ ((rb >> 1) & 3)) * 8);
    }
    f32x4 acc[4][4] = {};
    {
        float4 f0 = *(const float4*)(ga + 0);
        float4 f1 = *(const float4*)(ga + 4);
        float4 f2 = *(const float4*)(ga + 8);
        float4 f3 = *(const float4*)(ga + 12);
        short8 v;
        v[0] = (short)cvt1(f0.x); v[1] = (short)cvt1(f0.y);
        v[2] = (short)cvt1(f0.z); v[3] = (short)cvt1(f0.w);
        v[4] = (short)cvt1(f1.x); v[5] = (short)cvt1(f1.y);
        v[6] = (short)cvt1(f1.z); v[7] = (short)cvt1(f1.w);
        *(short8*)&As[0][r * 32 + pk0 * 8] = v;
        v[0] = (short)cvt1(f2.x); v[1] = (short)cvt1(f2.y);
        v[2] = (short)cvt1(f2.z); v[3] = (short)cvt1(f2.w);
        v[4] = (short)cvt1(f3.x); v[5] = (short)cvt1(f3.y);
        v[6] = (short)cvt1(f3.z); v[7] = (short)cvt1(f3.w);
        *(short8*)&As[0][r * 32 + pk1 * 8] = v;
        gload16(pb0, &Bs[0][ldst0]);
        gload16(pb1, &Bs[0][ldst1]);
    }
    __syncthreads();
    int cur = 0;
    for (int k0 = 0; k0 < K; k0 += 32) {
        const int nxt = cur ^ 1;
        const bool more = (k0 + 32 < K);
        float4 f0, f1, f2, f3;
        if (more) {
            gload16(pb0 + k0 + 32, &Bs[nxt][ldst0]);
            gload16(pb1 + k0 + 32, &Bs[nxt][ldst1]);
            f0 = *(const float4*)(ga + k0 + 32);
            f1 = *(const float4*)(ga + k0 + 36);
            f2 = *(const float4*)(ga + k0 + 40);
            f3 = *(const float4*)(ga + k0 + 44);
        }
        short8 af[4], bw[4];
        #pragma unroll
        for (int f = 0; f < 4; ++f) {
            af[f] = *(const short8*)&As[cur][offA[f]];
            bw[f] = *(const short8*)&Bs[cur][offB[f]];
        }
        #pragma unroll
        for (int fi = 0; fi < 4; ++fi)
            #pragma unroll
            for (int fj = 0; fj < 4; ++fj)
                mfma16(acc[fi][fj], af[fi], bw[fj]);
        if (more) {
            short8 v;
            v[0] = (short)cvt1(f0.x); v[1] = (short)cvt1(f0.y);
            v[2] = (short)cvt1(f0.z); v[3] = (short)cvt1(f0.w);
            v[4] = (short)cvt1(f1.x); v[5] = (short)cvt1(f1.y);
            v[6] = (short)cvt1(f1.z); v[7] = (short)cvt1(f1.w);
            *(short8*)&As[nxt][r * 32 + pk0 * 8] = v;
            v[0] = (short)cvt1(f2.x); v[1] = (short)cvt1(f2.y);
            v[2] = (short)cvt1(f2.z); v[3] = (short)cvt1(f2.w);
            v[4] = (short)cvt1(f3.x); v[5] = (short)cvt1(f3.y);
            v[6] = (short)cvt1(f3.z); v[7] = (short)cvt1(f3.w);
            *(short8*)&As[nxt][r * 32 + pk1 * 8] = v;
        }
        __syncthreads();
        cur = nxt;
    }
    #pragma unroll
    for (int fi = 0; fi < 4; ++fi) {
        const int m0 = bm + wr * 64 + fi * 16 + kg * 4;
        #pragma unroll
        for (int fj = 0; fj < 4; ++fj) {
            const int n = bn + wc * 64 + fj * 16 + fr;
            #pragma unroll
            for (int q = 0; q < 4; ++q) {
                if (CBF) {
                    unsigned short* Cs = (unsigned short*)Cv;
                    Cs[(size_t)(m0 + q) * ldc + n] = cvt1(acc[fi][fj][q]);
                } else {
                    float* Cf = (float*)Cv;
                    Cf[(size_t)(m0 + q) * ldc + n] = acc[fi][fj][q];
                }
            }
        }
    }
}

// ---------------------------------------------------------------------------
// fallback GEMM (fp32 in/out), used only if ws too small
__global__ __launch_bounds__(256) void gemm_mfma(
    const float* __restrict__ A, const float* __restrict__ W,
    float* __restrict__ C, int K, int lda, int ldc)
{
    __shared__ unsigned short As[128 * 32];
    __shared__ unsigned short Ws[128 * 32];
    const int tid = threadIdx.x;
    const int bm = blockIdx.y * 128;
    const int bn = blockIdx.x * 128;
    const int r = tid >> 1;
    const int h = tid & 1;
    const int wv = tid >> 6;
    const int wr = wv >> 1;
    const int wc = wv & 1;
    const int ln = tid & 63;
    const int fr = ln & 15;
    const int kg = ln >> 4;
    f32x4 acc[4][4] = {};
    const float* ga = A + (size_t)(bm + r) * lda + h * 16;
    const float* gw = W + (size_t)(bn + r) * K + h * 16;
    for (int k0 = 0; k0 < K; k0 += 32) {
        #pragma unroll
        for (int p = 0; p < 2; ++p) {
            const int pk = (2 * h + p) ^ ((r >> 1) & 3);
            float4 f0 = *(const float4*)(ga + k0 + p * 8);
            float4 f1 = *(const float4*)(ga + k0 + p * 8 + 4);
            short8 v;
            v[0] = (short)cvt1(f0.x); v[1] = (short)cvt1(f0.y);
            v[2] = (short)cvt1(f0.z); v[3] = (short)cvt1(f0.w);
            v[4] = (short)cvt1(f1.x); v[5] = (short)cvt1(f1.y);
            v[6] = (short)cvt1(f1.z); v[7] = (short)cvt1(f1.w);
            *(short8*)&As[r * 32 + pk * 8] = v;
            f0 = *(const float4*)(gw + k0 + p * 8);
            f1 = *(const float4*)(gw + k0 + p * 8 + 4);
            v[0] = (short)cvt1(f0.x); v[1] = (short)cvt1(f0.y);
            v[2] = (short)cvt1(f0.z); v[3] = (short)cvt1(f0.w);
            v[4] = (short)cvt1(f1.x); v[5] = (short)cvt1(f1.y);
            v[6] = (short)cvt1(f1.z); v[7] = (short)cvt1(f1.w);
            *(short8*)&Ws[r * 32 + pk * 8] = v;
        }
        __syncthreads();
        short8 af[4], bw[4];
        #pragma unroll
        for (int f = 0; f < 4; ++f) {
            const int ra = wr * 64 + f * 16 + fr;
            af[f] = *(const short8*)&As[ra * 32 + ((kg ^ ((ra >> 1) & 3)) * 8)];
            const int rb = wc * 64 + f * 16 + fr;
            bw[f] = *(const short8*)&Ws[rb * 32 + ((kg ^ ((rb >> 1) & 3)) * 8)];
        }
        #pragma unroll
        for (int fi = 0; fi < 4; ++fi)
            #pragma unroll
            for (int fj = 0; fj < 4; ++fj)
                mfma16(acc[fi][fj], af[fi], bw[fj]);
        __syncthreads();
    }
    #pragma unroll
    for (int fi = 0; fi < 4; ++fi) {
        const int m0 = bm + wr * 64 + fi * 16 + kg * 4;
        #pragma unroll
        for (int fj = 0; fj < 4; ++fj) {
            const int n = bn + wc * 64 + fj * 16 + fr;
            #pragma unroll
            for (int q = 0; q < 4; ++q)
                C[(size_t)(m0 + q) * ldc + n] = acc[fi][fj][q];
        }
    }
}

// ---------------------------------------------------------------------------
// x_proj fast: A = pre-split xc (xch/xcl), W = pre-split xpw. Pure gload+MFMA.
// BM=128, BN=32, K=DI. Emits dbc fp32 + split dt cols (dth/dtl).
__global__ __launch_bounds__(256) void gemm_xproj_pre(
    const unsigned short* __restrict__ Ahg, const unsigned short* __restrict__ Alg,
    const unsigned short* __restrict__ Whg, const unsigned short* __restrict__ Wlg,
    float* __restrict__ C,
    unsigned short* __restrict__ dth, unsigned short* __restrict__ dtl)
{
    __shared__ unsigned short Ahs[2][128 * 32], Als[2][128 * 32];
    __shared__ unsigned short Whs[2][32 * 32], Wls[2][32 * 32];
    int id = blockIdx.y * gridDim.x + blockIdx.x;
    const int qq = (gridDim.x * gridDim.y) >> 3;
    id = (id & 7) * qq + (id >> 3);
    const int bm = (id / gridDim.x) * 128, bn = (id % gridDim.x) * 32;

    const int tid = threadIdx.x;
    const int wv = tid >> 6, ln = tid & 63;
    const int fr = ln & 15, kg = ln >> 4;
    const int sr0 = wv * 32 + (ln >> 2);
    const int sr1 = sr0 + 16;
    const int sl = ln & 3;
    const int cg0 = sl ^ ((sr0 >> 1) & 3);
    const int cg1 = sl ^ ((sr1 >> 1) & 3);
    const unsigned short* pah0 = Ahg + (size_t)(bm + sr0) * DI + cg0 * 8;
    const unsigned short* pah1 = Ahg + (size_t)(bm + sr1) * DI + cg1 * 8;
    const unsigned short* pal0 = Alg + (size_t)(bm + sr0) * DI + cg0 * 8;
    const unsigned short* pal1 = Alg + (size_t)(bm + sr1) * DI + cg1 * 8;
    const int lA0 = (wv * 32 + 0) * 32;
    const int lA1 = (wv * 32 + 16) * 32;
    // W staging: waves 0,1 -> Wh rows (wv&1)*16..; waves 2,3 -> Wl rows
    const int wrow = (wv & 1) * 16 + (ln >> 2);
    const int cgw = sl ^ ((wrow >> 1) & 3);
    const unsigned short* pw = ((wv < 2) ? Whg : Wlg) + (size_t)(bn + wrow) * DI + cgw * 8;
    const int lW = ((wv & 1) * 16) * 32;
    unsigned short* wdst[2];
    wdst[0] = (wv < 2) ? &Whs[0][lW] : &Wls[0][lW];
    wdst[1] = (wv < 2) ? &Whs[1][lW] : &Wls[1][lW];

    int offA[2], offW[2];
    #pragma unroll
    for (int f = 0; f < 2; ++f) {
        const int ra = wv * 32 + f * 16 + fr;
        offA[f] = ra * 32 + ((kg ^ ((ra >> 1) & 3)) * 8);
        const int rb = f * 16 + fr;
        offW[f] = rb * 32 + ((kg ^ ((rb >> 1) & 3)) * 8);
    }
    f32x4 acc[2][2] = {};
    gload16(pah0, &Ahs[0][lA0]);
    gload16(pah1, &Ahs[0][lA1]);
    gload16(pal0, &Als[0][lA0]);
    gload16(pal1, &Als[0][lA1]);
    gload16(pw, wdst[0]);
    __syncthreads();
    int cur = 0;
    for (int k0 = 0; k0 < DI; k0 += 32) {
        const int nxt = cur ^ 1;
        if (k0 + 32 < DI) {
            gload16(pah0 + k0 + 32, &Ahs[nxt][lA0]);
            gload16(pah1 + k0 + 32, &Ahs[nxt][lA1]);
            gload16(pal0 + k0 + 32, &Als[nxt][lA0]);
            gload16(pal1 + k0 + 32, &Als[nxt][lA1]);
            gload16(pw + k0 + 32, wdst[nxt]);
        }
        short8 ah[2], alo[2], bh[2], bl[2];
        #pragma unroll
        for (int f = 0; f < 2; ++f) {
            ah[f]  = *(const short8*)&Ahs[cur][offA[f]];
            alo[f] = *(const short8*)&Als[cur][offA[f]];
            bh[f]  = *(const short8*)&Whs[cur][offW[f]];
            bl[f]  = *(const short8*)&Wls[cur][offW[f]];
        }
        #pragma unroll
        for (int fi = 0; fi < 2; ++fi)
            #pragma unroll
            for (int fj = 0; fj < 2; ++fj) {
                mfma16(acc[fi][fj], ah[fi], bh[fj]);
                mfma16(acc[fi][fj], ah[fi], bl[fj]);
                mfma16(acc[fi][fj], alo[fi], bh[fj]);
            }
        __syncthreads();
        cur = nxt;
    }
    #pragma unroll
    for (int fi = 0; fi < 2; ++fi) {
        const int m0 = bm + wv * 32 + fi * 16 + kg * 4;
        #pragma unroll
        for (int fj = 0; fj < 2; ++fj) {
            const int n = bn + fj * 16 + fr;
            #pragma unroll
            for (int q = 0; q < 4; ++q) {
                const float v = acc[fi][fj][q];
                C[(size_t)(m0 + q) * NDBC + n] = v;
                if (n < DTR) {
                    unsigned short hh, llo;
                    split_bf(v, hh, llo);
                    dth[(size_t)(m0 + q) * DTR + n] = hh;
                    dtl[(size_t)(m0 + q) * DTR + n] = llo;
                }
            }
        }
    }
}

// ---------------------------------------------------------------------------
// x_proj fallback: split in-kernel from fp32 xc. BM=128, BN=32.
template <int WRDT>
__global__ __launch_bounds__(256) void gemm_xproj(
    const float* __restrict__ A, const float* __restrict__ W,
    float* __restrict__ C, int K, int lda,
    unsigned short* __restrict__ dth, unsigned short* __restrict__ dtl)
{
    __shared__ unsigned short Ah[128 * 32], Al[128 * 32];
    __shared__ unsigned short Wh[32 * 32], Wl[32 * 32];
    const int tid = threadIdx.x;
    const int bm = blockIdx.y * 128;
    const int bn = blockIdx.x * 32;
    const int r = tid >> 1, hf = tid & 1;
    const int wv = tid >> 6;
    const int ln = tid & 63, fr = ln & 15, kg = ln >> 4;
    const int wsr = tid >> 3;
    const int wc4 = (tid & 7) << 2;
    f32x4 acc[2][2] = {};
    const float* ga = A + (size_t)(bm + r) * lda + hf * 16;
    const float* gw = W + (size_t)(bn + wsr) * K + wc4;
    for (int k0 = 0; k0 < K; k0 += 32) {
        #pragma unroll
        for (int j = 0; j < 4; ++j) {
            const int col = hf * 16 + j * 4;
            const int ad = r * 32 + (((col >> 3) ^ ((r >> 1) & 3)) << 3) + (col & 7);
            const float4 fa = *(const float4*)(ga + k0 + j * 4);
            short4v h4, l4;
            #pragma unroll
            for (int e = 0; e < 4; ++e) {
                unsigned short hh, llo;
                split_bf((&fa.x)[e], hh, llo);
                h4[e] = (short)hh; l4[e] = (short)llo;
            }
            *(short4v*)&Ah[ad] = h4;
            *(short4v*)&Al[ad] = l4;
        }
        {
            const int ad = wsr * 32 + (((wc4 >> 3) ^ ((wsr >> 1) & 3)) << 3) + (wc4 & 7);
            const float4 fw = *(const float4*)(gw + k0);
            short4v h4, l4;
            #pragma unroll
            for (int e = 0; e < 4; ++e) {
                unsigned short hh, llo;
                split_bf((&fw.x)[e], hh, llo);
                h4[e] = (short)hh; l4[e] = (short)llo;
            }
            *(short4v*)&Wh[ad] = h4;
            *(short4v*)&Wl[ad] = l4;
        }
        __syncthreads();
        short8 ah[2], alo[2], bh[2], bl[2];
        #pragma unroll
        for (int f = 0; f < 2; ++f) {
            const int ra = wv * 32 + f * 16 + fr;
            const int ao = ra * 32 + ((kg ^ ((ra >> 1) & 3)) * 8);
            ah[f]  = *(const short8*)&Ah[ao];
            alo[f] = *(const short8*)&Al[ao];
            const int rb = f * 16 + fr;
            const int bo = rb * 32 + ((kg ^ ((rb >> 1) & 3)) * 8);
            bh[f] = *(const short8*)&Wh[bo];
            bl[f] = *(const short8*)&Wl[bo];
        }
        #pragma unroll
        for (int fi = 0; fi < 2; ++fi)
            #pragma unroll
            for (int fj = 0; fj < 2; ++fj) {
                mfma16(acc[fi][fj], ah[fi], bh[fj]);
                mfma16(acc[fi][fj], ah[fi], bl[fj]);
                mfma16(acc[fi][fj], alo[fi], bh[fj]);
            }
        __syncthreads();
    }
    #pragma unroll
    for (int fi = 0; fi < 2; ++fi) {
        const int m0 = bm + wv * 32 + fi * 16 + kg * 4;
        #pragma unroll
        for (int fj = 0; fj < 2; ++fj) {
            const int n = bn + fj * 16 + fr;
            #pragma unroll
            for (int q = 0; q < 4; ++q) {
                const float v = acc[fi][fj][q];
                C[(size_t)(m0 + q) * NDBC + n] = v;
                if (WRDT && n < DTR) {
                    unsigned short hh, llo;
                    split_bf(v, hh, llo);
                    dth[(size_t)(m0 + q) * DTR + n] = hh;
                    dtl[(size_t)(m0 + q) * DTR + n] = llo;
                }
            }
        }
    }
}

// ---------------------------------------------------------------------------
// delta (fallback): split in-kernel from fp32 dbc/dtw. K=64.
__global__ __launch_bounds__(256) void gemm_delta(
    const float* __restrict__ A, const float* __restrict__ W,
    float* __restrict__ C, const float* __restrict__ bias)
{
    __shared__ unsigned short Ah[128 * 32], Al[128 * 32];
    __shared__ unsigned short Wh[128 * 32], Wl[128 * 32];
    const int tid = threadIdx.x;
    const int bm = blockIdx.y * 128;
    const int bn = blockIdx.x * 128;
    const int r = tid >> 1, hf = tid & 1;
    const int wv = tid >> 6, wr = wv >> 1, wc = wv & 1;
    const int ln = tid & 63, fr = ln & 15, kg = ln >> 4;
    f32x4 acc[4][4] = {};
    const float* ga = A + (size_t)(bm + r) * NDBC + hf * 16;
    const float* gw = W + (size_t)(bn + r) * DTR + hf * 16;
    for (int k0 = 0; k0 < DTR; k0 += 32) {
        #pragma unroll
        for (int j = 0; j < 4; ++j) {
            const int col = hf * 16 + j * 4;
            const int ad = r * 32 + (((col >> 3) ^ ((r >> 1) & 3)) << 3) + (col & 7);
            const float4 fa = *(const float4*)(ga + k0 + j * 4);
            const float4 fw = *(const float4*)(gw + k0 + j * 4);
            short4v ah4, al4, wh4, wl4;
            #pragma unroll
            for (int e = 0; e < 4; ++e) {
                unsigned short hh, llo;
                split_bf((&fa.x)[e], hh, llo);
                ah4[e] = (short)hh; al4[e] = (short)llo;
                split_bf((&fw.x)[e], hh, llo);
                wh4[e] = (short)hh; wl4[e] = (short)llo;
            }
            *(short4v*)&Ah[ad] = ah4; *(short4v*)&Al[ad] = al4;
            *(short4v*)&Wh[ad] = wh4; *(short4v*)&Wl[ad] = wl4;
        }
        __syncthreads();
        short8 ah[4], alo[4], bh[4], bl[4];
        #pragma unroll
        for (int f = 0; f < 4; ++f) {
            const int ra = wr * 64 + f * 16 + fr;
            const int ao = ra * 32 + ((kg ^ ((ra >> 1) & 3)) * 8);
            ah[f]  = *(const short8*)&Ah[ao];
            alo[f] = *(const short8*)&Al[ao];
            const int rb = wc * 64 + f * 16 + fr;
            const int bo = rb * 32 + ((kg ^ ((rb >> 1) & 3)) * 8);
            bh[f] = *(const short8*)&Wh[bo];
            bl[f] = *(const short8*)&Wl[bo];
        }
        #pragma unroll
        for (int fi = 0; fi < 4; ++fi)
            #pragma unroll
            for (int fj = 0; fj < 4; ++fj) {
                mfma16(acc[fi][fj], ah[fi], bh[fj]);
                mfma16(acc[fi][fj], ah[fi], bl[fj]);
                mfma16(acc[fi][fj], alo[fi], bh[fj]);
            }
        __syncthreads();
    }
    #pragma unroll
    for (int fi = 0; fi < 4; ++fi) {
        const int m0 = bm + wr * 64 + fi * 16 + kg * 4;
        #pragma unroll
        for (int fj = 0; fj < 4; ++fj) {
            const int n = bn + wc * 64 + fj * 16 + fr;
            const float bb = bias[n];
            #pragma unroll
            for (int q = 0; q < 4; ++q) {
                float v = acc[fi][fj][q] + bb;
                v = (v > 20.f) ? v : log1pf(__expf(v));
                C[(size_t)(m0 + q) * NXZ + n] = v;
            }
        }
    }
}

// ---------------------------------------------------------------------------
// delta (fast): all operands pre-split bf16; single stage via gload, K=64.
__global__ __launch_bounds__(256) void gemm_delta_pre(
    const unsigned short* __restrict__ Ahg, const unsigned short* __restrict__ Alg,
    const unsigned short* __restrict__ Whg, const unsigned short* __restrict__ Wlg,
    float* __restrict__ C, const float* __restrict__ bias)
{
    __shared__ unsigned short sAh[128 * 64], sAl[128 * 64];
    __shared__ unsigned short sWh[128 * 64], sWl[128 * 64];
    const int tid = threadIdx.x;
    const int bm = blockIdx.y * 128;
    const int bn = blockIdx.x * 128;
    const int wv = tid >> 6, ln = tid & 63;
    const int wr = wv >> 1, wc = wv & 1;
    const int fr = ln & 15, kg = ln >> 4;
    const int srow = ln >> 3;
    const int g = ln & 7;
    const int half = g >> 2, sub = g & 3;
    #pragma unroll
    for (int j = 0; j < 4; ++j) {
        const int row = wv * 32 + j * 8 + srow;
        const int sub2 = sub ^ ((row >> 1) & 3);
        const int scol = half * 32 + sub2 * 8;
        const int dst = (wv * 32 + j * 8) * 64;
        gload16(Ahg + (size_t)(bm + row) * DTR + scol, sAh + dst);
        gload16(Alg + (size_t)(bm + row) * DTR + scol, sAl + dst);
        gload16(Whg + (size_t)(bn + row) * DTR + scol, sWh + dst);
        gload16(Wlg + (size_t)(bn + row) * DTR + scol, sWl + dst);
    }
    __syncthreads();
    f32x4 acc[4][4] = {};
    #pragma unroll
    for (int ks = 0; ks < 2; ++ks) {
        short8 ah[4], alo[4], bh[4], bl[4];
        #pragma unroll
        for (int f = 0; f < 4; ++f) {
            const int ra = wr * 64 + f * 16 + fr;
            const int ao = ra * 64 + ks * 32 + ((kg ^ ((ra >> 1) & 3)) * 8);
            ah[f]  = *(const short8*)&sAh[ao];
            alo[f] = *(const short8*)&sAl[ao];
            const int rb = wc * 64 + f * 16 + fr;
            const int bo = rb * 64 + ks * 32 + ((kg ^ ((rb >> 1) & 3)) * 8);
            bh[f] = *(const short8*)&sWh[bo];
            bl[f] = *(const short8*)&sWl[bo];
        }
        #pragma unroll
        for (int fi = 0; fi < 4; ++fi)
            #pragma unroll
            for (int fj = 0; fj < 4; ++fj) {
                mfma16(acc[fi][fj], ah[fi], bh[fj]);
                mfma16(acc[fi][fj], ah[fi], bl[fj]);
                mfma16(acc[fi][fj], alo[fi], bh[fj]);
            }
    }
    #pragma unroll
    for (int fi = 0; fi < 4; ++fi) {
        const int m0 = bm + wr * 64 + fi * 16 + kg * 4;
        #pragma unroll
        for (int fj = 0; fj < 4; ++fj) {
            const int n = bn + wc * 64 + fj * 16 + fr;
            const float bb = bias[n];
            #pragma unroll
            for (int q = 0; q < 4; ++q) {
                float v = acc[fi][fj][q] + bb;
                v = (v > 20.f) ? v : log1pf(__expf(v));
                C[(size_t)(m0 + q) * NXZ + n] = v;
            }
        }
    }
}

// ---------------------------------------------------------------------------
// conv+silu, fp32 out (fallback path)
__global__ __launch_bounds__(256) void conv_silu(
    const float* __restrict__ xz, const float* __restrict__ cw,
    const float* __restrict__ cb, float* __restrict__ xc)
{
    const int g = blockIdx.x * 256 + threadIdx.x;
    const int c4 = g & (DI / 4 - 1);
    const int mq = g >> 9;
    const int m0 = mq << 2;
    const int l0 = m0 & (SL - 1);
    const int c = c4 << 2;
    const float4 w0 = *(const float4*)(cw + (size_t)(c + 0) * DCONV);
    const float4 w1 = *(const float4*)(cw + (size_t)(c + 1) * DCONV);
    const float4 w2 = *(const float4*)(cw + (size_t)(c + 2) * DCONV);
    const float4 w3 = *(const float4*)(cw + (size_t)(c + 3) * DCONV);
    const float4 cb4 = *(const float4*)(cb + c);
    float4 x[7];
    #pragma unroll
    for (int i = 0; i < 7; ++i) {
        if (l0 - 3 + i >= 0)
            x[i] = *(const float4*)(xz + (size_t)(m0 - 3 + i) * NXZ + c);
        else
            x[i] = make_float4(0.f, 0.f, 0.f, 0.f);
    }
    #pragma unroll
    for (int j = 0; j < 4; ++j) {
        float4 acc = cb4;
        #pragma unroll
        for (int k = 0; k < DCONV; ++k) {
            const float4 v = x[j + k];
            acc.x = fmaf(v.x, (&w0.x)[k], acc.x);
            acc.y = fmaf(v.y, (&w1.x)[k], acc.y);
            acc.z = fmaf(v.z, (&w2.x)[k], acc.z);
            acc.w = fmaf(v.w, (&w3.x)[k], acc.w);
        }
        acc.x = acc.x / (1.f + __expf(-acc.x));
        acc.y = acc.y / (1.f + __expf(-acc.y));
        acc.z = acc.z / (1.f + __expf(-acc.z));
        acc.w = acc.w / (1.f + __expf(-acc.w));
        *(float4*)(xc + (size_t)(m0 + j) * DI + c) = acc;
    }
}

// conv+silu, split bf16 (hi,lo) out — same split xproj applied in-kernel.
__global__ __launch_bounds__(256) void conv_silu_split(
    const float* __restrict__ xz, const float* __restrict__ cw,
    const float* __restrict__ cb, unsigned short* __restrict__ xch,
    unsigned short* __restrict__ xcl)
{
    const int g = blockIdx.x * 256 + threadIdx.x;
    const int c4 = g & (DI / 4 - 1);
    const int mq = g >> 9;
    const int m0 = mq << 2;
    const int l0 = m0 & (SL - 1);
    const int c = c4 << 2;
    const float4 w0 = *(const float4*)(cw + (size_t)(c + 0) * DCONV);
    const float4 w1 = *(const float4*)(cw + (size_t)(c + 1) * DCONV);
    const float4 w2 = *(const float4*)(cw + (size_t)(c + 2) * DCONV);
    const float4 w3 = *(const float4*)(cw + (size_t)(c + 3) * DCONV);
    const float4 cb4 = *(const float4*)(cb + c);
    float4 x[7];
    #pragma unroll
    for (int i = 0; i < 7; ++i) {
        if (l0 - 3 + i >= 0)
            x[i] = *(const float4*)(xz + (size_t)(m0 - 3 + i) * NXZ + c);
        else
            x[i] = make_float4(0.f, 0.f, 0.f, 0.f);
    }
    #pragma unroll
    for (int j = 0; j < 4; ++j) {
        float4 acc = cb4;
        #pragma unroll
        for (int k = 0; k < DCONV; ++k) {
            const float4 v = x[j + k];
            acc.x = fmaf(v.x, (&w0.x)[k], acc.x);
            acc.y = fmaf(v.y, (&w1.x)[k], acc.y);
            acc.z = fmaf(v.z, (&w2.x)[k], acc.z);
            acc.w = fmaf(v.w, (&w3.x)[k], acc.w);
        }
        short4v h4, l4;
        #pragma unroll
        for (int e = 0; e < 4; ++e) {
            float a = (&acc.x)[e];
            a = a / (1.f + __expf(-a));
            unsigned short hh, llo;
            split_bf(a, hh, llo);
            h4[e] = (short)hh; l4[e] = (short)llo;
        }
        *(short4v*)(xch + (size_t)(m0 + j) * DI + c) = h4;
        *(short4v*)(xcl + (size_t)(m0 + j) * DI + c) = l4;
    }
}

// ---------------------------------------------------------------------------
// Selective scan. YBF: y as bf16. UBF: u from split pair (u = hi + lo).
template <int YBF, int UBF>
__global__ __launch_bounds__(256) void scan_k(
    const float* uf, const unsigned short* __restrict__ uh,
    const unsigned short* __restrict__ ul,
    const float* __restrict__ dbc,
    const float* __restrict__ xz, void* __restrict__ yv,
    const float* __restrict__ Alog, const float* __restrict__ Dl)
{
    const int b = blockIdx.y;
    const int c0 = blockIdx.x * 16;
    const int tid = threadIdx.x;
    const int ch = tid >> 4;
    const int s = tid & 15;
    const float Aa = -__expf(Alog[(size_t)(c0 + ch) * DS + s]) * 1.44269504088896f;
    __shared__ float sdl[16][68];
    __shared__ float sxb[16][68];
    __shared__ float sbc[32][68];
    __shared__ float sy[2][64][16];
    __shared__ float sD[16];
    if (tid < 16) sD[tid] = Dl[c0 + tid];
    __syncthreads();
    float h = 0.f;
    const int row = tid >> 2;
    const int q = (tid & 3) << 2;
    int pp = 0;
    for (int t0b = 0; t0b < SL; t0b += 64) {
        const size_t mb = (size_t)b * SL + t0b;
        const float4 dlv = *(const float4*)(xz + (mb + row) * NXZ + c0 + q);
        float4 uv;
        if (UBF) {
            const short4v uh4 = *(const short4v*)(uh + (mb + row) * DI + c0 + q);
            const short4v ul4 = *(const short4v*)(ul + (mb + row) * DI + c0 + q);
            #pragma unroll
            for (int e = 0; e < 4; ++e)
                (&uv.x)[e] = bf2f((unsigned short)uh4[e]) +
                             bf2f((unsigned short)ul4[e]);
        } else {
            uv = *(const float4*)(uf + (mb + row) * DI + c0 + q);
        }
        const float4 zv = *(const float4*)(xz + (mb + row) * NXZ + DI + c0 + q);
        float4 p0, p1;
        #pragma unroll
        for (int j = 0; j < 4; ++j) {
            const float dl = (&dlv.x)[j], uu = (&uv.x)[j], zz = (&zv.x)[j];
            const float w = zz / (1.f + __expf(-zz));
            sdl[q + j][row] = dl;
            sxb[q + j][row] = dl * uu;
            (&p1.x)[j] = w;
            (&p0.x)[j] = uu * sD[q + j] * w;
        }
        #pragma unroll
        for (int p = 0; p < 2; ++p) {
            const int idx = p * 256 + tid;
            const int r2 = idx >> 3, q2 = (idx & 7) << 2;
            const float4 v = *(const float4*)(dbc + (mb + r2) * NDBC + DTR + q2);
            sbc[q2 + 0][r2] = v.x; sbc[q2 + 1][r2] = v.y;
            sbc[q2 + 2][r2] = v.z; sbc[q2 + 3][r2] = v.w;
        }
        __syncthreads();
        for (int it = 0; it < 16; ++it) {
            const int t0 = it * 4;
            const float4 dl4 = *(const float4*)&sdl[ch][t0];
            const float4 xb4 = *(const float4*)&sxb[ch][t0];
            const float4 B4  = *(const float4*)&sbc[s][t0];
            const float4 C4  = *(const float4*)&sbc[16 + s][t0];
            float py0, py1, py2, py3;
            {
                const float dA = exp2_raw(dl4.x * Aa);
                h = fmaf(dA, h, xb4.x * B4.x);
                py0 = dpp_sum16(h * C4.x);
            }
            {
                const float dA = exp2_raw(dl4.y * Aa);
                h = fmaf(dA, h, xb4.y * B4.y);
                py1 = dpp_sum16(h * C4.y);
            }
            {
                const float dA = exp2_raw(dl4.z * Aa);
                h = fmaf(dA, h, xb4.z * B4.z);
                py2 = dpp_sum16(h * C4.z);
            }
            {
                const float dA = exp2_raw(dl4.w * Aa);
                h = fmaf(dA, h, xb4.w * B4.w);
                py3 = dpp_sum16(h * C4.w);
            }
            if (s < 4) {
                const int t = t0 + s;
                const float lo_ = (s & 1) ? py1 : py0;
                const float hi_ = (s & 1) ? py3 : py2;
                sy[pp][t][ch] = (s & 2) ? hi_ : lo_;
            }
        }
        __syncthreads();
        if (YBF) {
            unsigned short* y16 = (unsigned short*)yv;
            short4v s4;
            #pragma unroll
            for (int e = 0; e < 4; ++e)
                s4[e] = (short)cvt1(fmaf(sy[pp][row][q + e],
                                         (&p1.x)[e], (&p0.x)[e]));
            *(short4v*)(y16 + (mb + row) * DI + c0 + q) = s4;
        } else {
            float* y = (float*)yv;
            float4 yvv;
            #pragma unroll
            for (int e = 0; e < 4; ++e)
                (&yvv.x)[e] = fmaf(sy[pp][row][q + e], (&p1.x)[e], (&p0.x)[e]);
            *(float4*)(y + (mb + row) * DI + c0 + q) = yvv;
        }
        pp ^= 1;
    }
}

// ---------------------------------------------------------------------------
extern "C" void kernel_launch(void* const* d_in, const int* in_sizes, int n_in,
                              void* d_out, int out_size, void* d_ws, size_t ws_size,
                              hipStream_t stream)
{
    const float* x0   = (const float*)d_in[0];
    const float* in_w = (const float*)d_in[1];
    const float* cw   = (const float*)d_in[2];
    const float* cb   = (const float*)d_in[3];
    const float* xpw  = (const float*)d_in[4];
    const float* dtw  = (const float*)d_in[5];
    const float* dtb  = (const float*)d_in[6];
    const float* Alog = (const float*)d_in[7];
    const float* Dp   = (const float*)d_in[8];
    const float* ow   = (const float*)d_in[9];

    const size_t perB = (size_t)SL * (NXZ + DI + NDBC) * sizeof(float); // ~51.1MB
    const size_t wby  = ((size_t)NXZ * DIMK + (size_t)DIMK * DI) * 2;   // 12.6MB
    int nbc = 0, fast = 0;
    if (ws_size >= 4 * perB + wby)      { nbc = 4; fast = 1; }
    else if (ws_size >= 2 * perB + wby) { nbc = 2; fast = 1; }
    else if (ws_size >= perB + wby)     { nbc = 1; fast = 1; }
    else if (ws_size >= 4 * perB)       { nbc = 4; }
    else if (ws_size >= 2 * perB)       { nbc = 2; }
    else if (ws_size >= perB)           { nbc = 1; }
    else return;
    const int nchunks = NB / nbc;
    const int M = nbc * SL;
    const size_t dtby = ((size_t)DI * DTR * 2 + (size_t)M * DTR * 2) * 2;
    const size_t yby  = (size_t)M * DI * 2;            // y16
    const size_t xpby = (size_t)NDBC * DI * 2 * 2;     // xpwh + xpwl
    const size_t base = (size_t)nbc * perB + wby;
    const int fastd = fast && (ws_size >= base + dtby);
    const int fasty = fastd && (ws_size >= base + dtby + yby);
    const int fastx = fasty && (ws_size >= base + dtby + yby + xpby);

    float* xz  = (float*)d_ws;
    float* xc  = xz + (size_t)M * NXZ;   // fp32 xc OR (xch | xcl) split pair
    float* dbc = xc + (size_t)M * DI;
    unsigned short* xch = (unsigned short*)xc;          // [M, DI] bf16 hi
    unsigned short* xcl = xch + (size_t)M * DI;         // [M, DI] bf16 lo
    unsigned short* wi16 = (unsigned short*)(dbc + (size_t)M * NDBC);
    unsigned short* ow16 = wi16 + (size_t)NXZ * DIMK;
    unsigned short* dtwh = ow16 + (size_t)DIMK * DI;
    unsigned short* dtwl = dtwh + (size_t)DI * DTR;
    unsigned short* dth  = dtwl + (size_t)DI * DTR;
    unsigned short* dtl  = dth + (size_t)M * DTR;
    unsigned short* y16  = dtl + (size_t)M * DTR;
    unsigned short* xpwh = y16 + (size_t)M * DI;
    unsigned short* xpwl = xpwh + (size_t)NDBC * DI;

    unsigned short* xb16 = (unsigned short*)d_out + (size_t)MT * DIMK;
    float* xbuf = (float*)d_out;

    const dim3 blk(256);
    if (fastx) {
        const int n4x = MT * DIMK / 4;
        cvt_bf16<<<dim3(n4x / 256), blk, 0, stream>>>(x0, xb16, n4x);
    }
    const int ncv = (NXZ * DIMK / 4) + (DIMK * DI / 4) + (DI * DTR / 4) +
                    (NDBC * DI / 4);
    for (int ly = 0; ly < NDEPTH; ++ly) {
        const float* Wi   = in_w + (size_t)ly * NXZ * DIMK;
        const float* cwl  = cw   + (size_t)ly * DI * DCONV;
        const float* cbl  = cb   + (size_t)ly * DI;
        const float* xpl  = xpw  + (size_t)ly * NDBC * DI;
        const float* dtwl_ = dtw + (size_t)ly * DI * DTR;
        const float* dtbl = dtb  + (size_t)ly * DI;
        const float* Al   = Alog + (size_t)ly * DI * DS;
        const float* Dl   = Dp   + (size_t)ly * DI;
        const float* owl  = ow   + (size_t)ly * DIMK * DI;

        if (fast)
            cvt_layer<<<dim3((ncv + 255) / 256), blk, 0, stream>>>(
                Wi, owl, dtwl_, xpl, wi16, ow16, dtwh, dtwl, xpwh, xpwl,
                fastd, fastx);

        for (int ck = 0; ck < nchunks; ++ck) {
            if (fastx) {
                // ---- fastest path: all bf16 operand GEMMs ----
                const unsigned short* xin16 = xb16 + (size_t)ck * M * DIMK;
                gemm_bb<0><<<dim3(NXZ / 128, M / 128), blk, 0, stream>>>(
                    xin16, wi16, xz, DIMK, DIMK, DIMK, NXZ);
                conv_silu_split<<<dim3(M * (DI / 16) / 256), blk, 0, stream>>>(
                    xz, cwl, cbl, xch, xcl);
                gemm_xproj_pre<<<dim3(3, M / 128), blk, 0, stream>>>(
                    xch, xcl, xpwh, xpwl, dbc, dth, dtl);
                gemm_delta_pre<<<dim3(DI / 128, M / 128), blk, 0, stream>>>(
                    dth, dtl, dtwh, dtwl, xz, dtbl);
                scan_k<1, 1><<<dim3(DI / 16, nbc), blk, 0, stream>>>(
                    nullptr, xch, xcl, dbc, xz, y16, Al, Dl);
                void* dst = (ly < NDEPTH - 1)
                    ? (void*)(xb16 + (size_t)ck * M * DIMK)
                    : (void*)((float*)d_out + (size_t)ck * M * DIMK);
                if (ly < NDEPTH - 1)
                    gemm_bb<1><<<dim3(DIMK / 128, M / 128), blk, 0, stream>>>(
                        y16, ow16, dst, DI, DI, DI, DIMK);
                else
                    gemm_bb<0><<<dim3(DIMK / 128, M / 128), blk, 0, stream>>>(
                        y16, ow16, dst, DI, DI, DI, DIMK);
            } else if (fast) {
                // ---- round-10 path ----
                if (ly == 0) {
                    const float* xin = x0 + (size_t)ck * M * DIMK;
                    gemm_fb<0><<<dim3(NXZ / 128, M / 128), blk, 0, stream>>>(
                        xin, wi16, xz, DIMK, DIMK, DIMK, NXZ);
                } else {
                    const unsigned short* xin16 = xb16 + (size_t)ck * M * DIMK;
                    gemm_bb<0><<<dim3(NXZ / 128, M / 128), blk, 0, stream>>>(
                        xin16, wi16, xz, DIMK, DIMK, DIMK, NXZ);
                }
                conv_silu<<<dim3(M * (DI / 16) / 256), blk, 0, stream>>>(
                    xz, cwl, cbl, xc);
                if (fastd) {
                    gemm_xproj<1><<<dim3(3, M / 128), blk, 0, stream>>>(
                        xc, xpl, dbc, DI, DI, dth, dtl);
                    gemm_delta_pre<<<dim3(DI / 128, M / 128), blk, 0, stream>>>(
                        dth, dtl, dtwh, dtwl, xz, dtbl);
                } else {
                    gemm_xproj<0><<<dim3(3, M / 128), blk, 0, stream>>>(
                        xc, xpl, dbc, DI, DI, nullptr, nullptr);
                    gemm_delta<<<dim3(DI / 128, M / 128), blk, 0, stream>>>(
                        dbc, dtwl_, xz, dtbl);
                }
                void* dst = (ly < NDEPTH - 1)
                    ? (void*)(xb16 + (size_t)ck * M * DIMK)
                    : (void*)((float*)d_out + (size_t)ck * M * DIMK);
                if (fasty) {
                    scan_k<1, 0><<<dim3(DI / 16, nbc), blk, 0, stream>>>(
                        xc, nullptr, nullptr, dbc, xz, y16, Al, Dl);
                    if (ly < NDEPTH - 1)
                        gemm_bb<1><<<dim3(DIMK / 128, M / 128), blk, 0, stream>>>(
                            y16, ow16, dst, DI, DI, DI, DIMK);
                    else
                        gemm_bb<0><<<dim3(DIMK / 128, M / 128), blk, 0, stream>>>(
                            y16, ow16, dst, DI, DI, DI, DIMK);
                } else {
                    scan_k<0, 0><<<dim3(DI / 16, nbc), blk, 0, stream>>>(
                        xc, nullptr, nullptr, dbc, xz, xc, Al, Dl);
                    if (ly < NDEPTH - 1)
                        gemm_fb<1><<<dim3(DIMK / 128, M / 128), blk, 0, stream>>>(
                            xc, ow16, dst, DI, DI, DI, DIMK);
                    else
                        gemm_fb<0><<<dim3(DIMK / 128, M / 128), blk, 0, stream>>>(
                            xc, ow16, dst, DI, DI, DI, DIMK);
                }
            } else {
                // ---- minimal-ws fallback ----
                const float* xin = (ly == 0 ? x0 : xbuf) + (size_t)ck * M * DIMK;
                gemm_mfma<<<dim3(NXZ / 128, M / 128), blk, 0, stream>>>(
                    xin, Wi, xz, DIMK, DIMK, NXZ);
                conv_silu<<<dim3(M * (DI / 16) / 256), blk, 0, stream>>>(
                    xz, cwl, cbl, xc);
                gemm_xproj<0><<<dim3(3, M / 128), blk, 0, stream>>>(
                    xc, xpl, dbc, DI, DI, nullptr, nullptr);
                gemm_delta<<<dim3(DI / 128, M / 128), blk, 0, stream>>>(
                    dbc, dtwl_, xz, dtbl);
                scan_k<0, 0><<<dim3(DI / 16, nbc), blk, 0, stream>>>(
                    xc, nullptr, nullptr, dbc, xz, xc, Al, Dl);
                float* xdst = (ly == NDEPTH - 1 ? (float*)d_out : xbuf) +
                              (size_t)ck * M * DIMK;
                gemm_mfma<<<dim3(DIMK / 128, M / 128), blk, 0, stream>>>(
                    xc, owl, xdst, DI, DI, DIMK);
            }
        }
    }
}

// Round 12
// 1596.752 us; speedup vs baseline: 1.5176x; 1.0335x over previous
//
#include <hip/hip_runtime.h>
#include <hip/hip_bf16.h>
#include <math.h>

#define DIMK 1024
#define NDEPTH 4
#define DS 16
#define DCONV 4
#define DI 2048
#define DTR 64
#define NB 4
#define SL 2048
#define MT (NB * SL)        // 8192
#define NXZ (2 * DI)        // 4096
#define NDBC (DTR + 2 * DS) // 96

typedef float f32x4 __attribute__((ext_vector_type(4)));
typedef short short8 __attribute__((ext_vector_type(8)));
typedef short short4v __attribute__((ext_vector_type(4)));

__device__ inline unsigned short f2bf(float f) {
    unsigned u = __builtin_bit_cast(unsigned, f);
    unsigned r = (u + 0x7FFFu + ((u >> 16) & 1u)) >> 16;
    return (unsigned short)r;
}
__device__ inline float bf2f(unsigned short h) {
    unsigned u = ((unsigned)h) << 16;
    return __builtin_bit_cast(float, u);
}
__device__ inline void split_bf(float f, unsigned short& hi, unsigned short& lo) {
    hi = f2bf(f);
    lo = f2bf(f - bf2f(hi));
}
__device__ inline unsigned short cvt1(float f) {
    __hip_bfloat16 t = __float2bfloat16(f);
    return __builtin_bit_cast(unsigned short, t);
}
__device__ inline void mfma16(f32x4& d, short8 a, short8 b) {
    asm volatile("v_mfma_f32_16x16x32_bf16 %0, %1, %2, %0"
                 : "+v"(d) : "v"(a), "v"(b));
}
__device__ __forceinline__ float dpp_sum16(float p) {
    asm("v_add_f32_dpp %0, %0, %0 quad_perm:[1,0,3,2] row_mask:0xf bank_mask:0xf bound_ctrl:0" : "+v"(p));
    asm("v_add_f32_dpp %0, %0, %0 quad_perm:[2,3,0,1] row_mask:0xf bank_mask:0xf bound_ctrl:0" : "+v"(p));
    asm("v_add_f32_dpp %0, %0, %0 row_ror:4 row_mask:0xf bank_mask:0xf bound_ctrl:0" : "+v"(p));
    asm("v_add_f32_dpp %0, %0, %0 row_ror:8 row_mask:0xf bank_mask:0xf bound_ctrl:0" : "+v"(p));
    return p;
}
__device__ __forceinline__ float exp2_raw(float x) {
    float r;
    asm("v_exp_f32 %0, %1" : "=v"(r) : "v"(x));
    return r;
}
__device__ __forceinline__ void gload16(const unsigned short* g, unsigned short* l) {
    __builtin_amdgcn_global_load_lds(
        (const __attribute__((address_space(1))) unsigned int*)(g),
        (__attribute__((address_space(3))) unsigned int*)(l),
        16, 0, 0);
}

// ---------------------------------------------------------------------------
__global__ __launch_bounds__(256) void cvt_bf16(
    const float* __restrict__ s, unsigned short* __restrict__ d, int n4)
{
    const int g = blockIdx.x * 256 + threadIdx.x;
    if (g < n4) {
        const float4 f = *(const float4*)(s + (size_t)g * 4);
        short4v v;
        v[0] = (short)cvt1(f.x); v[1] = (short)cvt1(f.y);
        v[2] = (short)cvt1(f.z); v[3] = (short)cvt1(f.w);
        *(short4v*)(d + (size_t)g * 4) = v;
    }
}

// per-layer weight conversions (fallback when ws too small for prepass)
__global__ __launch_bounds__(256) void cvt_layer(
    const float* __restrict__ wi, const float* __restrict__ owp,
    const float* __restrict__ dtwp, const float* __restrict__ xpwp,
    unsigned short* __restrict__ wi16, unsigned short* __restrict__ ow16,
    unsigned short* __restrict__ dtwh, unsigned short* __restrict__ dtwl,
    unsigned short* __restrict__ xpwh, unsigned short* __restrict__ xpwl,
    int fastd, int fastx)
{
    int g = blockIdx.x * 256 + threadIdx.x;
    const int n4w = NXZ * DIMK / 4;
    const int n4o = DIMK * DI / 4;
    const int n4d = DI * DTR / 4;
    const int n4x = NDBC * DI / 4;
    if (g < n4w) {
        const float4 f = *(const float4*)(wi + (size_t)g * 4);
        short4v v;
        v[0] = (short)cvt1(f.x); v[1] = (short)cvt1(f.y);
        v[2] = (short)cvt1(f.z); v[3] = (short)cvt1(f.w);
        *(short4v*)(wi16 + (size_t)g * 4) = v;
        return;
    }
    g -= n4w;
    if (g < n4o) {
        const float4 f = *(const float4*)(owp + (size_t)g * 4);
        short4v v;
        v[0] = (short)cvt1(f.x); v[1] = (short)cvt1(f.y);
        v[2] = (short)cvt1(f.z); v[3] = (short)cvt1(f.w);
        *(short4v*)(ow16 + (size_t)g * 4) = v;
        return;
    }
    g -= n4o;
    if (g < n4d) {
        if (fastd) {
            const float4 f = *(const float4*)(dtwp + (size_t)g * 4);
            short4v h4, l4;
            #pragma unroll
            for (int e = 0; e < 4; ++e) {
                unsigned short h, l;
                split_bf((&f.x)[e], h, l);
                h4[e] = (short)h; l4[e] = (short)l;
            }
            *(short4v*)(dtwh + (size_t)g * 4) = h4;
            *(short4v*)(dtwl + (size_t)g * 4) = l4;
        }
        return;
    }
    g -= n4d;
    if (g < n4x && fastx) {
        const float4 f = *(const float4*)(xpwp + (size_t)g * 4);
        short4v h4, l4;
        #pragma unroll
        for (int e = 0; e < 4; ++e) {
            unsigned short h, l;
            split_bf((&f.x)[e], h, l);
            h4[e] = (short)h; l4[e] = (short)l;
        }
        *(short4v*)(xpwh + (size_t)g * 4) = h4;
        *(short4v*)(xpwl + (size_t)g * 4) = l4;
    }
}

// one-shot prepass: all 4 layers' weights
__global__ __launch_bounds__(256) void cvt_all(
    const float* __restrict__ wi, const float* __restrict__ owp,
    const float* __restrict__ dtwp, const float* __restrict__ xpwp,
    unsigned short* __restrict__ wi16, unsigned short* __restrict__ ow16,
    unsigned short* __restrict__ dtwh, unsigned short* __restrict__ dtwl,
    unsigned short* __restrict__ xpwh, unsigned short* __restrict__ xpwl)
{
    const int n4w = NXZ * DIMK / 4;
    const int n4o = DIMK * DI / 4;
    const int n4d = DI * DTR / 4;
    const int n4x = NDBC * DI / 4;
    const int per = n4w + n4o + n4d + n4x;
    int g = blockIdx.x * 256 + threadIdx.x;
    const int ly = g / per;
    if (ly >= NDEPTH) return;
    g -= ly * per;
    if (g < n4w) {
        const float4 f = *(const float4*)(wi + (size_t)ly * NXZ * DIMK + (size_t)g * 4);
        short4v v;
        v[0] = (short)cvt1(f.x); v[1] = (short)cvt1(f.y);
        v[2] = (short)cvt1(f.z); v[3] = (short)cvt1(f.w);
        *(short4v*)(wi16 + (size_t)ly * NXZ * DIMK + (size_t)g * 4) = v;
        return;
    }
    g -= n4w;
    if (g < n4o) {
        const float4 f = *(const float4*)(owp + (size_t)ly * DIMK * DI + (size_t)g * 4);
        short4v v;
        v[0] = (short)cvt1(f.x); v[1] = (short)cvt1(f.y);
        v[2] = (short)cvt1(f.z); v[3] = (short)cvt1(f.w);
        *(short4v*)(ow16 + (size_t)ly * DIMK * DI + (size_t)g * 4) = v;
        return;
    }
    g -= n4o;
    if (g < n4d) {
        const float4 f = *(const float4*)(dtwp + (size_t)ly * DI * DTR + (size_t)g * 4);
        short4v h4, l4;
        #pragma unroll
        for (int e = 0; e < 4; ++e) {
            unsigned short h, l;
            split_bf((&f.x)[e], h, l);
            h4[e] = (short)h; l4[e] = (short)l;
        }
        *(short4v*)(dtwh + (size_t)ly * DI * DTR + (size_t)g * 4) = h4;
        *(short4v*)(dtwl + (size_t)ly * DI * DTR + (size_t)g * 4) = l4;
        return;
    }
    g -= n4d;
    if (g < n4x) {
        const float4 f = *(const float4*)(xpwp + (size_t)ly * NDBC * DI + (size_t)g * 4);
        short4v h4, l4;
        #pragma unroll
        for (int e = 0; e < 4; ++e) {
            unsigned short h, l;
            split_bf((&f.x)[e], h, l);
            h4[e] = (short)h; l4[e] = (short)l;
        }
        *(short4v*)(xpwh + (size_t)ly * NDBC * DI + (size_t)g * 4) = h4;
        *(short4v*)(xpwl + (size_t)ly * NDBC * DI + (size_t)g * 4) = l4;
    }
}

// ---------------------------------------------------------------------------
// C[m,n] = sum_k A[m,k]*B[n,k]; A,B bf16 global. Single-buffer m97 structure
// + XCD swizzle. CBF: 1 -> bf16 C out.
template <int CBF>
__global__ __launch_bounds__(256) void gemm_bb(
    const unsigned short* __restrict__ A, const unsigned short* __restrict__ B,
    void* __restrict__ Cv, int K, int lda, int ldb, int ldc)
{
    __shared__ unsigned short As[128 * 32];
    __shared__ unsigned short Bs[128 * 32];
    int id = blockIdx.y * gridDim.x + blockIdx.x;
    const int qq = (gridDim.x * gridDim.y) >> 3;
    id = (id & 7) * qq + (id >> 3);
    const int bm = (id / gridDim.x) * 128, bn = (id % gridDim.x) * 128;

    const int tid = threadIdx.x;
    const int wv = tid >> 6, ln = tid & 63;
    const int wr = wv >> 1, wc = wv & 1;
    const int fr = ln & 15, kg = ln >> 4;
    const int sr0 = wv * 32 + (ln >> 2);
    const int sr1 = sr0 + 16;
    const int sl = ln & 3;
    const int cg0 = sl ^ ((sr0 >> 1) & 3);
    const int cg1 = sl ^ ((sr1 >> 1) & 3);
    const unsigned short* pa0 = A + (size_t)(bm + sr0) * lda + cg0 * 8;
    const unsigned short* pa1 = A + (size_t)(bm + sr1) * lda + cg1 * 8;
    const unsigned short* pb0 = B + (size_t)(bn + sr0) * ldb + cg0 * 8;
    const unsigned short* pb1 = B + (size_t)(bn + sr1) * ldb + cg1 * 8;
    unsigned short* la0 = As + (wv * 32 + 0) * 32;
    unsigned short* la1 = As + (wv * 32 + 16) * 32;
    unsigned short* lb0 = Bs + (wv * 32 + 0) * 32;
    unsigned short* lb1 = Bs + (wv * 32 + 16) * 32;
    int offA[4], offB[4];
    #pragma unroll
    for (int f = 0; f < 4; ++f) {
        const int ra = wr * 64 + f * 16 + fr;
        offA[f] = ra * 32 + ((kg ^ ((ra >> 1) & 3)) * 8);
        const int rb = wc * 64 + f * 16 + fr;
        offB[f] = rb * 32 + ((kg ^ ((rb >> 1) & 3)) * 8);
    }
    f32x4 acc[4][4] = {};
    for (int k0 = 0; k0 < K; k0 += 32) {
        gload16(pa0 + k0, la0);
        gload16(pa1 + k0, la1);
        gload16(pb0 + k0, lb0);
        gload16(pb1 + k0, lb1);
        __syncthreads();
        short8 af[4], bw[4];
        #pragma unroll
        for (int f = 0; f < 4; ++f) {
            af[f] = *(const short8*)&As[offA[f]];
            bw[f] = *(const short8*)&Bs[offB[f]];
        }
        #pragma unroll
        for (int fi = 0; fi < 4; ++fi)
            #pragma unroll
            for (int fj = 0; fj < 4; ++fj)
                mfma16(acc[fi][fj], af[fi], bw[fj]);
        __syncthreads();
    }
    #pragma unroll
    for (int fi = 0; fi < 4; ++fi) {
        const int m0 = bm + wr * 64 + fi * 16 + kg * 4;
        #pragma unroll
        for (int fj = 0; fj < 4; ++fj) {
            const int n = bn + wc * 64 + fj * 16 + fr;
            #pragma unroll
            for (int q = 0; q < 4; ++q) {
                if (CBF) {
                    unsigned short* Cs = (unsigned short*)Cv;
                    Cs[(size_t)(m0 + q) * ldc + n] = cvt1(acc[fi][fj][q]);
                } else {
                    float* Cf = (float*)Cv;
                    Cf[(size_t)(m0 + q) * ldc + n] = acc[fi][fj][q];
                }
            }
        }
    }
}

// ---------------------------------------------------------------------------
// A fp32 (reg prefetch + cvt), B bf16 (gload dbuf). CBF: bf16 C. (mid path)
template <int CBF>
__global__ __launch_bounds__(256) void gemm_fb(
    const float* __restrict__ A, const unsigned short* __restrict__ B,
    void* __restrict__ Cv, int K, int lda, int ldb, int ldc)
{
    __shared__ unsigned short As[2][128 * 32];
    __shared__ unsigned short Bs[2][128 * 32];
    int id = blockIdx.y * gridDim.x + blockIdx.x;
    const int qq = (gridDim.x * gridDim.y) >> 3;
    id = (id & 7) * qq + (id >> 3);
    const int bm = (id / gridDim.x) * 128, bn = (id % gridDim.x) * 128;

    const int tid = threadIdx.x;
    const int wv = tid >> 6, ln = tid & 63;
    const int wr = wv >> 1, wc = wv & 1;
    const int fr = ln & 15, kg = ln >> 4;
    const int r = tid >> 1, hf = tid & 1;
    const int sr0 = wv * 32 + (ln >> 2);
    const int sr1 = sr0 + 16;
    const int sl = ln & 3;
    const int cg0 = sl ^ ((sr0 >> 1) & 3);
    const int cg1 = sl ^ ((sr1 >> 1) & 3);
    const unsigned short* pb0 = B + (size_t)(bn + sr0) * ldb + cg0 * 8;
    const unsigned short* pb1 = B + (size_t)(bn + sr1) * ldb + cg1 * 8;
    const int ldst0 = (wv * 32 + 0) * 32;
    const int ldst1 = (wv * 32 + 16) * 32;
    const float* ga = A + (size_t)(bm + r) * lda + hf * 16;
    const int pk0 = (2 * hf + 0) ^ ((r >> 1) & 3);
    const int pk1 = (2 * hf + 1) ^ ((r >> 1) & 3);
    int offA[4], offB[4];
    #pragma unroll
    for (int f = 0; f < 4; ++f) {
        const int ra = wr * 64 + f * 16 + fr;
        offA[f] = ra * 32 + ((kg ^ ((ra >> 1) & 3)) * 8);
        const int rb = wc * 64 + f * 16 + fr;
        offB[f] = rb * 32 + ((kg ^ ((rb >> 1) & 3)) * 8);
    }
    f32x4 acc[4][4] = {};
    {
        float4 f0 = *(const float4*)(ga + 0);
        float4 f1 = *(const float4*)(ga + 4);
        float4 f2 = *(const float4*)(ga + 8);
        float4 f3 = *(const float4*)(ga + 12);
        short8 v;
        v[0] = (short)cvt1(f0.x); v[1] = (short)cvt1(f0.y);
        v[2] = (short)cvt1(f0.z); v[3] = (short)cvt1(f0.w);
        v[4] = (short)cvt1(f1.x); v[5] = (short)cvt1(f1.y);
        v[6] = (short)cvt1(f1.z); v[7] = (short)cvt1(f1.w);
        *(short8*)&As[0][r * 32 + pk0 * 8] = v;
        v[0] = (short)cvt1(f2.x); v[1] = (short)cvt1(f2.y);
        v[2] = (short)cvt1(f2.z); v[3] = (short)cvt1(f2.w);
        v[4] = (short)cvt1(f3.x); v[5] = (short)cvt1(f3.y);
        v[6] = (short)cvt1(f3.z); v[7] = (short)cvt1(f3.w);
        *(short8*)&As[0][r * 32 + pk1 * 8] = v;
        gload16(pb0, &Bs[0][ldst0]);
        gload16(pb1, &Bs[0][ldst1]);
    }
    __syncthreads();
    int cur = 0;
    for (int k0 = 0; k0 < K; k0 += 32) {
        const int nxt = cur ^ 1;
        const bool more = (k0 + 32 < K);
        float4 f0, f1, f2, f3;
        if (more) {
            gload16(pb0 + k0 + 32, &Bs[nxt][ldst0]);
            gload16(pb1 + k0 + 32, &Bs[nxt][ldst1]);
            f0 = *(const float4*)(ga + k0 + 32);
            f1 = *(const float4*)(ga + k0 + 36);
            f2 = *(const float4*)(ga + k0 + 40);
            f3 = *(const float4*)(ga + k0 + 44);
        }
        short8 af[4], bw[4];
        #pragma unroll
        for (int f = 0; f < 4; ++f) {
            af[f] = *(const short8*)&As[cur][offA[f]];
            bw[f] = *(const short8*)&Bs[cur][offB[f]];
        }
        #pragma unroll
        for (int fi = 0; fi < 4; ++fi)
            #pragma unroll
            for (int fj = 0; fj < 4; ++fj)
                mfma16(acc[fi][fj], af[fi], bw[fj]);
        if (more) {
            short8 v;
            v[0] = (short)cvt1(f0.x); v[1] = (short)cvt1(f0.y);
            v[2] = (short)cvt1(f0.z); v[3] = (short)cvt1(f0.w);
            v[4] = (short)cvt1(f1.x); v[5] = (short)cvt1(f1.y);
            v[6] = (short)cvt1(f1.z); v[7] = (short)cvt1(f1.w);
            *(short8*)&As[nxt][r * 32 + pk0 * 8] = v;
            v[0] = (short)cvt1(f2.x); v[1] = (short)cvt1(f2.y);
            v[2] = (short)cvt1(f2.z); v[3] = (short)cvt1(f2.w);
            v[4] = (short)cvt1(f3.x); v[5] = (short)cvt1(f3.y);
            v[6] = (short)cvt1(f3.z); v[7] = (short)cvt1(f3.w);
            *(short8*)&As[nxt][r * 32 + pk1 * 8] = v;
        }
        __syncthreads();
        cur = nxt;
    }
    #pragma unroll
    for (int fi = 0; fi < 4; ++fi) {
        const int m0 = bm + wr * 64 + fi * 16 + kg * 4;
        #pragma unroll
        for (int fj = 0; fj < 4; ++fj) {
            const int n = bn + wc * 64 + fj * 16 + fr;
            #pragma unroll
            for (int q = 0; q < 4; ++q) {
                if (CBF) {
                    unsigned short* Cs = (unsigned short*)Cv;
                    Cs[(size_t)(m0 + q) * ldc + n] = cvt1(acc[fi][fj][q]);
                } else {
                    float* Cf = (float*)Cv;
                    Cf[(size_t)(m0 + q) * ldc + n] = acc[fi][fj][q];
                }
            }
        }
    }
}

// ---------------------------------------------------------------------------
// fallback GEMM (fp32 in/out), used only if ws too small
__global__ __launch_bounds__(256) void gemm_mfma(
    const float* __restrict__ A, const float* __restrict__ W,
    float* __restrict__ C, int K, int lda, int ldc)
{
    __shared__ unsigned short As[128 * 32];
    __shared__ unsigned short Ws[128 * 32];
    const int tid = threadIdx.x;
    const int bm = blockIdx.y * 128;
    const int bn = blockIdx.x * 128;
    const int r = tid >> 1;
    const int h = tid & 1;
    const int wv = tid >> 6;
    const int wr = wv >> 1;
    const int wc = wv & 1;
    const int ln = tid & 63;
    const int fr = ln & 15;
    const int kg = ln >> 4;
    f32x4 acc[4][4] = {};
    const float* ga = A + (size_t)(bm + r) * lda + h * 16;
    const float* gw = W + (size_t)(bn + r) * K + h * 16;
    for (int k0 = 0; k0 < K; k0 += 32) {
        #pragma unroll
        for (int p = 0; p < 2; ++p) {
            const int pk = (2 * h + p) ^ ((r >> 1) & 3);
            float4 f0 = *(const float4*)(ga + k0 + p * 8);
            float4 f1 = *(const float4*)(ga + k0 + p * 8 + 4);
            short8 v;
            v[0] = (short)cvt1(f0.x); v[1] = (short)cvt1(f0.y);
            v[2] = (short)cvt1(f0.z); v[3] = (short)cvt1(f0.w);
            v[4] = (short)cvt1(f1.x); v[5] = (short)cvt1(f1.y);
            v[6] = (short)cvt1(f1.z); v[7] = (short)cvt1(f1.w);
            *(short8*)&As[r * 32 + pk * 8] = v;
            f0 = *(const float4*)(gw + k0 + p * 8);
            f1 = *(const float4*)(gw + k0 + p * 8 + 4);
            v[0] = (short)cvt1(f0.x); v[1] = (short)cvt1(f0.y);
            v[2] = (short)cvt1(f0.z); v[3] = (short)cvt1(f0.w);
            v[4] = (short)cvt1(f1.x); v[5] = (short)cvt1(f1.y);
            v[6] = (short)cvt1(f1.z); v[7] = (short)cvt1(f1.w);
            *(short8*)&Ws[r * 32 + pk * 8] = v;
        }
        __syncthreads();
        short8 af[4], bw[4];
        #pragma unroll
        for (int f = 0; f < 4; ++f) {
            const int ra = wr * 64 + f * 16 + fr;
            af[f] = *(const short8*)&As[ra * 32 + ((kg ^ ((ra >> 1) & 3)) * 8)];
            const int rb = wc * 64 + f * 16 + fr;
            bw[f] = *(const short8*)&Ws[rb * 32 + ((kg ^ ((rb >> 1) & 3)) * 8)];
        }
        #pragma unroll
        for (int fi = 0; fi < 4; ++fi)
            #pragma unroll
            for (int fj = 0; fj < 4; ++fj)
                mfma16(acc[fi][fj], af[fi], bw[fj]);
        __syncthreads();
    }
    #pragma unroll
    for (int fi = 0; fi < 4; ++fi) {
        const int m0 = bm + wr * 64 + fi * 16 + kg * 4;
        #pragma unroll
        for (int fj = 0; fj < 4; ++fj) {
            const int n = bn + wc * 64 + fj * 16 + fr;
            #pragma unroll
            for (int q = 0; q < 4; ++q)
                C[(size_t)(m0 + q) * ldc + n] = acc[fi][fj][q];
        }
    }
}

// ---------------------------------------------------------------------------
// x_proj fast: A = pre-split xc (xch/xcl), W = pre-split xpw. Pure gload+MFMA.
__global__ __launch_bounds__(256) void gemm_xproj_pre(
    const unsigned short* __restrict__ Ahg, const unsigned short* __restrict__ Alg,
    const unsigned short* __restrict__ Whg, const unsigned short* __restrict__ Wlg,
    float* __restrict__ C,
    unsigned short* __restrict__ dth, unsigned short* __restrict__ dtl)
{
    __shared__ unsigned short Ahs[2][128 * 32], Als[2][128 * 32];
    __shared__ unsigned short Whs[2][32 * 32], Wls[2][32 * 32];
    int id = blockIdx.y * gridDim.x + blockIdx.x;
    const int qq = (gridDim.x * gridDim.y) >> 3;
    id = (id & 7) * qq + (id >> 3);
    const int bm = (id / gridDim.x) * 128, bn = (id % gridDim.x) * 32;

    const int tid = threadIdx.x;
    const int wv = tid >> 6, ln = tid & 63;
    const int fr = ln & 15, kg = ln >> 4;
    const int sr0 = wv * 32 + (ln >> 2);
    const int sr1 = sr0 + 16;
    const int sl = ln & 3;
    const int cg0 = sl ^ ((sr0 >> 1) & 3);
    const int cg1 = sl ^ ((sr1 >> 1) & 3);
    const unsigned short* pah0 = Ahg + (size_t)(bm + sr0) * DI + cg0 * 8;
    const unsigned short* pah1 = Ahg + (size_t)(bm + sr1) * DI + cg1 * 8;
    const unsigned short* pal0 = Alg + (size_t)(bm + sr0) * DI + cg0 * 8;
    const unsigned short* pal1 = Alg + (size_t)(bm + sr1) * DI + cg1 * 8;
    const int lA0 = (wv * 32 + 0) * 32;
    const int lA1 = (wv * 32 + 16) * 32;
    const int wrow = (wv & 1) * 16 + (ln >> 2);
    const int cgw = sl ^ ((wrow >> 1) & 3);
    const unsigned short* pw = ((wv < 2) ? Whg : Wlg) + (size_t)(bn + wrow) * DI + cgw * 8;
    const int lW = ((wv & 1) * 16) * 32;
    unsigned short* wdst[2];
    wdst[0] = (wv < 2) ? &Whs[0][lW] : &Wls[0][lW];
    wdst[1] = (wv < 2) ? &Whs[1][lW] : &Wls[1][lW];

    int offA[2], offW[2];
    #pragma unroll
    for (int f = 0; f < 2; ++f) {
        const int ra = wv * 32 + f * 16 + fr;
        offA[f] = ra * 32 + ((kg ^ ((ra >> 1) & 3)) * 8);
        const int rb = f * 16 + fr;
        offW[f] = rb * 32 + ((kg ^ ((rb >> 1) & 3)) * 8);
    }
    f32x4 acc[2][2] = {};
    gload16(pah0, &Ahs[0][lA0]);
    gload16(pah1, &Ahs[0][lA1]);
    gload16(pal0, &Als[0][lA0]);
    gload16(pal1, &Als[0][lA1]);
    gload16(pw, wdst[0]);
    __syncthreads();
    int cur = 0;
    for (int k0 = 0; k0 < DI; k0 += 32) {
        const int nxt = cur ^ 1;
        if (k0 + 32 < DI) {
            gload16(pah0 + k0 + 32, &Ahs[nxt][lA0]);
            gload16(pah1 + k0 + 32, &Ahs[nxt][lA1]);
            gload16(pal0 + k0 + 32, &Als[nxt][lA0]);
            gload16(pal1 + k0 + 32, &Als[nxt][lA1]);
            gload16(pw + k0 + 32, wdst[nxt]);
        }
        short8 ah[2], alo[2], bh[2], bl[2];
        #pragma unroll
        for (int f = 0; f < 2; ++f) {
            ah[f]  = *(const short8*)&Ahs[cur][offA[f]];
            alo[f] = *(const short8*)&Als[cur][offA[f]];
            bh[f]  = *(const short8*)&Whs[cur][offW[f]];
            bl[f]  = *(const short8*)&Wls[cur][offW[f]];
        }
        #pragma unroll
        for (int fi = 0; fi < 2; ++fi)
            #pragma unroll
            for (int fj = 0; fj < 2; ++fj) {
                mfma16(acc[fi][fj], ah[fi], bh[fj]);
                mfma16(acc[fi][fj], ah[fi], bl[fj]);
                mfma16(acc[fi][fj], alo[fi], bh[fj]);
            }
        __syncthreads();
        cur = nxt;
    }
    #pragma unroll
    for (int fi = 0; fi < 2; ++fi) {
        const int m0 = bm + wv * 32 + fi * 16 + kg * 4;
        #pragma unroll
        for (int fj = 0; fj < 2; ++fj) {
            const int n = bn + fj * 16 + fr;
            #pragma unroll
            for (int q = 0; q < 4; ++q) {
                const float v = acc[fi][fj][q];
                C[(size_t)(m0 + q) * NDBC + n] = v;
                if (n < DTR) {
                    unsigned short hh, llo;
                    split_bf(v, hh, llo);
                    dth[(size_t)(m0 + q) * DTR + n] = hh;
                    dtl[(size_t)(m0 + q) * DTR + n] = llo;
                }
            }
        }
    }
}

// ---------------------------------------------------------------------------
// x_proj fallback: split in-kernel from fp32 xc. BM=128, BN=32.
template <int WRDT>
__global__ __launch_bounds__(256) void gemm_xproj(
    const float* __restrict__ A, const float* __restrict__ W,
    float* __restrict__ C, int K, int lda,
    unsigned short* __restrict__ dth, unsigned short* __restrict__ dtl)
{
    __shared__ unsigned short Ah[128 * 32], Al[128 * 32];
    __shared__ unsigned short Wh[32 * 32], Wl[32 * 32];
    const int tid = threadIdx.x;
    const int bm = blockIdx.y * 128;
    const int bn = blockIdx.x * 32;
    const int r = tid >> 1, hf = tid & 1;
    const int wv = tid >> 6;
    const int ln = tid & 63, fr = ln & 15, kg = ln >> 4;
    const int wsr = tid >> 3;
    const int wc4 = (tid & 7) << 2;
    f32x4 acc[2][2] = {};
    const float* ga = A + (size_t)(bm + r) * lda + hf * 16;
    const float* gw = W + (size_t)(bn + wsr) * K + wc4;
    for (int k0 = 0; k0 < K; k0 += 32) {
        #pragma unroll
        for (int j = 0; j < 4; ++j) {
            const int col = hf * 16 + j * 4;
            const int ad = r * 32 + (((col >> 3) ^ ((r >> 1) & 3)) << 3) + (col & 7);
            const float4 fa = *(const float4*)(ga + k0 + j * 4);
            short4v h4, l4;
            #pragma unroll
            for (int e = 0; e < 4; ++e) {
                unsigned short hh, llo;
                split_bf((&fa.x)[e], hh, llo);
                h4[e] = (short)hh; l4[e] = (short)llo;
            }
            *(short4v*)&Ah[ad] = h4;
            *(short4v*)&Al[ad] = l4;
        }
        {
            const int ad = wsr * 32 + (((wc4 >> 3) ^ ((wsr >> 1) & 3)) << 3) + (wc4 & 7);
            const float4 fw = *(const float4*)(gw + k0);
            short4v h4, l4;
            #pragma unroll
            for (int e = 0; e < 4; ++e) {
                unsigned short hh, llo;
                split_bf((&fw.x)[e], hh, llo);
                h4[e] = (short)hh; l4[e] = (short)llo;
            }
            *(short4v*)&Wh[ad] = h4;
            *(short4v*)&Wl[ad] = l4;
        }
        __syncthreads();
        short8 ah[2], alo[2], bh[2], bl[2];
        #pragma unroll
        for (int f = 0; f < 2; ++f) {
            const int ra = wv * 32 + f * 16 + fr;
            const int ao = ra * 32 + ((kg ^ ((ra >> 1) & 3)) * 8);
            ah[f]  = *(const short8*)&Ah[ao];
            alo[f] = *(const short8*)&Al[ao];
            const int rb = f * 16 + fr;
            const int bo = rb * 32 + ((kg ^ ((rb >> 1) & 3)) * 8);
            bh[f] = *(const short8*)&Wh[bo];
            bl[f] = *(const short8*)&Wl[bo];
        }
        #pragma unroll
        for (int fi = 0; fi < 2; ++fi)
            #pragma unroll
            for (int fj = 0; fj < 2; ++fj) {
                mfma16(acc[fi][fj], ah[fi], bh[fj]);
                mfma16(acc[fi][fj], ah[fi], bl[fj]);
                mfma16(acc[fi][fj], alo[fi], bh[fj]);
            }
        __syncthreads();
    }
    #pragma unroll
    for (int fi = 0; fi < 2; ++fi) {
        const int m0 = bm + wv * 32 + fi * 16 + kg * 4;
        #pragma unroll
        for (int fj = 0; fj < 2; ++fj) {
            const int n = bn + fj * 16 + fr;
            #pragma unroll
            for (int q = 0; q < 4; ++q) {
                const float v = acc[fi][fj][q];
                C[(size_t)(m0 + q) * NDBC + n] = v;
                if (WRDT && n < DTR) {
                    unsigned short hh, llo;
                    split_bf(v, hh, llo);
                    dth[(size_t)(m0 + q) * DTR + n] = hh;
                    dtl[(size_t)(m0 + q) * DTR + n] = llo;
                }
            }
        }
    }
}

// ---------------------------------------------------------------------------
// delta (fallback): split in-kernel from fp32 dbc/dtw. K=64.
__global__ __launch_bounds__(256) void gemm_delta(
    const float* __restrict__ A, const float* __restrict__ W,
    float* __restrict__ C, const float* __restrict__ bias)
{
    __shared__ unsigned short Ah[128 * 32], Al[128 * 32];
    __shared__ unsigned short Wh[128 * 32], Wl[128 * 32];
    const int tid = threadIdx.x;
    const int bm = blockIdx.y * 128;
    const int bn = blockIdx.x * 128;
    const int r = tid >> 1, hf = tid & 1;
    const int wv = tid >> 6, wr = wv >> 1, wc = wv & 1;
    const int ln = tid & 63, fr = ln & 15, kg = ln >> 4;
    f32x4 acc[4][4] = {};
    const float* ga = A + (size_t)(bm + r) * NDBC + hf * 16;
    const float* gw = W + (size_t)(bn + r) * DTR + hf * 16;
    for (int k0 = 0; k0 < DTR; k0 += 32) {
        #pragma unroll
        for (int j = 0; j < 4; ++j) {
            const int col = hf * 16 + j * 4;
            const int ad = r * 32 + (((col >> 3) ^ ((r >> 1) & 3)) << 3) + (col & 7);
            const float4 fa = *(const float4*)(ga + k0 + j * 4);
            const float4 fw = *(const float4*)(gw + k0 + j * 4);
            short4v ah4, al4, wh4, wl4;
            #pragma unroll
            for (int e = 0; e < 4; ++e) {
                unsigned short hh, llo;
                split_bf((&fa.x)[e], hh, llo);
                ah4[e] = (short)hh; al4[e] = (short)llo;
                split_bf((&fw.x)[e], hh, llo);
                wh4[e] = (short)hh; wl4[e] = (short)llo;
            }
            *(short4v*)&Ah[ad] = ah4; *(short4v*)&Al[ad] = al4;
            *(short4v*)&Wh[ad] = wh4; *(short4v*)&Wl[ad] = wl4;
        }
        __syncthreads();
        short8 ah[4], alo[4], bh[4], bl[4];
        #pragma unroll
        for (int f = 0; f < 4; ++f) {
            const int ra = wr * 64 + f * 16 + fr;
            const int ao = ra * 32 + ((kg ^ ((ra >> 1) & 3)) * 8);
            ah[f]  = *(const short8*)&Ah[ao];
            alo[f] = *(const short8*)&Al[ao];
            const int rb = wc * 64 + f * 16 + fr;
            const int bo = rb * 32 + ((kg ^ ((rb >> 1) & 3)) * 8);
            bh[f] = *(const short8*)&Wh[bo];
            bl[f] = *(const short8*)&Wl[bo];
        }
        #pragma unroll
        for (int fi = 0; fi < 4; ++fi)
            #pragma unroll
            for (int fj = 0; fj < 4; ++fj) {
                mfma16(acc[fi][fj], ah[fi], bh[fj]);
                mfma16(acc[fi][fj], ah[fi], bl[fj]);
                mfma16(acc[fi][fj], alo[fi], bh[fj]);
            }
        __syncthreads();
    }
    #pragma unroll
    for (int fi = 0; fi < 4; ++fi) {
        const int m0 = bm + wr * 64 + fi * 16 + kg * 4;
        #pragma unroll
        for (int fj = 0; fj < 4; ++fj) {
            const int n = bn + wc * 64 + fj * 16 + fr;
            const float bb = bias[n];
            #pragma unroll
            for (int q = 0; q < 4; ++q) {
                float v = acc[fi][fj][q] + bb;
                v = (v > 20.f) ? v : log1pf(__expf(v));
                C[(size_t)(m0 + q) * NXZ + n] = v;
            }
        }
    }
}

// ---------------------------------------------------------------------------
// delta (fast): all operands pre-split bf16; single stage via gload, K=64.
__global__ __launch_bounds__(256) void gemm_delta_pre(
    const unsigned short* __restrict__ Ahg, const unsigned short* __restrict__ Alg,
    const unsigned short* __restrict__ Whg, const unsigned short* __restrict__ Wlg,
    float* __restrict__ C, const float* __restrict__ bias)
{
    __shared__ unsigned short sAh[128 * 64], sAl[128 * 64];
    __shared__ unsigned short sWh[128 * 64], sWl[128 * 64];
    const int tid = threadIdx.x;
    const int bm = blockIdx.y * 128;
    const int bn = blockIdx.x * 128;
    const int wv = tid >> 6, ln = tid & 63;
    const int wr = wv >> 1, wc = wv & 1;
    const int fr = ln & 15, kg = ln >> 4;
    const int srow = ln >> 3;
    const int g = ln & 7;
    const int half = g >> 2, sub = g & 3;
    #pragma unroll
    for (int j = 0; j < 4; ++j) {
        const int row = wv * 32 + j * 8 + srow;
        const int sub2 = sub ^ ((row >> 1) & 3);
        const int scol = half * 32 + sub2 * 8;
        const int dst = (wv * 32 + j * 8) * 64;
        gload16(Ahg + (size_t)(bm + row) * DTR + scol, sAh + dst);
        gload16(Alg + (size_t)(bm + row) * DTR + scol, sAl + dst);
        gload16(Whg + (size_t)(bn + row) * DTR + scol, sWh + dst);
        gload16(Wlg + (size_t)(bn + row) * DTR + scol, sWl + dst);
    }
    __syncthreads();
    f32x4 acc[4][4] = {};
    #pragma unroll
    for (int ks = 0; ks < 2; ++ks) {
        short8 ah[4], alo[4], bh[4], bl[4];
        #pragma unroll
        for (int f = 0; f < 4; ++f) {
            const int ra = wr * 64 + f * 16 + fr;
            const int ao = ra * 64 + ks * 32 + ((kg ^ ((ra >> 1) & 3)) * 8);
            ah[f]  = *(const short8*)&sAh[ao];
            alo[f] = *(const short8*)&sAl[ao];
            const int rb = wc * 64 + f * 16 + fr;
            const int bo = rb * 64 + ks * 32 + ((kg ^ ((rb >> 1) & 3)) * 8);
            bh[f] = *(const short8*)&sWh[bo];
            bl[f] = *(const short8*)&sWl[bo];
        }
        #pragma unroll
        for (int fi = 0; fi < 4; ++fi)
            #pragma unroll
            for (int fj = 0; fj < 4; ++fj) {
                mfma16(acc[fi][fj], ah[fi], bh[fj]);
                mfma16(acc[fi][fj], ah[fi], bl[fj]);
                mfma16(acc[fi][fj], alo[fi], bh[fj]);
            }
    }
    #pragma unroll
    for (int fi = 0; fi < 4; ++fi) {
        const int m0 = bm + wr * 64 + fi * 16 + kg * 4;
        #pragma unroll
        for (int fj = 0; fj < 4; ++fj) {
            const int n = bn + wc * 64 + fj * 16 + fr;
            const float bb = bias[n];
            #pragma unroll
            for (int q = 0; q < 4; ++q) {
                float v = acc[fi][fj][q] + bb;
                v = (v > 20.f) ? v : log1pf(__expf(v));
                C[(size_t)(m0 + q) * NXZ + n] = v;
            }
        }
    }
}

// ---------------------------------------------------------------------------
// conv+silu, fp32 out (fallback path)
__global__ __launch_bounds__(256) void conv_silu(
    const float* __restrict__ xz, const float* __restrict__ cw,
    const float* __restrict__ cb, float* __restrict__ xc)
{
    const int g = blockIdx.x * 256 + threadIdx.x;
    const int c4 = g & (DI / 4 - 1);
    const int mq = g >> 9;
    const int m0 = mq << 2;
    const int l0 = m0 & (SL - 1);
    const int c = c4 << 2;
    const float4 w0 = *(const float4*)(cw + (size_t)(c + 0) * DCONV);
    const float4 w1 = *(const float4*)(cw + (size_t)(c + 1) * DCONV);
    const float4 w2 = *(const float4*)(cw + (size_t)(c + 2) * DCONV);
    const float4 w3 = *(const float4*)(cw + (size_t)(c + 3) * DCONV);
    const float4 cb4 = *(const float4*)(cb + c);
    float4 x[7];
    #pragma unroll
    for (int i = 0; i < 7; ++i) {
        if (l0 - 3 + i >= 0)
            x[i] = *(const float4*)(xz + (size_t)(m0 - 3 + i) * NXZ + c);
        else
            x[i] = make_float4(0.f, 0.f, 0.f, 0.f);
    }
    #pragma unroll
    for (int j = 0; j < 4; ++j) {
        float4 acc = cb4;
        #pragma unroll
        for (int k = 0; k < DCONV; ++k) {
            const float4 v = x[j + k];
            acc.x = fmaf(v.x, (&w0.x)[k], acc.x);
            acc.y = fmaf(v.y, (&w1.x)[k], acc.y);
            acc.z = fmaf(v.z, (&w2.x)[k], acc.z);
            acc.w = fmaf(v.w, (&w3.x)[k], acc.w);
        }
        acc.x = acc.x / (1.f + __expf(-acc.x));
        acc.y = acc.y / (1.f + __expf(-acc.y));
        acc.z = acc.z / (1.f + __expf(-acc.z));
        acc.w = acc.w / (1.f + __expf(-acc.w));
        *(float4*)(xc + (size_t)(m0 + j) * DI + c) = acc;
    }
}

// conv+silu, split bf16 (hi,lo) out
__global__ __launch_bounds__(256) void conv_silu_split(
    const float* __restrict__ xz, const float* __restrict__ cw,
    const float* __restrict__ cb, unsigned short* __restrict__ xch,
    unsigned short* __restrict__ xcl)
{
    const int g = blockIdx.x * 256 + threadIdx.x;
    const int c4 = g & (DI / 4 - 1);
    const int mq = g >> 9;
    const int m0 = mq << 2;
    const int l0 = m0 & (SL - 1);
    const int c = c4 << 2;
    const float4 w0 = *(const float4*)(cw + (size_t)(c + 0) * DCONV);
    const float4 w1 = *(const float4*)(cw + (size_t)(c + 1) * DCONV);
    const float4 w2 = *(const float4*)(cw + (size_t)(c + 2) * DCONV);
    const float4 w3 = *(const float4*)(cw + (size_t)(c + 3) * DCONV);
    const float4 cb4 = *(const float4*)(cb + c);
    float4 x[7];
    #pragma unroll
    for (int i = 0; i < 7; ++i) {
        if (l0 - 3 + i >= 0)
            x[i] = *(const float4*)(xz + (size_t)(m0 - 3 + i) * NXZ + c);
        else
            x[i] = make_float4(0.f, 0.f, 0.f, 0.f);
    }
    #pragma unroll
    for (int j = 0; j < 4; ++j) {
        float4 acc = cb4;
        #pragma unroll
        for (int k = 0; k < DCONV; ++k) {
            const float4 v = x[j + k];
            acc.x = fmaf(v.x, (&w0.x)[k], acc.x);
            acc.y = fmaf(v.y, (&w1.x)[k], acc.y);
            acc.z = fmaf(v.z, (&w2.x)[k], acc.z);
            acc.w = fmaf(v.w, (&w3.x)[k], acc.w);
        }
        short4v h4, l4;
        #pragma unroll
        for (int e = 0; e < 4; ++e) {
            float a = (&acc.x)[e];
            a = a / (1.f + __expf(-a));
            unsigned short hh, llo;
            split_bf(a, hh, llo);
            h4[e] = (short)hh; l4[e] = (short)llo;
        }
        *(short4v*)(xch + (size_t)(m0 + j) * DI + c) = h4;
        *(short4v*)(xcl + (size_t)(m0 + j) * DI + c) = l4;
    }
}

// ---------------------------------------------------------------------------
// Selective scan v5: reg-prefetch staging (T14), double-buffered staging LDS,
// ONE barrier per tile (y-epilogue pipelined one tile behind).
// YBF: y as bf16. UBF: u from split pair.
template <int YBF, int UBF>
__global__ __launch_bounds__(256) void scan_k(
    const float* uf, const unsigned short* __restrict__ uh,
    const unsigned short* __restrict__ ul,
    const float* __restrict__ dbc,
    const float* __restrict__ xz, void* __restrict__ yv,
    const float* __restrict__ Alog, const float* __restrict__ Dl)
{
    const int b = blockIdx.y;
    const int c0 = blockIdx.x * 16;
    const int tid = threadIdx.x;
    const int ch = tid >> 4;
    const int s = tid & 15;
    const float Aa = -__expf(Alog[(size_t)(c0 + ch) * DS + s]) * 1.44269504088896f;
    __shared__ float sdl[2][16][68];
    __shared__ float sxb[2][16][68];
    __shared__ float sbc[2][32][68];
    __shared__ float sy[2][64][16];
    __shared__ float sD[16];
    if (tid < 16) sD[tid] = Dl[c0 + tid];
    float h = 0.f;
    const int row = tid >> 2;
    const int q = (tid & 3) << 2;
    const size_t base = (size_t)b * SL;
    const int r2a = tid >> 3, q2a = (tid & 7) << 2;
    const int r2b = 32 + (tid >> 3);

    float4 dlv, zv, g0, g1, uvf;
    short4v uh4, ul4;
    {
        const size_t m = base + row;
        dlv = *(const float4*)(xz + m * NXZ + c0 + q);
        if (UBF) {
            uh4 = *(const short4v*)(uh + m * DI + c0 + q);
            ul4 = *(const short4v*)(ul + m * DI + c0 + q);
        } else {
            uvf = *(const float4*)(uf + m * DI + c0 + q);
        }
        zv = *(const float4*)(xz + m * NXZ + DI + c0 + q);
        g0 = *(const float4*)(dbc + (base + r2a) * NDBC + DTR + q2a);
        g1 = *(const float4*)(dbc + (base + r2b) * NDBC + DTR + q2a);
    }
    float4 p0c, p1c, p0p, p1p;
    int pp = 0;
    __syncthreads();   // sD ready
    const int NT = SL / 64;
    for (int tile = 0; tile < NT; ++tile) {
        const int buf = tile & 1;
        // ---- stage current tile (consume prefetched regs) ----
        float4 uv;
        if (UBF) {
            #pragma unroll
            for (int e = 0; e < 4; ++e)
                (&uv.x)[e] = bf2f((unsigned short)uh4[e]) +
                             bf2f((unsigned short)ul4[e]);
        } else uv = uvf;
        #pragma unroll
        for (int j = 0; j < 4; ++j) {
            const float dl = (&dlv.x)[j], uu = (&uv.x)[j], zz = (&zv.x)[j];
            const float w = zz / (1.f + __expf(-zz));
            sdl[buf][q + j][row] = dl;
            sxb[buf][q + j][row] = dl * uu;
            (&p1c.x)[j] = w;
            (&p0c.x)[j] = uu * sD[q + j] * w;
        }
        sbc[buf][q2a + 0][r2a] = g0.x; sbc[buf][q2a + 1][r2a] = g0.y;
        sbc[buf][q2a + 2][r2a] = g0.z; sbc[buf][q2a + 3][r2a] = g0.w;
        sbc[buf][q2a + 0][r2b] = g1.x; sbc[buf][q2a + 1][r2b] = g1.y;
        sbc[buf][q2a + 2][r2b] = g1.z; sbc[buf][q2a + 3][r2b] = g1.w;
        __syncthreads();   // single barrier per tile
        // ---- y-epilogue for previous tile ----
        if (tile > 0) {
            const size_t mp = base + (size_t)(tile - 1) * 64 + row;
            if (YBF) {
                unsigned short* y16 = (unsigned short*)yv;
                short4v s4;
                #pragma unroll
                for (int e = 0; e < 4; ++e)
                    s4[e] = (short)cvt1(fmaf(sy[pp ^ 1][row][q + e],
                                             (&p1p.x)[e], (&p0p.x)[e]));
                *(short4v*)(y16 + mp * DI + c0 + q) = s4;
            } else {
                float* y = (float*)yv;
                float4 yvv;
                #pragma unroll
                for (int e = 0; e < 4; ++e)
                    (&yvv.x)[e] = fmaf(sy[pp ^ 1][row][q + e],
                                       (&p1p.x)[e], (&p0p.x)[e]);
                *(float4*)(y + mp * DI + c0 + q) = yvv;
            }
        }
        // ---- prefetch next tile into regs (hides under t-loop) ----
        if (tile + 1 < NT) {
            const size_t m = base + (size_t)(tile + 1) * 64 + row;
            dlv = *(const float4*)(xz + m * NXZ + c0 + q);
            if (UBF) {
                uh4 = *(const short4v*)(uh + m * DI + c0 + q);
                ul4 = *(const short4v*)(ul + m * DI + c0 + q);
            } else {
                uvf = *(const float4*)(uf + m * DI + c0 + q);
            }
            zv = *(const float4*)(xz + m * NXZ + DI + c0 + q);
            const size_t mb2 = base + (size_t)(tile + 1) * 64;
            g0 = *(const float4*)(dbc + (mb2 + r2a) * NDBC + DTR + q2a);
            g1 = *(const float4*)(dbc + (mb2 + r2b) * NDBC + DTR + q2a);
        }
        // ---- t-loop on buf ----
        for (int it = 0; it < 16; ++it) {
            const int t0 = it * 4;
            const float4 dl4 = *(const float4*)&sdl[buf][ch][t0];
            const float4 xb4 = *(const float4*)&sxb[buf][ch][t0];
            const float4 B4  = *(const float4*)&sbc[buf][s][t0];
            const float4 C4  = *(const float4*)&sbc[buf][16 + s][t0];
            float py0, py1, py2, py3;
            {
                const float dA = exp2_raw(dl4.x * Aa);
                h = fmaf(dA, h, xb4.x * B4.x);
                py0 = dpp_sum16(h * C4.x);
            }
            {
                const float dA = exp2_raw(dl4.y * Aa);
                h = fmaf(dA, h, xb4.y * B4.y);
                py1 = dpp_sum16(h * C4.y);
            }
            {
                const float dA = exp2_raw(dl4.z * Aa);
                h = fmaf(dA, h, xb4.z * B4.z);
                py2 = dpp_sum16(h * C4.z);
            }
            {
                const float dA = exp2_raw(dl4.w * Aa);
                h = fmaf(dA, h, xb4.w * B4.w);
                py3 = dpp_sum16(h * C4.w);
            }
            if (s < 4) {
                const int t = t0 + s;
                const float lo_ = (s & 1) ? py1 : py0;
                const float hi_ = (s & 1) ? py3 : py2;
                sy[pp][t][ch] = (s & 2) ? hi_ : lo_;
            }
        }
        p0p = p0c; p1p = p1c;
        pp ^= 1;
    }
    __syncthreads();
    // final epilogue (tile NT-1)
    {
        const size_t mp = base + (size_t)(NT - 1) * 64 + row;
        if (YBF) {
            unsigned short* y16 = (unsigned short*)yv;
            short4v s4;
            #pragma unroll
            for (int e = 0; e < 4; ++e)
                s4[e] = (short)cvt1(fmaf(sy[pp ^ 1][row][q + e],
                                         (&p1p.x)[e], (&p0p.x)[e]));
            *(short4v*)(y16 + mp * DI + c0 + q) = s4;
        } else {
            float* y = (float*)yv;
            float4 yvv;
            #pragma unroll
            for (int e = 0; e < 4; ++e)
                (&yvv.x)[e] = fmaf(sy[pp ^ 1][row][q + e],
                                   (&p1p.x)[e], (&p0p.x)[e]);
            *(float4*)(y + mp * DI + c0 + q) = yvv;
        }
    }
}

// ---------------------------------------------------------------------------
extern "C" void kernel_launch(void* const* d_in, const int* in_sizes, int n_in,
                              void* d_out, int out_size, void* d_ws, size_t ws_size,
                              hipStream_t stream)
{
    const float* x0   = (const float*)d_in[0];
    const float* in_w = (const float*)d_in[1];
    const float* cw   = (const float*)d_in[2];
    const float* cb   = (const float*)d_in[3];
    const float* xpw  = (const float*)d_in[4];
    const float* dtw  = (const float*)d_in[5];
    const float* dtb  = (const float*)d_in[6];
    const float* Alog = (const float*)d_in[7];
    const float* Dp   = (const float*)d_in[8];
    const float* ow   = (const float*)d_in[9];

    const size_t perB = (size_t)SL * (NXZ + DI + NDBC) * sizeof(float); // ~51.1MB
    const size_t wby  = ((size_t)NXZ * DIMK + (size_t)DIMK * DI) * 2;   // 12.6MB
    int nbc = 0, fast = 0;
    if (ws_size >= 4 * perB + wby)      { nbc = 4; fast = 1; }
    else if (ws_size >= 2 * perB + wby) { nbc = 2; fast = 1; }
    else if (ws_size >= perB + wby)     { nbc = 1; fast = 1; }
    else if (ws_size >= 4 * perB)       { nbc = 4; }
    else if (ws_size >= 2 * perB)       { nbc = 2; }
    else if (ws_size >= perB)           { nbc = 1; }
    else return;
    const int nchunks = NB / nbc;
    const int M = nbc * SL;
    const size_t dtby = ((size_t)DI * DTR * 2 + (size_t)M * DTR * 2) * 2;
    const size_t yby  = (size_t)M * DI * 2;
    const size_t xpby = (size_t)NDBC * DI * 2 * 2;
    const size_t base = (size_t)nbc * perB + wby;
    const int fastd = fast && (ws_size >= base + dtby);
    const int fasty = fastd && (ws_size >= base + dtby + yby);
    const int fastx = fasty && (ws_size >= base + dtby + yby + xpby);
    // all-layer weight prepass sizing
    const size_t wAll = ((size_t)NDEPTH * NXZ * DIMK + (size_t)NDEPTH * DIMK * DI +
                         2 * (size_t)NDEPTH * DI * DTR + 2 * (size_t)NDEPTH * NDBC * DI) * 2;
    const size_t chunkBy = (size_t)nbc * perB;
    const int fastw = fastx &&
        (ws_size >= chunkBy + wAll + (size_t)M * DTR * 2 * 2 + yby);

    float* xz  = (float*)d_ws;
    float* xc  = xz + (size_t)M * NXZ;
    float* dbc = xc + (size_t)M * DI;
    unsigned short* xch = (unsigned short*)xc;
    unsigned short* xcl = xch + (size_t)M * DI;

    // layout after dbc differs by mode
    unsigned short* p = (unsigned short*)(dbc + (size_t)M * NDBC);
    unsigned short *wi16, *ow16, *dtwh, *dtwl, *xpwh, *xpwl, *dth, *dtl, *y16;
    size_t wiStride = 0, owStride = 0, dtwStride = 0, xpwStride = 0;
    if (fastw) {
        wi16 = p;                    p += (size_t)NDEPTH * NXZ * DIMK;
        ow16 = p;                    p += (size_t)NDEPTH * DIMK * DI;
        dtwh = p;                    p += (size_t)NDEPTH * DI * DTR;
        dtwl = p;                    p += (size_t)NDEPTH * DI * DTR;
        xpwh = p;                    p += (size_t)NDEPTH * NDBC * DI;
        xpwl = p;                    p += (size_t)NDEPTH * NDBC * DI;
        wiStride = (size_t)NXZ * DIMK; owStride = (size_t)DIMK * DI;
        dtwStride = (size_t)DI * DTR;  xpwStride = (size_t)NDBC * DI;
    } else {
        wi16 = p;                    p += (size_t)NXZ * DIMK;
        ow16 = p;                    p += (size_t)DIMK * DI;
        dtwh = p;                    p += (size_t)DI * DTR;
        dtwl = p;                    p += (size_t)DI * DTR;
        xpwh = nullptr; xpwl = nullptr;
    }
    dth = p;                         p += (size_t)M * DTR;
    dtl = p;                         p += (size_t)M * DTR;
    y16 = p;                         p += (size_t)M * DI;
    if (!fastw && fastx) { xpwh = p; p += (size_t)NDBC * DI; xpwl = p; }

    unsigned short* xb16 = (unsigned short*)d_out + (size_t)MT * DIMK;
    float* xbuf = (float*)d_out;

    const dim3 blk(256);
    if (fastx) {
        const int n4x0 = MT * DIMK / 4;
        cvt_bf16<<<dim3(n4x0 / 256), blk, 0, stream>>>(x0, xb16, n4x0);
    }
    if (fastw) {
        const int per = (NXZ * DIMK / 4) + (DIMK * DI / 4) + (DI * DTR / 4) +
                        (NDBC * DI / 4);
        cvt_all<<<dim3((NDEPTH * per + 255) / 256), blk, 0, stream>>>(
            in_w, ow, dtw, xpw, wi16, ow16, dtwh, dtwl, xpwh, xpwl);
    }
    const int ncv = (NXZ * DIMK / 4) + (DIMK * DI / 4) + (DI * DTR / 4) +
                    (NDBC * DI / 4);
    for (int ly = 0; ly < NDEPTH; ++ly) {
        const float* Wi   = in_w + (size_t)ly * NXZ * DIMK;
        const float* cwl  = cw   + (size_t)ly * DI * DCONV;
        const float* cbl  = cb   + (size_t)ly * DI;
        const float* xpl  = xpw  + (size_t)ly * NDBC * DI;
        const float* dtwl_ = dtw + (size_t)ly * DI * DTR;
        const float* dtbl = dtb  + (size_t)ly * DI;
        const float* Al   = Alog + (size_t)ly * DI * DS;
        const float* Dl   = Dp   + (size_t)ly * DI;
        const float* owl  = ow   + (size_t)ly * DIMK * DI;

        const unsigned short* wi16L = wi16 + (size_t)ly * wiStride;
        const unsigned short* ow16L = ow16 + (size_t)ly * owStride;
        const unsigned short* dtwhL = dtwh + (size_t)ly * dtwStride;
        const unsigned short* dtwlL = dtwl + (size_t)ly * dtwStride;
        const unsigned short* xpwhL = fastx ? xpwh + (size_t)ly * xpwStride : nullptr;
        const unsigned short* xpwlL = fastx ? xpwl + (size_t)ly * xpwStride : nullptr;

        if (fast && !fastw)
            cvt_layer<<<dim3((ncv + 255) / 256), blk, 0, stream>>>(
                Wi, owl, dtwl_, xpl, wi16, ow16, dtwh, dtwl,
                (unsigned short*)xpwh, (unsigned short*)xpwl, fastd, fastx);

        for (int ck = 0; ck < nchunks; ++ck) {
            if (fastx) {
                const unsigned short* xin16 = xb16 + (size_t)ck * M * DIMK;
                gemm_bb<0><<<dim3(NXZ / 128, M / 128), blk, 0, stream>>>(
                    xin16, wi16L, xz, DIMK, DIMK, DIMK, NXZ);
                conv_silu_split<<<dim3(M * (DI / 16) / 256), blk, 0, stream>>>(
                    xz, cwl, cbl, xch, xcl);
                gemm_xproj_pre<<<dim3(3, M / 128), blk, 0, stream>>>(
                    xch, xcl, xpwhL, xpwlL, dbc, dth, dtl);
                gemm_delta_pre<<<dim3(DI / 128, M / 128), blk, 0, stream>>>(
                    dth, dtl, dtwhL, dtwlL, xz, dtbl);
                scan_k<1, 1><<<dim3(DI / 16, nbc), blk, 0, stream>>>(
                    nullptr, xch, xcl, dbc, xz, y16, Al, Dl);
                void* dst = (ly < NDEPTH - 1)
                    ? (void*)(xb16 + (size_t)ck * M * DIMK)
                    : (void*)((float*)d_out + (size_t)ck * M * DIMK);
                if (ly < NDEPTH - 1)
                    gemm_bb<1><<<dim3(DIMK / 128, M / 128), blk, 0, stream>>>(
                        y16, ow16L, dst, DI, DI, DI, DIMK);
                else
                    gemm_bb<0><<<dim3(DIMK / 128, M / 128), blk, 0, stream>>>(
                        y16, ow16L, dst, DI, DI, DI, DIMK);
            } else if (fast) {
                if (ly == 0) {
                    const float* xin = x0 + (size_t)ck * M * DIMK;
                    gemm_fb<0><<<dim3(NXZ / 128, M / 128), blk, 0, stream>>>(
                        xin, wi16, xz, DIMK, DIMK, DIMK, NXZ);
                } else {
                    const unsigned short* xin16 = xb16 + (size_t)ck * M * DIMK;
                    gemm_bb<0><<<dim3(NXZ / 128, M / 128), blk, 0, stream>>>(
                        xin16, wi16, xz, DIMK, DIMK, DIMK, NXZ);
                }
                conv_silu<<<dim3(M * (DI / 16) / 256), blk, 0, stream>>>(
                    xz, cwl, cbl, xc);
                if (fastd) {
                    gemm_xproj<1><<<dim3(3, M / 128), blk, 0, stream>>>(
                        xc, xpl, dbc, DI, DI, dth, dtl);
                    gemm_delta_pre<<<dim3(DI / 128, M / 128), blk, 0, stream>>>(
                        dth, dtl, dtwh, dtwl, xz, dtbl);
                } else {
                    gemm_xproj<0><<<dim3(3, M / 128), blk, 0, stream>>>(
                        xc, xpl, dbc, DI, DI, nullptr, nullptr);
                    gemm_delta<<<dim3(DI / 128, M / 128), blk, 0, stream>>>(
                        dbc, dtwl_, xz, dtbl);
                }
                void* dst = (ly < NDEPTH - 1)
                    ? (void*)(xb16 + (size_t)ck * M * DIMK)
                    : (void*)((float*)d_out + (size_t)ck * M * DIMK);
                if (fasty) {
                    scan_k<1, 0><<<dim3(DI / 16, nbc), blk, 0, stream>>>(
                        xc, nullptr, nullptr, dbc, xz, y16, Al, Dl);
                    if (ly < NDEPTH - 1)
                        gemm_bb<1><<<dim3(DIMK / 128, M / 128), blk, 0, stream>>>(
                            y16, ow16, dst, DI, DI, DI, DIMK);
                    else
                        gemm_bb<0><<<dim3(DIMK / 128, M / 128), blk, 0, stream>>>(
                            y16, ow16, dst, DI, DI, DI, DIMK);
                } else {
                    scan_k<0, 0><<<dim3(DI / 16, nbc), blk, 0, stream>>>(
                        xc, nullptr, nullptr, dbc, xz, xc, Al, Dl);
                    if (ly < NDEPTH - 1)
                        gemm_fb<1><<<dim3(DIMK / 128, M / 128), blk, 0, stream>>>(
                            xc, ow16, dst, DI, DI, DI, DIMK);
                    else
                        gemm_fb<0><<<dim3(DIMK / 128, M / 128), blk, 0, stream>>>(
                            xc, ow16, dst, DI, DI, DI, DIMK);
                }
            } else {
                const float* xin = (ly == 0 ? x0 : xbuf) + (size_t)ck * M * DIMK;
                gemm_mfma<<<dim3(NXZ / 128, M / 128), blk, 0, stream>>>(
                    xin, Wi, xz, DIMK, DIMK, NXZ);
                conv_silu<<<dim3(M * (DI / 16) / 256), blk, 0, stream>>>(
                    xz, cwl, cbl, xc);
                gemm_xproj<0><<<dim3(3, M / 128), blk, 0, stream>>>(
                    xc, xpl, dbc, DI, DI, nullptr, nullptr);
                gemm_delta<<<dim3(DI / 128, M / 128), blk, 0, stream>>>(
                    dbc, dtwl_, xz, dtbl);
                scan_k<0, 0><<<dim3(DI / 16, nbc), blk, 0, stream>>>(
                    xc, nullptr, nullptr, dbc, xz, xc, Al, Dl);
                float* xdst = (ly == NDEPTH - 1 ? (float*)d_out : xbuf) +
                              (size_t)ck * M * DIMK;
                gemm_mfma<<<dim3(DIMK / 128, M / 128), blk, 0, stream>>>(
                    xc, owl, xdst, DI, DI, DIMK);
            }
        }
    }
}

// Round 13
// 1585.920 us; speedup vs baseline: 1.5280x; 1.0068x over previous
//
#include <hip/hip_runtime.h>
#include <hip/hip_bf16.h>
#include <math.h>

#define DIMK 1024
#define NDEPTH 4
#define DS 16
#define DCONV 4
#define DI 2048
#define DTR 64
#define NB 4
#define SL 2048
#define MT (NB * SL)        // 8192
#define NXZ (2 * DI)        // 4096
#define NDBC (DTR + 2 * DS) // 96

typedef float f32x4 __attribute__((ext_vector_type(4)));
typedef short short8 __attribute__((ext_vector_type(8)));
typedef short short4v __attribute__((ext_vector_type(4)));

__device__ inline unsigned short f2bf(float f) {
    unsigned u = __builtin_bit_cast(unsigned, f);
    unsigned r = (u + 0x7FFFu + ((u >> 16) & 1u)) >> 16;
    return (unsigned short)r;
}
__device__ inline float bf2f(unsigned short h) {
    unsigned u = ((unsigned)h) << 16;
    return __builtin_bit_cast(float, u);
}
__device__ inline void split_bf(float f, unsigned short& hi, unsigned short& lo) {
    hi = f2bf(f);
    lo = f2bf(f - bf2f(hi));
}
__device__ inline unsigned short cvt1(float f) {
    __hip_bfloat16 t = __float2bfloat16(f);
    return __builtin_bit_cast(unsigned short, t);
}
__device__ inline void mfma16(f32x4& d, short8 a, short8 b) {
    asm volatile("v_mfma_f32_16x16x32_bf16 %0, %1, %2, %0"
                 : "+v"(d) : "v"(a), "v"(b));
}
__device__ __forceinline__ float dpp_sum16(float p) {
    asm("v_add_f32_dpp %0, %0, %0 quad_perm:[1,0,3,2] row_mask:0xf bank_mask:0xf bound_ctrl:0" : "+v"(p));
    asm("v_add_f32_dpp %0, %0, %0 quad_perm:[2,3,0,1] row_mask:0xf bank_mask:0xf bound_ctrl:0" : "+v"(p));
    asm("v_add_f32_dpp %0, %0, %0 row_ror:4 row_mask:0xf bank_mask:0xf bound_ctrl:0" : "+v"(p));
    asm("v_add_f32_dpp %0, %0, %0 row_ror:8 row_mask:0xf bank_mask:0xf bound_ctrl:0" : "+v"(p));
    return p;
}
__device__ __forceinline__ float exp2_raw(float x) {
    float r;
    asm("v_exp_f32 %0, %1" : "=v"(r) : "v"(x));
    return r;
}
__device__ __forceinline__ void gload16(const unsigned short* g, unsigned short* l) {
    __builtin_amdgcn_global_load_lds(
        (const __attribute__((address_space(1))) unsigned int*)(g),
        (__attribute__((address_space(3))) unsigned int*)(l),
        16, 0, 0);
}

// ---------------------------------------------------------------------------
__global__ __launch_bounds__(256) void cvt_bf16(
    const float* __restrict__ s, unsigned short* __restrict__ d, int n4)
{
    const int g = blockIdx.x * 256 + threadIdx.x;
    if (g < n4) {
        const float4 f = *(const float4*)(s + (size_t)g * 4);
        short4v v;
        v[0] = (short)cvt1(f.x); v[1] = (short)cvt1(f.y);
        v[2] = (short)cvt1(f.z); v[3] = (short)cvt1(f.w);
        *(short4v*)(d + (size_t)g * 4) = v;
    }
}

// per-layer weight conversions (fallback when ws too small for prepass)
__global__ __launch_bounds__(256) void cvt_layer(
    const float* __restrict__ wi, const float* __restrict__ owp,
    const float* __restrict__ dtwp, const float* __restrict__ xpwp,
    unsigned short* __restrict__ wi16, unsigned short* __restrict__ ow16,
    unsigned short* __restrict__ dtwh, unsigned short* __restrict__ dtwl,
    unsigned short* __restrict__ xpwh, unsigned short* __restrict__ xpwl,
    int fastd, int fastx)
{
    int g = blockIdx.x * 256 + threadIdx.x;
    const int n4w = NXZ * DIMK / 4;
    const int n4o = DIMK * DI / 4;
    const int n4d = DI * DTR / 4;
    const int n4x = NDBC * DI / 4;
    if (g < n4w) {
        const float4 f = *(const float4*)(wi + (size_t)g * 4);
        short4v v;
        v[0] = (short)cvt1(f.x); v[1] = (short)cvt1(f.y);
        v[2] = (short)cvt1(f.z); v[3] = (short)cvt1(f.w);
        *(short4v*)(wi16 + (size_t)g * 4) = v;
        return;
    }
    g -= n4w;
    if (g < n4o) {
        const float4 f = *(const float4*)(owp + (size_t)g * 4);
        short4v v;
        v[0] = (short)cvt1(f.x); v[1] = (short)cvt1(f.y);
        v[2] = (short)cvt1(f.z); v[3] = (short)cvt1(f.w);
        *(short4v*)(ow16 + (size_t)g * 4) = v;
        return;
    }
    g -= n4o;
    if (g < n4d) {
        if (fastd) {
            const float4 f = *(const float4*)(dtwp + (size_t)g * 4);
            short4v h4, l4;
            #pragma unroll
            for (int e = 0; e < 4; ++e) {
                unsigned short h, l;
                split_bf((&f.x)[e], h, l);
                h4[e] = (short)h; l4[e] = (short)l;
            }
            *(short4v*)(dtwh + (size_t)g * 4) = h4;
            *(short4v*)(dtwl + (size_t)g * 4) = l4;
        }
        return;
    }
    g -= n4d;
    if (g < n4x && fastx) {
        const float4 f = *(const float4*)(xpwp + (size_t)g * 4);
        short4v h4, l4;
        #pragma unroll
        for (int e = 0; e < 4; ++e) {
            unsigned short h, l;
            split_bf((&f.x)[e], h, l);
            h4[e] = (short)h; l4[e] = (short)l;
        }
        *(short4v*)(xpwh + (size_t)g * 4) = h4;
        *(short4v*)(xpwl + (size_t)g * 4) = l4;
    }
}

// one-shot prepass: all 4 layers' weights
__global__ __launch_bounds__(256) void cvt_all(
    const float* __restrict__ wi, const float* __restrict__ owp,
    const float* __restrict__ dtwp, const float* __restrict__ xpwp,
    unsigned short* __restrict__ wi16, unsigned short* __restrict__ ow16,
    unsigned short* __restrict__ dtwh, unsigned short* __restrict__ dtwl,
    unsigned short* __restrict__ xpwh, unsigned short* __restrict__ xpwl)
{
    const int n4w = NXZ * DIMK / 4;
    const int n4o = DIMK * DI / 4;
    const int n4d = DI * DTR / 4;
    const int n4x = NDBC * DI / 4;
    const int per = n4w + n4o + n4d + n4x;
    int g = blockIdx.x * 256 + threadIdx.x;
    const int ly = g / per;
    if (ly >= NDEPTH) return;
    g -= ly * per;
    if (g < n4w) {
        const float4 f = *(const float4*)(wi + (size_t)ly * NXZ * DIMK + (size_t)g * 4);
        short4v v;
        v[0] = (short)cvt1(f.x); v[1] = (short)cvt1(f.y);
        v[2] = (short)cvt1(f.z); v[3] = (short)cvt1(f.w);
        *(short4v*)(wi16 + (size_t)ly * NXZ * DIMK + (size_t)g * 4) = v;
        return;
    }
    g -= n4w;
    if (g < n4o) {
        const float4 f = *(const float4*)(owp + (size_t)ly * DIMK * DI + (size_t)g * 4);
        short4v v;
        v[0] = (short)cvt1(f.x); v[1] = (short)cvt1(f.y);
        v[2] = (short)cvt1(f.z); v[3] = (short)cvt1(f.w);
        *(short4v*)(ow16 + (size_t)ly * DIMK * DI + (size_t)g * 4) = v;
        return;
    }
    g -= n4o;
    if (g < n4d) {
        const float4 f = *(const float4*)(dtwp + (size_t)ly * DI * DTR + (size_t)g * 4);
        short4v h4, l4;
        #pragma unroll
        for (int e = 0; e < 4; ++e) {
            unsigned short h, l;
            split_bf((&f.x)[e], h, l);
            h4[e] = (short)h; l4[e] = (short)l;
        }
        *(short4v*)(dtwh + (size_t)ly * DI * DTR + (size_t)g * 4) = h4;
        *(short4v*)(dtwl + (size_t)ly * DI * DTR + (size_t)g * 4) = l4;
        return;
    }
    g -= n4d;
    if (g < n4x) {
        const float4 f = *(const float4*)(xpwp + (size_t)ly * NDBC * DI + (size_t)g * 4);
        short4v h4, l4;
        #pragma unroll
        for (int e = 0; e < 4; ++e) {
            unsigned short h, l;
            split_bf((&f.x)[e], h, l);
            h4[e] = (short)h; l4[e] = (short)l;
        }
        *(short4v*)(xpwh + (size_t)ly * NDBC * DI + (size_t)g * 4) = h4;
        *(short4v*)(xpwl + (size_t)ly * NDBC * DI + (size_t)g * 4) = l4;
    }
}

// ---------------------------------------------------------------------------
// C[m,n] = sum_k A[m,k]*B[n,k]; A,B bf16 global. BK=64 single-buffer
// (half the barrier drains per FLOP) + XCD swizzle. CBF: 1 -> bf16 C.
// LDS layout: row-major [128][64] shorts with group involution g ^= (row&7)
// applied on the pre-swizzled GLOBAL source (linear gload dest) and on reads.
template <int CBF>
__global__ __launch_bounds__(256) void gemm_bb(
    const unsigned short* __restrict__ A, const unsigned short* __restrict__ B,
    void* __restrict__ Cv, int K, int lda, int ldb, int ldc)
{
    __shared__ unsigned short As[128 * 64];
    __shared__ unsigned short Bs[128 * 64];
    int id = blockIdx.y * gridDim.x + blockIdx.x;
    const int qq = (gridDim.x * gridDim.y) >> 3;
    id = (id & 7) * qq + (id >> 3);
    const int bm = (id / gridDim.x) * 128, bn = (id % gridDim.x) * 128;

    const int tid = threadIdx.x;
    const int wv = tid >> 6, ln = tid & 63;
    const int wr = wv >> 1, wc = wv & 1;
    const int fr = ln & 15, kg = ln >> 4;

    // staging: wave wv covers rows wv*32 .. wv*32+31 in 4 instrs of 8 rows
    const unsigned short* pa[4];
    const unsigned short* pb[4];
    unsigned short* la[4];
    unsigned short* lb[4];
    #pragma unroll
    for (int j = 0; j < 4; ++j) {
        const int Rj = wv * 32 + j * 8;
        const int r = Rj + (ln >> 3);
        const int gs = (ln & 7) ^ (r & 7);   // pre-swizzled source group
        pa[j] = A + (size_t)(bm + r) * lda + gs * 8;
        pb[j] = B + (size_t)(bn + r) * ldb + gs * 8;
        la[j] = As + Rj * 64;
        lb[j] = Bs + Rj * 64;
    }
    // fragment read offsets (shorts): [kh][f]
    int offA[2][4], offB[2][4];
    #pragma unroll
    for (int kh = 0; kh < 2; ++kh)
        #pragma unroll
        for (int f = 0; f < 4; ++f) {
            const int ra = wr * 64 + f * 16 + fr;
            offA[kh][f] = ra * 64 + (((kh * 4 + kg) ^ (ra & 7)) * 8);
            const int rb = wc * 64 + f * 16 + fr;
            offB[kh][f] = rb * 64 + (((kh * 4 + kg) ^ (rb & 7)) * 8);
        }
    f32x4 acc[4][4] = {};
    for (int k0 = 0; k0 < K; k0 += 64) {
        #pragma unroll
        for (int j = 0; j < 4; ++j) {
            gload16(pa[j] + k0, la[j]);
            gload16(pb[j] + k0, lb[j]);
        }
        __syncthreads();
        #pragma unroll
        for (int kh = 0; kh < 2; ++kh) {
            short8 af[4], bw[4];
            #pragma unroll
            for (int f = 0; f < 4; ++f) {
                af[f] = *(const short8*)&As[offA[kh][f]];
                bw[f] = *(const short8*)&Bs[offB[kh][f]];
            }
            #pragma unroll
            for (int fi = 0; fi < 4; ++fi)
                #pragma unroll
                for (int fj = 0; fj < 4; ++fj)
                    mfma16(acc[fi][fj], af[fi], bw[fj]);
        }
        __syncthreads();
    }
    #pragma unroll
    for (int fi = 0; fi < 4; ++fi) {
        const int m0 = bm + wr * 64 + fi * 16 + kg * 4;
        #pragma unroll
        for (int fj = 0; fj < 4; ++fj) {
            const int n = bn + wc * 64 + fj * 16 + fr;
            #pragma unroll
            for (int q = 0; q < 4; ++q) {
                if (CBF) {
                    unsigned short* Cs = (unsigned short*)Cv;
                    Cs[(size_t)(m0 + q) * ldc + n] = cvt1(acc[fi][fj][q]);
                } else {
                    float* Cf = (float*)Cv;
                    Cf[(size_t)(m0 + q) * ldc + n] = acc[fi][fj][q];
                }
            }
        }
    }
}

// ---------------------------------------------------------------------------
// A fp32 (reg prefetch + cvt), B bf16 (gload dbuf). CBF: bf16 C. (mid path)
template <int CBF>
__global__ __launch_bounds__(256) void gemm_fb(
    const float* __restrict__ A, const unsigned short* __restrict__ B,
    void* __restrict__ Cv, int K, int lda, int ldb, int ldc)
{
    __shared__ unsigned short As[2][128 * 32];
    __shared__ unsigned short Bs[2][128 * 32];
    int id = blockIdx.y * gridDim.x + blockIdx.x;
    const int qq = (gridDim.x * gridDim.y) >> 3;
    id = (id & 7) * qq + (id >> 3);
    const int bm = (id / gridDim.x) * 128, bn = (id % gridDim.x) * 128;

    const int tid = threadIdx.x;
    const int wv = tid >> 6, ln = tid & 63;
    const int wr = wv >> 1, wc = wv & 1;
    const int fr = ln & 15, kg = ln >> 4;
    const int r = tid >> 1, hf = tid & 1;
    const int sr0 = wv * 32 + (ln >> 2);
    const int sr1 = sr0 + 16;
    const int sl = ln & 3;
    const int cg0 = sl ^ ((sr0 >> 1) & 3);
    const int cg1 = sl ^ ((sr1 >> 1) & 3);
    const unsigned short* pb0 = B + (size_t)(bn + sr0) * ldb + cg0 * 8;
    const unsigned short* pb1 = B + (size_t)(bn + sr1) * ldb + cg1 * 8;
    const int ldst0 = (wv * 32 + 0) * 32;
    const int ldst1 = (wv * 32 + 16) * 32;
    const float* ga = A + (size_t)(bm + r) * lda + hf * 16;
    const int pk0 = (2 * hf + 0) ^ ((r >> 1) & 3);
    const int pk1 = (2 * hf + 1) ^ ((r >> 1) & 3);
    int offA[4], offB[4];
    #pragma unroll
    for (int f = 0; f < 4; ++f) {
        const int ra = wr * 64 + f * 16 + fr;
        offA[f] = ra * 32 + ((kg ^ ((ra >> 1) & 3)) * 8);
        const int rb = wc * 64 + f * 16 + fr;
        offB[f] = rb * 32 + ((kg ^ ((rb >> 1) & 3)) * 8);
    }
    f32x4 acc[4][4] = {};
    {
        float4 f0 = *(const float4*)(ga + 0);
        float4 f1 = *(const float4*)(ga + 4);
        float4 f2 = *(const float4*)(ga + 8);
        float4 f3 = *(const float4*)(ga + 12);
        short8 v;
        v[0] = (short)cvt1(f0.x); v[1] = (short)cvt1(f0.y);
        v[2] = (short)cvt1(f0.z); v[3] = (short)cvt1(f0.w);
        v[4] = (short)cvt1(f1.x); v[5] = (short)cvt1(f1.y);
        v[6] = (short)cvt1(f1.z); v[7] = (short)cvt1(f1.w);
        *(short8*)&As[0][r * 32 + pk0 * 8] = v;
        v[0] = (short)cvt1(f2.x); v[1] = (short)cvt1(f2.y);
        v[2] = (short)cvt1(f2.z); v[3] = (short)cvt1(f2.w);
        v[4] = (short)cvt1(f3.x); v[5] = (short)cvt1(f3.y);
        v[6] = (short)cvt1(f3.z); v[7] = (short)cvt1(f3.w);
        *(short8*)&As[0][r * 32 + pk1 * 8] = v;
        gload16(pb0, &Bs[0][ldst0]);
        gload16(pb1, &Bs[0][ldst1]);
    }
    __syncthreads();
    int cur = 0;
    for (int k0 = 0; k0 < K; k0 += 32) {
        const int nxt = cur ^ 1;
        const bool more = (k0 + 32 < K);
        float4 f0, f1, f2, f3;
        if (more) {
            gload16(pb0 + k0 + 32, &Bs[nxt][ldst0]);
            gload16(pb1 + k0 + 32, &Bs[nxt][ldst1]);
            f0 = *(const float4*)(ga + k0 + 32);
            f1 = *(const float4*)(ga + k0 + 36);
            f2 = *(const float4*)(ga + k0 + 40);
            f3 = *(const float4*)(ga + k0 + 44);
        }
        short8 af[4], bw[4];
        #pragma unroll
        for (int f = 0; f < 4; ++f) {
            af[f] = *(const short8*)&As[cur][offA[f]];
            bw[f] = *(const short8*)&Bs[cur][offB[f]];
        }
        #pragma unroll
        for (int fi = 0; fi < 4; ++fi)
            #pragma unroll
            for (int fj = 0; fj < 4; ++fj)
                mfma16(acc[fi][fj], af[fi], bw[fj]);
        if (more) {
            short8 v;
            v[0] = (short)cvt1(f0.x); v[1] = (short)cvt1(f0.y);
            v[2] = (short)cvt1(f0.z); v[3] = (short)cvt1(f0.w);
            v[4] = (short)cvt1(f1.x); v[5] = (short)cvt1(f1.y);
            v[6] = (short)cvt1(f1.z); v[7] = (short)cvt1(f1.w);
            *(short8*)&As[nxt][r * 32 + pk0 * 8] = v;
            v[0] = (short)cvt1(f2.x); v[1] = (short)cvt1(f2.y);
            v[2] = (short)cvt1(f2.z); v[3] = (short)cvt1(f2.w);
            v[4] = (short)cvt1(f3.x); v[5] = (short)cvt1(f3.y);
            v[6] = (short)cvt1(f3.z); v[7] = (short)cvt1(f3.w);
            *(short8*)&As[nxt][r * 32 + pk1 * 8] = v;
        }
        __syncthreads();
        cur = nxt;
    }
    #pragma unroll
    for (int fi = 0; fi < 4; ++fi) {
        const int m0 = bm + wr * 64 + fi * 16 + kg * 4;
        #pragma unroll
        for (int fj = 0; fj < 4; ++fj) {
            const int n = bn + wc * 64 + fj * 16 + fr;
            #pragma unroll
            for (int q = 0; q < 4; ++q) {
                if (CBF) {
                    unsigned short* Cs = (unsigned short*)Cv;
                    Cs[(size_t)(m0 + q) * ldc + n] = cvt1(acc[fi][fj][q]);
                } else {
                    float* Cf = (float*)Cv;
                    Cf[(size_t)(m0 + q) * ldc + n] = acc[fi][fj][q];
                }
            }
        }
    }
}

// ---------------------------------------------------------------------------
// fallback GEMM (fp32 in/out), used only if ws too small
__global__ __launch_bounds__(256) void gemm_mfma(
    const float* __restrict__ A, const float* __restrict__ W,
    float* __restrict__ C, int K, int lda, int ldc)
{
    __shared__ unsigned short As[128 * 32];
    __shared__ unsigned short Ws[128 * 32];
    const int tid = threadIdx.x;
    const int bm = blockIdx.y * 128;
    const int bn = blockIdx.x * 128;
    const int r = tid >> 1;
    const int h = tid & 1;
    const int wv = tid >> 6;
    const int wr = wv >> 1;
    const int wc = wv & 1;
    const int ln = tid & 63;
    const int fr = ln & 15;
    const int kg = ln >> 4;
    f32x4 acc[4][4] = {};
    const float* ga = A + (size_t)(bm + r) * lda + h * 16;
    const float* gw = W + (size_t)(bn + r) * K + h * 16;
    for (int k0 = 0; k0 < K; k0 += 32) {
        #pragma unroll
        for (int p = 0; p < 2; ++p) {
            const int pk = (2 * h + p) ^ ((r >> 1) & 3);
            float4 f0 = *(const float4*)(ga + k0 + p * 8);
            float4 f1 = *(const float4*)(ga + k0 + p * 8 + 4);
            short8 v;
            v[0] = (short)cvt1(f0.x); v[1] = (short)cvt1(f0.y);
            v[2] = (short)cvt1(f0.z); v[3] = (short)cvt1(f0.w);
            v[4] = (short)cvt1(f1.x); v[5] = (short)cvt1(f1.y);
            v[6] = (short)cvt1(f1.z); v[7] = (short)cvt1(f1.w);
            *(short8*)&As[r * 32 + pk * 8] = v;
            f0 = *(const float4*)(gw + k0 + p * 8);
            f1 = *(const float4*)(gw + k0 + p * 8 + 4);
            v[0] = (short)cvt1(f0.x); v[1] = (short)cvt1(f0.y);
            v[2] = (short)cvt1(f0.z); v[3] = (short)cvt1(f0.w);
            v[4] = (short)cvt1(f1.x); v[5] = (short)cvt1(f1.y);
            v[6] = (short)cvt1(f1.z); v[7] = (short)cvt1(f1.w);
            *(short8*)&Ws[r * 32 + pk * 8] = v;
        }
        __syncthreads();
        short8 af[4], bw[4];
        #pragma unroll
        for (int f = 0; f < 4; ++f) {
            const int ra = wr * 64 + f * 16 + fr;
            af[f] = *(const short8*)&As[ra * 32 + ((kg ^ ((ra >> 1) & 3)) * 8)];
            const int rb = wc * 64 + f * 16 + fr;
            bw[f] = *(const short8*)&Ws[rb * 32 + ((kg ^ ((rb >> 1) & 3)) * 8)];
        }
        #pragma unroll
        for (int fi = 0; fi < 4; ++fi)
            #pragma unroll
            for (int fj = 0; fj < 4; ++fj)
                mfma16(acc[fi][fj], af[fi], bw[fj]);
        __syncthreads();
    }
    #pragma unroll
    for (int fi = 0; fi < 4; ++fi) {
        const int m0 = bm + wr * 64 + fi * 16 + kg * 4;
        #pragma unroll
        for (int fj = 0; fj < 4; ++fj) {
            const int n = bn + wc * 64 + fj * 16 + fr;
            #pragma unroll
            for (int q = 0; q < 4; ++q)
                C[(size_t)(m0 + q) * ldc + n] = acc[fi][fj][q];
        }
    }
}

// ---------------------------------------------------------------------------
// x_proj fast: A = pre-split xc (xch/xcl), W = pre-split xpw. Pure gload+MFMA.
__global__ __launch_bounds__(256) void gemm_xproj_pre(
    const unsigned short* __restrict__ Ahg, const unsigned short* __restrict__ Alg,
    const unsigned short* __restrict__ Whg, const unsigned short* __restrict__ Wlg,
    float* __restrict__ C,
    unsigned short* __restrict__ dth, unsigned short* __restrict__ dtl)
{
    __shared__ unsigned short Ahs[2][128 * 32], Als[2][128 * 32];
    __shared__ unsigned short Whs[2][32 * 32], Wls[2][32 * 32];
    int id = blockIdx.y * gridDim.x + blockIdx.x;
    const int qq = (gridDim.x * gridDim.y) >> 3;
    id = (id & 7) * qq + (id >> 3);
    const int bm = (id / gridDim.x) * 128, bn = (id % gridDim.x) * 32;

    const int tid = threadIdx.x;
    const int wv = tid >> 6, ln = tid & 63;
    const int fr = ln & 15, kg = ln >> 4;
    const int sr0 = wv * 32 + (ln >> 2);
    const int sr1 = sr0 + 16;
    const int sl = ln & 3;
    const int cg0 = sl ^ ((sr0 >> 1) & 3);
    const int cg1 = sl ^ ((sr1 >> 1) & 3);
    const unsigned short* pah0 = Ahg + (size_t)(bm + sr0) * DI + cg0 * 8;
    const unsigned short* pah1 = Ahg + (size_t)(bm + sr1) * DI + cg1 * 8;
    const unsigned short* pal0 = Alg + (size_t)(bm + sr0) * DI + cg0 * 8;
    const unsigned short* pal1 = Alg + (size_t)(bm + sr1) * DI + cg1 * 8;
    const int lA0 = (wv * 32 + 0) * 32;
    const int lA1 = (wv * 32 + 16) * 32;
    const int wrow = (wv & 1) * 16 + (ln >> 2);
    const int cgw = sl ^ ((wrow >> 1) & 3);
    const unsigned short* pw = ((wv < 2) ? Whg : Wlg) + (size_t)(bn + wrow) * DI + cgw * 8;
    const int lW = ((wv & 1) * 16) * 32;
    unsigned short* wdst[2];
    wdst[0] = (wv < 2) ? &Whs[0][lW] : &Wls[0][lW];
    wdst[1] = (wv < 2) ? &Whs[1][lW] : &Wls[1][lW];

    int offA[2], offW[2];
    #pragma unroll
    for (int f = 0; f < 2; ++f) {
        const int ra = wv * 32 + f * 16 + fr;
        offA[f] = ra * 32 + ((kg ^ ((ra >> 1) & 3)) * 8);
        const int rb = f * 16 + fr;
        offW[f] = rb * 32 + ((kg ^ ((rb >> 1) & 3)) * 8);
    }
    f32x4 acc[2][2] = {};
    gload16(pah0, &Ahs[0][lA0]);
    gload16(pah1, &Ahs[0][lA1]);
    gload16(pal0, &Als[0][lA0]);
    gload16(pal1, &Als[0][lA1]);
    gload16(pw, wdst[0]);
    __syncthreads();
    int cur = 0;
    for (int k0 = 0; k0 < DI; k0 += 32) {
        const int nxt = cur ^ 1;
        if (k0 + 32 < DI) {
            gload16(pah0 + k0 + 32, &Ahs[nxt][lA0]);
            gload16(pah1 + k0 + 32, &Ahs[nxt][lA1]);
            gload16(pal0 + k0 + 32, &Als[nxt][lA0]);
            gload16(pal1 + k0 + 32, &Als[nxt][lA1]);
            gload16(pw + k0 + 32, wdst[nxt]);
        }
        short8 ah[2], alo[2], bh[2], bl[2];
        #pragma unroll
        for (int f = 0; f < 2; ++f) {
            ah[f]  = *(const short8*)&Ahs[cur][offA[f]];
            alo[f] = *(const short8*)&Als[cur][offA[f]];
            bh[f]  = *(const short8*)&Whs[cur][offW[f]];
            bl[f]  = *(const short8*)&Wls[cur][offW[f]];
        }
        #pragma unroll
        for (int fi = 0; fi < 2; ++fi)
            #pragma unroll
            for (int fj = 0; fj < 2; ++fj) {
                mfma16(acc[fi][fj], ah[fi], bh[fj]);
                mfma16(acc[fi][fj], ah[fi], bl[fj]);
                mfma16(acc[fi][fj], alo[fi], bh[fj]);
            }
        __syncthreads();
        cur = nxt;
    }
    #pragma unroll
    for (int fi = 0; fi < 2; ++fi) {
        const int m0 = bm + wv * 32 + fi * 16 + kg * 4;
        #pragma unroll
        for (int fj = 0; fj < 2; ++fj) {
            const int n = bn + fj * 16 + fr;
            #pragma unroll
            for (int q = 0; q < 4; ++q) {
                const float v = acc[fi][fj][q];
                C[(size_t)(m0 + q) * NDBC + n] = v;
                if (n < DTR) {
                    unsigned short hh, llo;
                    split_bf(v, hh, llo);
                    dth[(size_t)(m0 + q) * DTR + n] = hh;
                    dtl[(size_t)(m0 + q) * DTR + n] = llo;
                }
            }
        }
    }
}

// ---------------------------------------------------------------------------
// x_proj fallback: split in-kernel from fp32 xc. BM=128, BN=32.
template <int WRDT>
__global__ __launch_bounds__(256) void gemm_xproj(
    const float* __restrict__ A, const float* __restrict__ W,
    float* __restrict__ C, int K, int lda,
    unsigned short* __restrict__ dth, unsigned short* __restrict__ dtl)
{
    __shared__ unsigned short Ah[128 * 32], Al[128 * 32];
    __shared__ unsigned short Wh[32 * 32], Wl[32 * 32];
    const int tid = threadIdx.x;
    const int bm = blockIdx.y * 128;
    const int bn = blockIdx.x * 32;
    const int r = tid >> 1, hf = tid & 1;
    const int wv = tid >> 6;
    const int ln = tid & 63, fr = ln & 15, kg = ln >> 4;
    const int wsr = tid >> 3;
    const int wc4 = (tid & 7) << 2;
    f32x4 acc[2][2] = {};
    const float* ga = A + (size_t)(bm + r) * lda + hf * 16;
    const float* gw = W + (size_t)(bn + wsr) * K + wc4;
    for (int k0 = 0; k0 < K; k0 += 32) {
        #pragma unroll
        for (int j = 0; j < 4; ++j) {
            const int col = hf * 16 + j * 4;
            const int ad = r * 32 + (((col >> 3) ^ ((r >> 1) & 3)) << 3) + (col & 7);
            const float4 fa = *(const float4*)(ga + k0 + j * 4);
            short4v h4, l4;
            #pragma unroll
            for (int e = 0; e < 4; ++e) {
                unsigned short hh, llo;
                split_bf((&fa.x)[e], hh, llo);
                h4[e] = (short)hh; l4[e] = (short)llo;
            }
            *(short4v*)&Ah[ad] = h4;
            *(short4v*)&Al[ad] = l4;
        }
        {
            const int ad = wsr * 32 + (((wc4 >> 3) ^ ((wsr >> 1) & 3)) << 3) + (wc4 & 7);
            const float4 fw = *(const float4*)(gw + k0);
            short4v h4, l4;
            #pragma unroll
            for (int e = 0; e < 4; ++e) {
                unsigned short hh, llo;
                split_bf((&fw.x)[e], hh, llo);
                h4[e] = (short)hh; l4[e] = (short)llo;
            }
            *(short4v*)&Wh[ad] = h4;
            *(short4v*)&Wl[ad] = l4;
        }
        __syncthreads();
        short8 ah[2], alo[2], bh[2], bl[2];
        #pragma unroll
        for (int f = 0; f < 2; ++f) {
            const int ra = wv * 32 + f * 16 + fr;
            const int ao = ra * 32 + ((kg ^ ((ra >> 1) & 3)) * 8);
            ah[f]  = *(const short8*)&Ah[ao];
            alo[f] = *(const short8*)&Al[ao];
            const int rb = f * 16 + fr;
            const int bo = rb * 32 + ((kg ^ ((rb >> 1) & 3)) * 8);
            bh[f] = *(const short8*)&Wh[bo];
            bl[f] = *(const short8*)&Wl[bo];
        }
        #pragma unroll
        for (int fi = 0; fi < 2; ++fi)
            #pragma unroll
            for (int fj = 0; fj < 2; ++fj) {
                mfma16(acc[fi][fj], ah[fi], bh[fj]);
                mfma16(acc[fi][fj], ah[fi], bl[fj]);
                mfma16(acc[fi][fj], alo[fi], bh[fj]);
            }
        __syncthreads();
    }
    #pragma unroll
    for (int fi = 0; fi < 2; ++fi) {
        const int m0 = bm + wv * 32 + fi * 16 + kg * 4;
        #pragma unroll
        for (int fj = 0; fj < 2; ++fj) {
            const int n = bn + fj * 16 + fr;
            #pragma unroll
            for (int q = 0; q < 4; ++q) {
                const float v = acc[fi][fj][q];
                C[(size_t)(m0 + q) * NDBC + n] = v;
                if (WRDT && n < DTR) {
                    unsigned short hh, llo;
                    split_bf(v, hh, llo);
                    dth[(size_t)(m0 + q) * DTR + n] = hh;
                    dtl[(size_t)(m0 + q) * DTR + n] = llo;
                }
            }
        }
    }
}

// ---------------------------------------------------------------------------
// delta (fallback): split in-kernel from fp32 dbc/dtw. K=64.
__global__ __launch_bounds__(256) void gemm_delta(
    const float* __restrict__ A, const float* __restrict__ W,
    float* __restrict__ C, const float* __restrict__ bias)
{
    __shared__ unsigned short Ah[128 * 32], Al[128 * 32];
    __shared__ unsigned short Wh[128 * 32], Wl[128 * 32];
    const int tid = threadIdx.x;
    const int bm = blockIdx.y * 128;
    const int bn = blockIdx.x * 128;
    const int r = tid >> 1, hf = tid & 1;
    const int wv = tid >> 6, wr = wv >> 1, wc = wv & 1;
    const int ln = tid & 63, fr = ln & 15, kg = ln >> 4;
    f32x4 acc[4][4] = {};
    const float* ga = A + (size_t)(bm + r) * NDBC + hf * 16;
    const float* gw = W + (size_t)(bn + r) * DTR + hf * 16;
    for (int k0 = 0; k0 < DTR; k0 += 32) {
        #pragma unroll
        for (int j = 0; j < 4; ++j) {
            const int col = hf * 16 + j * 4;
            const int ad = r * 32 + (((col >> 3) ^ ((r >> 1) & 3)) << 3) + (col & 7);
            const float4 fa = *(const float4*)(ga + k0 + j * 4);
            const float4 fw = *(const float4*)(gw + k0 + j * 4);
            short4v ah4, al4, wh4, wl4;
            #pragma unroll
            for (int e = 0; e < 4; ++e) {
                unsigned short hh, llo;
                split_bf((&fa.x)[e], hh, llo);
                ah4[e] = (short)hh; al4[e] = (short)llo;
                split_bf((&fw.x)[e], hh, llo);
                wh4[e] = (short)hh; wl4[e] = (short)llo;
            }
            *(short4v*)&Ah[ad] = ah4; *(short4v*)&Al[ad] = al4;
            *(short4v*)&Wh[ad] = wh4; *(short4v*)&Wl[ad] = wl4;
        }
        __syncthreads();
        short8 ah[4], alo[4], bh[4], bl[4];
        #pragma unroll
        for (int f = 0; f < 4; ++f) {
            const int ra = wr * 64 + f * 16 + fr;
            const int ao = ra * 32 + ((kg ^ ((ra >> 1) & 3)) * 8);
            ah[f]  = *(const short8*)&Ah[ao];
            alo[f] = *(const short8*)&Al[ao];
            const int rb = wc * 64 + f * 16 + fr;
            const int bo = rb * 32 + ((kg ^ ((rb >> 1) & 3)) * 8);
            bh[f] = *(const short8*)&Wh[bo];
            bl[f] = *(const short8*)&Wl[bo];
        }
        #pragma unroll
        for (int fi = 0; fi < 4; ++fi)
            #pragma unroll
            for (int fj = 0; fj < 4; ++fj) {
                mfma16(acc[fi][fj], ah[fi], bh[fj]);
                mfma16(acc[fi][fj], ah[fi], bl[fj]);
                mfma16(acc[fi][fj], alo[fi], bh[fj]);
            }
        __syncthreads();
    }
    #pragma unroll
    for (int fi = 0; fi < 4; ++fi) {
        const int m0 = bm + wr * 64 + fi * 16 + kg * 4;
        #pragma unroll
        for (int fj = 0; fj < 4; ++fj) {
            const int n = bn + wc * 64 + fj * 16 + fr;
            const float bb = bias[n];
            #pragma unroll
            for (int q = 0; q < 4; ++q) {
                float v = acc[fi][fj][q] + bb;
                v = (v > 20.f) ? v : log1pf(__expf(v));
                C[(size_t)(m0 + q) * NXZ + n] = v;
            }
        }
    }
}

// ---------------------------------------------------------------------------
// delta (fast): all operands pre-split bf16; single stage via gload, K=64.
__global__ __launch_bounds__(256) void gemm_delta_pre(
    const unsigned short* __restrict__ Ahg, const unsigned short* __restrict__ Alg,
    const unsigned short* __restrict__ Whg, const unsigned short* __restrict__ Wlg,
    float* __restrict__ C, const float* __restrict__ bias)
{
    __shared__ unsigned short sAh[128 * 64], sAl[128 * 64];
    __shared__ unsigned short sWh[128 * 64], sWl[128 * 64];
    const int tid = threadIdx.x;
    const int bm = blockIdx.y * 128;
    const int bn = blockIdx.x * 128;
    const int wv = tid >> 6, ln = tid & 63;
    const int wr = wv >> 1, wc = wv & 1;
    const int fr = ln & 15, kg = ln >> 4;
    const int srow = ln >> 3;
    const int g = ln & 7;
    const int half = g >> 2, sub = g & 3;
    #pragma unroll
    for (int j = 0; j < 4; ++j) {
        const int row = wv * 32 + j * 8 + srow;
        const int sub2 = sub ^ ((row >> 1) & 3);
        const int scol = half * 32 + sub2 * 8;
        const int dst = (wv * 32 + j * 8) * 64;
        gload16(Ahg + (size_t)(bm + row) * DTR + scol, sAh + dst);
        gload16(Alg + (size_t)(bm + row) * DTR + scol, sAl + dst);
        gload16(Whg + (size_t)(bn + row) * DTR + scol, sWh + dst);
        gload16(Wlg + (size_t)(bn + row) * DTR + scol, sWl + dst);
    }
    __syncthreads();
    f32x4 acc[4][4] = {};
    #pragma unroll
    for (int ks = 0; ks < 2; ++ks) {
        short8 ah[4], alo[4], bh[4], bl[4];
        #pragma unroll
        for (int f = 0; f < 4; ++f) {
            const int ra = wr * 64 + f * 16 + fr;
            const int ao = ra * 64 + ks * 32 + ((kg ^ ((ra >> 1) & 3)) * 8);
            ah[f]  = *(const short8*)&sAh[ao];
            alo[f] = *(const short8*)&sAl[ao];
            const int rb = wc * 64 + f * 16 + fr;
            const int bo = rb * 64 + ks * 32 + ((kg ^ ((rb >> 1) & 3)) * 8);
            bh[f] = *(const short8*)&sWh[bo];
            bl[f] = *(const short8*)&sWl[bo];
        }
        #pragma unroll
        for (int fi = 0; fi < 4; ++fi)
            #pragma unroll
            for (int fj = 0; fj < 4; ++fj) {
                mfma16(acc[fi][fj], ah[fi], bh[fj]);
                mfma16(acc[fi][fj], ah[fi], bl[fj]);
                mfma16(acc[fi][fj], alo[fi], bh[fj]);
            }
    }
    #pragma unroll
    for (int fi = 0; fi < 4; ++fi) {
        const int m0 = bm + wr * 64 + fi * 16 + kg * 4;
        #pragma unroll
        for (int fj = 0; fj < 4; ++fj) {
            const int n = bn + wc * 64 + fj * 16 + fr;
            const float bb = bias[n];
            #pragma unroll
            for (int q = 0; q < 4; ++q) {
                float v = acc[fi][fj][q] + bb;
                v = (v > 20.f) ? v : log1pf(__expf(v));
                C[(size_t)(m0 + q) * NXZ + n] = v;
            }
        }
    }
}

// ---------------------------------------------------------------------------
// conv+silu, fp32 out (fallback path)
__global__ __launch_bounds__(256) void conv_silu(
    const float* __restrict__ xz, const float* __restrict__ cw,
    const float* __restrict__ cb, float* __restrict__ xc)
{
    const int g = blockIdx.x * 256 + threadIdx.x;
    const int c4 = g & (DI / 4 - 1);
    const int mq = g >> 9;
    const int m0 = mq << 2;
    const int l0 = m0 & (SL - 1);
    const int c = c4 << 2;
    const float4 w0 = *(const float4*)(cw + (size_t)(c + 0) * DCONV);
    const float4 w1 = *(const float4*)(cw + (size_t)(c + 1) * DCONV);
    const float4 w2 = *(const float4*)(cw + (size_t)(c + 2) * DCONV);
    const float4 w3 = *(const float4*)(cw + (size_t)(c + 3) * DCONV);
    const float4 cb4 = *(const float4*)(cb + c);
    float4 x[7];
    #pragma unroll
    for (int i = 0; i < 7; ++i) {
        if (l0 - 3 + i >= 0)
            x[i] = *(const float4*)(xz + (size_t)(m0 - 3 + i) * NXZ + c);
        else
            x[i] = make_float4(0.f, 0.f, 0.f, 0.f);
    }
    #pragma unroll
    for (int j = 0; j < 4; ++j) {
        float4 acc = cb4;
        #pragma unroll
        for (int k = 0; k < DCONV; ++k) {
            const float4 v = x[j + k];
            acc.x = fmaf(v.x, (&w0.x)[k], acc.x);
            acc.y = fmaf(v.y, (&w1.x)[k], acc.y);
            acc.z = fmaf(v.z, (&w2.x)[k], acc.z);
            acc.w = fmaf(v.w, (&w3.x)[k], acc.w);
        }
        acc.x = acc.x / (1.f + __expf(-acc.x));
        acc.y = acc.y / (1.f + __expf(-acc.y));
        acc.z = acc.z / (1.f + __expf(-acc.z));
        acc.w = acc.w / (1.f + __expf(-acc.w));
        *(float4*)(xc + (size_t)(m0 + j) * DI + c) = acc;
    }
}

// conv+silu, split bf16 (hi,lo) out
__global__ __launch_bounds__(256) void conv_silu_split(
    const float* __restrict__ xz, const float* __restrict__ cw,
    const float* __restrict__ cb, unsigned short* __restrict__ xch,
    unsigned short* __restrict__ xcl)
{
    const int g = blockIdx.x * 256 + threadIdx.x;
    const int c4 = g & (DI / 4 - 1);
    const int mq = g >> 9;
    const int m0 = mq << 2;
    const int l0 = m0 & (SL - 1);
    const int c = c4 << 2;
    const float4 w0 = *(const float4*)(cw + (size_t)(c + 0) * DCONV);
    const float4 w1 = *(const float4*)(cw + (size_t)(c + 1) * DCONV);
    const float4 w2 = *(const float4*)(cw + (size_t)(c + 2) * DCONV);
    const float4 w3 = *(const float4*)(cw + (size_t)(c + 3) * DCONV);
    const float4 cb4 = *(const float4*)(cb + c);
    float4 x[7];
    #pragma unroll
    for (int i = 0; i < 7; ++i) {
        if (l0 - 3 + i >= 0)
            x[i] = *(const float4*)(xz + (size_t)(m0 - 3 + i) * NXZ + c);
        else
            x[i] = make_float4(0.f, 0.f, 0.f, 0.f);
    }
    #pragma unroll
    for (int j = 0; j < 4; ++j) {
        float4 acc = cb4;
        #pragma unroll
        for (int k = 0; k < DCONV; ++k) {
            const float4 v = x[j + k];
            acc.x = fmaf(v.x, (&w0.x)[k], acc.x);
            acc.y = fmaf(v.y, (&w1.x)[k], acc.y);
            acc.z = fmaf(v.z, (&w2.x)[k], acc.z);
            acc.w = fmaf(v.w, (&w3.x)[k], acc.w);
        }
        short4v h4, l4;
        #pragma unroll
        for (int e = 0; e < 4; ++e) {
            float a = (&acc.x)[e];
            a = a / (1.f + __expf(-a));
            unsigned short hh, llo;
            split_bf(a, hh, llo);
            h4[e] = (short)hh; l4[e] = (short)llo;
        }
        *(short4v*)(xch + (size_t)(m0 + j) * DI + c) = h4;
        *(short4v*)(xcl + (size_t)(m0 + j) * DI + c) = l4;
    }
}

// ---------------------------------------------------------------------------
// Selective scan v5: reg-prefetch staging, double-buffered staging LDS,
// ONE barrier per tile (y-epilogue pipelined one tile behind).
template <int YBF, int UBF>
__global__ __launch_bounds__(256) void scan_k(
    const float* uf, const unsigned short* __restrict__ uh,
    const unsigned short* __restrict__ ul,
    const float* __restrict__ dbc,
    const float* __restrict__ xz, void* __restrict__ yv,
    const float* __restrict__ Alog, const float* __restrict__ Dl)
{
    const int b = blockIdx.y;
    const int c0 = blockIdx.x * 16;
    const int tid = threadIdx.x;
    const int ch = tid >> 4;
    const int s = tid & 15;
    const float Aa = -__expf(Alog[(size_t)(c0 + ch) * DS + s]) * 1.44269504088896f;
    __shared__ float sdl[2][16][68];
    __shared__ float sxb[2][16][68];
    __shared__ float sbc[2][32][68];
    __shared__ float sy[2][64][16];
    __shared__ float sD[16];
    if (tid < 16) sD[tid] = Dl[c0 + tid];
    float h = 0.f;
    const int row = tid >> 2;
    const int q = (tid & 3) << 2;
    const size_t base = (size_t)b * SL;
    const int r2a = tid >> 3, q2a = (tid & 7) << 2;
    const int r2b = 32 + (tid >> 3);

    float4 dlv, zv, g0, g1, uvf;
    short4v uh4, ul4;
    {
        const size_t m = base + row;
        dlv = *(const float4*)(xz + m * NXZ + c0 + q);
        if (UBF) {
            uh4 = *(const short4v*)(uh + m * DI + c0 + q);
            ul4 = *(const short4v*)(ul + m * DI + c0 + q);
        } else {
            uvf = *(const float4*)(uf + m * DI + c0 + q);
        }
        zv = *(const float4*)(xz + m * NXZ + DI + c0 + q);
        g0 = *(const float4*)(dbc + (base + r2a) * NDBC + DTR + q2a);
        g1 = *(const float4*)(dbc + (base + r2b) * NDBC + DTR + q2a);
    }
    float4 p0c, p1c, p0p, p1p;
    int pp = 0;
    __syncthreads();
    const int NT = SL / 64;
    for (int tile = 0; tile < NT; ++tile) {
        const int buf = tile & 1;
        float4 uv;
        if (UBF) {
            #pragma unroll
            for (int e = 0; e < 4; ++e)
                (&uv.x)[e] = bf2f((unsigned short)uh4[e]) +
                             bf2f((unsigned short)ul4[e]);
        } else uv = uvf;
        #pragma unroll
        for (int j = 0; j < 4; ++j) {
            const float dl = (&dlv.x)[j], uu = (&uv.x)[j], zz = (&zv.x)[j];
            const float w = zz / (1.f + __expf(-zz));
            sdl[buf][q + j][row] = dl;
            sxb[buf][q + j][row] = dl * uu;
            (&p1c.x)[j] = w;
            (&p0c.x)[j] = uu * sD[q + j] * w;
        }
        sbc[buf][q2a + 0][r2a] = g0.x; sbc[buf][q2a + 1][r2a] = g0.y;
        sbc[buf][q2a + 2][r2a] = g0.z; sbc[buf][q2a + 3][r2a] = g0.w;
        sbc[buf][q2a + 0][r2b] = g1.x; sbc[buf][q2a + 1][r2b] = g1.y;
        sbc[buf][q2a + 2][r2b] = g1.z; sbc[buf][q2a + 3][r2b] = g1.w;
        __syncthreads();
        if (tile > 0) {
            const size_t mp = base + (size_t)(tile - 1) * 64 + row;
            if (YBF) {
                unsigned short* y16 = (unsigned short*)yv;
                short4v s4;
                #pragma unroll
                for (int e = 0; e < 4; ++e)
                    s4[e] = (short)cvt1(fmaf(sy[pp ^ 1][row][q + e],
                                             (&p1p.x)[e], (&p0p.x)[e]));
                *(short4v*)(y16 + mp * DI + c0 + q) = s4;
            } else {
                float* y = (float*)yv;
                float4 yvv;
                #pragma unroll
                for (int e = 0; e < 4; ++e)
                    (&yvv.x)[e] = fmaf(sy[pp ^ 1][row][q + e],
                                       (&p1p.x)[e], (&p0p.x)[e]);
                *(float4*)(y + mp * DI + c0 + q) = yvv;
            }
        }
        if (tile + 1 < NT) {
            const size_t m = base + (size_t)(tile + 1) * 64 + row;
            dlv = *(const float4*)(xz + m * NXZ + c0 + q);
            if (UBF) {
                uh4 = *(const short4v*)(uh + m * DI + c0 + q);
                ul4 = *(const short4v*)(ul + m * DI + c0 + q);
            } else {
                uvf = *(const float4*)(uf + m * DI + c0 + q);
            }
            zv = *(const float4*)(xz + m * NXZ + DI + c0 + q);
            const size_t mb2 = base + (size_t)(tile + 1) * 64;
            g0 = *(const float4*)(dbc + (mb2 + r2a) * NDBC + DTR + q2a);
            g1 = *(const float4*)(dbc + (mb2 + r2b) * NDBC + DTR + q2a);
        }
        for (int it = 0; it < 16; ++it) {
            const int t0 = it * 4;
            const float4 dl4 = *(const float4*)&sdl[buf][ch][t0];
            const float4 xb4 = *(const float4*)&sxb[buf][ch][t0];
            const float4 B4  = *(const float4*)&sbc[buf][s][t0];
            const float4 C4  = *(const float4*)&sbc[buf][16 + s][t0];
            float py0, py1, py2, py3;
            {
                const float dA = exp2_raw(dl4.x * Aa);
                h = fmaf(dA, h, xb4.x * B4.x);
                py0 = dpp_sum16(h * C4.x);
            }
            {
                const float dA = exp2_raw(dl4.y * Aa);
                h = fmaf(dA, h, xb4.y * B4.y);
                py1 = dpp_sum16(h * C4.y);
            }
            {
                const float dA = exp2_raw(dl4.z * Aa);
                h = fmaf(dA, h, xb4.z * B4.z);
                py2 = dpp_sum16(h * C4.z);
            }
            {
                const float dA = exp2_raw(dl4.w * Aa);
                h = fmaf(dA, h, xb4.w * B4.w);
                py3 = dpp_sum16(h * C4.w);
            }
            if (s < 4) {
                const int t = t0 + s;
                const float lo_ = (s & 1) ? py1 : py0;
                const float hi_ = (s & 1) ? py3 : py2;
                sy[pp][t][ch] = (s & 2) ? hi_ : lo_;
            }
        }
        p0p = p0c; p1p = p1c;
        pp ^= 1;
    }
    __syncthreads();
    {
        const size_t mp = base + (size_t)(NT - 1) * 64 + row;
        if (YBF) {
            unsigned short* y16 = (unsigned short*)yv;
            short4v s4;
            #pragma unroll
            for (int e = 0; e < 4; ++e)
                s4[e] = (short)cvt1(fmaf(sy[pp ^ 1][row][q + e],
                                         (&p1p.x)[e], (&p0p.x)[e]));
            *(short4v*)(y16 + mp * DI + c0 + q) = s4;
        } else {
            float* y = (float*)yv;
            float4 yvv;
            #pragma unroll
            for (int e = 0; e < 4; ++e)
                (&yvv.x)[e] = fmaf(sy[pp ^ 1][row][q + e],
                                   (&p1p.x)[e], (&p0p.x)[e]);
            *(float4*)(y + mp * DI + c0 + q) = yvv;
        }
    }
}

// ---------------------------------------------------------------------------
extern "C" void kernel_launch(void* const* d_in, const int* in_sizes, int n_in,
                              void* d_out, int out_size, void* d_ws, size_t ws_size,
                              hipStream_t stream)
{
    const float* x0   = (const float*)d_in[0];
    const float* in_w = (const float*)d_in[1];
    const float* cw   = (const float*)d_in[2];
    const float* cb   = (const float*)d_in[3];
    const float* xpw  = (const float*)d_in[4];
    const float* dtw  = (const float*)d_in[5];
    const float* dtb  = (const float*)d_in[6];
    const float* Alog = (const float*)d_in[7];
    const float* Dp   = (const float*)d_in[8];
    const float* ow   = (const float*)d_in[9];

    const size_t perB = (size_t)SL * (NXZ + DI + NDBC) * sizeof(float); // ~51.1MB
    const size_t wby  = ((size_t)NXZ * DIMK + (size_t)DIMK * DI) * 2;   // 12.6MB
    int nbc = 0, fast = 0;
    if (ws_size >= 4 * perB + wby)      { nbc = 4; fast = 1; }
    else if (ws_size >= 2 * perB + wby) { nbc = 2; fast = 1; }
    else if (ws_size >= perB + wby)     { nbc = 1; fast = 1; }
    else if (ws_size >= 4 * perB)       { nbc = 4; }
    else if (ws_size >= 2 * perB)       { nbc = 2; }
    else if (ws_size >= perB)           { nbc = 1; }
    else return;
    const int nchunks = NB / nbc;
    const int M = nbc * SL;
    const size_t dtby = ((size_t)DI * DTR * 2 + (size_t)M * DTR * 2) * 2;
    const size_t yby  = (size_t)M * DI * 2;
    const size_t xpby = (size_t)NDBC * DI * 2 * 2;
    const size_t base = (size_t)nbc * perB + wby;
    const int fastd = fast && (ws_size >= base + dtby);
    const int fasty = fastd && (ws_size >= base + dtby + yby);
    const int fastx = fasty && (ws_size >= base + dtby + yby + xpby);
    const size_t wAll = ((size_t)NDEPTH * NXZ * DIMK + (size_t)NDEPTH * DIMK * DI +
                         2 * (size_t)NDEPTH * DI * DTR + 2 * (size_t)NDEPTH * NDBC * DI) * 2;
    const size_t chunkBy = (size_t)nbc * perB;
    const int fastw = fastx &&
        (ws_size >= chunkBy + wAll + (size_t)M * DTR * 2 * 2 + yby);

    float* xz  = (float*)d_ws;
    float* xc  = xz + (size_t)M * NXZ;
    float* dbc = xc + (size_t)M * DI;
    unsigned short* xch = (unsigned short*)xc;
    unsigned short* xcl = xch + (size_t)M * DI;

    unsigned short* p = (unsigned short*)(dbc + (size_t)M * NDBC);
    unsigned short *wi16, *ow16, *dtwh, *dtwl, *xpwh, *xpwl, *dth, *dtl, *y16;
    size_t wiStride = 0, owStride = 0, dtwStride = 0, xpwStride = 0;
    if (fastw) {
        wi16 = p;                    p += (size_t)NDEPTH * NXZ * DIMK;
        ow16 = p;                    p += (size_t)NDEPTH * DIMK * DI;
        dtwh = p;                    p += (size_t)NDEPTH * DI * DTR;
        dtwl = p;                    p += (size_t)NDEPTH * DI * DTR;
        xpwh = p;                    p += (size_t)NDEPTH * NDBC * DI;
        xpwl = p;                    p += (size_t)NDEPTH * NDBC * DI;
        wiStride = (size_t)NXZ * DIMK; owStride = (size_t)DIMK * DI;
        dtwStride = (size_t)DI * DTR;  xpwStride = (size_t)NDBC * DI;
    } else {
        wi16 = p;                    p += (size_t)NXZ * DIMK;
        ow16 = p;                    p += (size_t)DIMK * DI;
        dtwh = p;                    p += (size_t)DI * DTR;
        dtwl = p;                    p += (size_t)DI * DTR;
        xpwh = nullptr; xpwl = nullptr;
    }
    dth = p;                         p += (size_t)M * DTR;
    dtl = p;                         p += (size_t)M * DTR;
    y16 = p;                         p += (size_t)M * DI;
    if (!fastw && fastx) { xpwh = p; p += (size_t)NDBC * DI; xpwl = p; }

    unsigned short* xb16 = (unsigned short*)d_out + (size_t)MT * DIMK;
    float* xbuf = (float*)d_out;

    const dim3 blk(256);
    if (fastx) {
        const int n4x0 = MT * DIMK / 4;
        cvt_bf16<<<dim3(n4x0 / 256), blk, 0, stream>>>(x0, xb16, n4x0);
    }
    if (fastw) {
        const int per = (NXZ * DIMK / 4) + (DIMK * DI / 4) + (DI * DTR / 4) +
                        (NDBC * DI / 4);
        cvt_all<<<dim3((NDEPTH * per + 255) / 256), blk, 0, stream>>>(
            in_w, ow, dtw, xpw, wi16, ow16, dtwh, dtwl, xpwh, xpwl);
    }
    const int ncv = (NXZ * DIMK / 4) + (DIMK * DI / 4) + (DI * DTR / 4) +
                    (NDBC * DI / 4);
    for (int ly = 0; ly < NDEPTH; ++ly) {
        const float* Wi   = in_w + (size_t)ly * NXZ * DIMK;
        const float* cwl  = cw   + (size_t)ly * DI * DCONV;
        const float* cbl  = cb   + (size_t)ly * DI;
        const float* xpl  = xpw  + (size_t)ly * NDBC * DI;
        const float* dtwl_ = dtw + (size_t)ly * DI * DTR;
        const float* dtbl = dtb  + (size_t)ly * DI;
        const float* Al   = Alog + (size_t)ly * DI * DS;
        const float* Dl   = Dp   + (size_t)ly * DI;
        const float* owl  = ow   + (size_t)ly * DIMK * DI;

        const unsigned short* wi16L = wi16 + (size_t)ly * wiStride;
        const unsigned short* ow16L = ow16 + (size_t)ly * owStride;
        const unsigned short* dtwhL = dtwh + (size_t)ly * dtwStride;
        const unsigned short* dtwlL = dtwl + (size_t)ly * dtwStride;
        const unsigned short* xpwhL = fastx ? xpwh + (size_t)ly * xpwStride : nullptr;
        const unsigned short* xpwlL = fastx ? xpwl + (size_t)ly * xpwStride : nullptr;

        if (fast && !fastw)
            cvt_layer<<<dim3((ncv + 255) / 256), blk, 0, stream>>>(
                Wi, owl, dtwl_, xpl, wi16, ow16, dtwh, dtwl,
                (unsigned short*)xpwh, (unsigned short*)xpwl, fastd, fastx);

        for (int ck = 0; ck < nchunks; ++ck) {
            if (fastx) {
                const unsigned short* xin16 = xb16 + (size_t)ck * M * DIMK;
                gemm_bb<0><<<dim3(NXZ / 128, M / 128), blk, 0, stream>>>(
                    xin16, wi16L, xz, DIMK, DIMK, DIMK, NXZ);
                conv_silu_split<<<dim3(M * (DI / 16) / 256), blk, 0, stream>>>(
                    xz, cwl, cbl, xch, xcl);
                gemm_xproj_pre<<<dim3(3, M / 128), blk, 0, stream>>>(
                    xch, xcl, xpwhL, xpwlL, dbc, dth, dtl);
                gemm_delta_pre<<<dim3(DI / 128, M / 128), blk, 0, stream>>>(
                    dth, dtl, dtwhL, dtwlL, xz, dtbl);
                scan_k<1, 1><<<dim3(DI / 16, nbc), blk, 0, stream>>>(
                    nullptr, xch, xcl, dbc, xz, y16, Al, Dl);
                void* dst = (ly < NDEPTH - 1)
                    ? (void*)(xb16 + (size_t)ck * M * DIMK)
                    : (void*)((float*)d_out + (size_t)ck * M * DIMK);
                if (ly < NDEPTH - 1)
                    gemm_bb<1><<<dim3(DIMK / 128, M / 128), blk, 0, stream>>>(
                        y16, ow16L, dst, DI, DI, DI, DIMK);
                else
                    gemm_bb<0><<<dim3(DIMK / 128, M / 128), blk, 0, stream>>>(
                        y16, ow16L, dst, DI, DI, DI, DIMK);
            } else if (fast) {
                if (ly == 0) {
                    const float* xin = x0 + (size_t)ck * M * DIMK;
                    gemm_fb<0><<<dim3(NXZ / 128, M / 128), blk, 0, stream>>>(
                        xin, wi16, xz, DIMK, DIMK, DIMK, NXZ);
                } else {
                    const unsigned short* xin16 = xb16 + (size_t)ck * M * DIMK;
                    gemm_bb<0><<<dim3(NXZ / 128, M / 128), blk, 0, stream>>>(
                        xin16, wi16, xz, DIMK, DIMK, DIMK, NXZ);
                }
                conv_silu<<<dim3(M * (DI / 16) / 256), blk, 0, stream>>>(
                    xz, cwl, cbl, xc);
                if (fastd) {
                    gemm_xproj<1><<<dim3(3, M / 128), blk, 0, stream>>>(
                        xc, xpl, dbc, DI, DI, dth, dtl);
                    gemm_delta_pre<<<dim3(DI / 128, M / 128), blk, 0, stream>>>(
                        dth, dtl, dtwh, dtwl, xz, dtbl);
                } else {
                    gemm_xproj<0><<<dim3(3, M / 128), blk, 0, stream>>>(
                        xc, xpl, dbc, DI, DI, nullptr, nullptr);
                    gemm_delta<<<dim3(DI / 128, M / 128), blk, 0, stream>>>(
                        dbc, dtwl_, xz, dtbl);
                }
                void* dst = (ly < NDEPTH - 1)
                    ? (void*)(xb16 + (size_t)ck * M * DIMK)
                    : (void*)((float*)d_out + (size_t)ck * M * DIMK);
                if (fasty) {
                    scan_k<1, 0><<<dim3(DI / 16, nbc), blk, 0, stream>>>(
                        xc, nullptr, nullptr, dbc, xz, y16, Al, Dl);
                    if (ly < NDEPTH - 1)
                        gemm_bb<1><<<dim3(DIMK / 128, M / 128), blk, 0, stream>>>(
                            y16, ow16, dst, DI, DI, DI, DIMK);
                    else
                        gemm_bb<0><<<dim3(DIMK / 128, M / 128), blk, 0, stream>>>(
                            y16, ow16, dst, DI, DI, DI, DIMK);
                } else {
                    scan_k<0, 0><<<dim3(DI / 16, nbc), blk, 0, stream>>>(
                        xc, nullptr, nullptr, dbc, xz, xc, Al, Dl);
                    if (ly < NDEPTH - 1)
                        gemm_fb<1><<<dim3(DIMK / 128, M / 128), blk, 0, stream>>>(
                            xc, ow16, dst, DI, DI, DI, DIMK);
                    else
                        gemm_fb<0><<<dim3(DIMK / 128, M / 128), blk, 0, stream>>>(
                            xc, ow16, dst, DI, DI, DI, DIMK);
                }
            } else {
                const float* xin = (ly == 0 ? x0 : xbuf) + (size_t)ck * M * DIMK;
                gemm_mfma<<<dim3(NXZ / 128, M / 128), blk, 0, stream>>>(
                    xin, Wi, xz, DIMK, DIMK, NXZ);
                conv_silu<<<dim3(M * (DI / 16) / 256), blk, 0, stream>>>(
                    xz, cwl, cbl, xc);
                gemm_xproj<0><<<dim3(3, M / 128), blk, 0, stream>>>(
                    xc, xpl, dbc, DI, DI, nullptr, nullptr);
                gemm_delta<<<dim3(DI / 128, M / 128), blk, 0, stream>>>(
                    dbc, dtwl_, xz, dtbl);
                scan_k<0, 0><<<dim3(DI / 16, nbc), blk, 0, stream>>>(
                    xc, nullptr, nullptr, dbc, xz, xc, Al, Dl);
                float* xdst = (ly == NDEPTH - 1 ? (float*)d_out : xbuf) +
                              (size_t)ck * M * DIMK;
                gemm_mfma<<<dim3(DIMK / 128, M / 128), blk, 0, stream>>>(
                    xc, owl, xdst, DI, DI, DIMK);
            }
        }
    }
}